// Round 4
// baseline (336.664 us; speedup 1.0000x reference)
//
#include <hip/hip_runtime.h>
#include <stdint.h>
#include <cmath>

// Problem constants
#define B_    2
#define N_    2048
#define DIM_  1536
#define H_    8
#define NPOS  (2*N_ - 1)   // 4095 (posb padded to 4096 rows; pad row never gathered)
#define NB_   32           // basis per class (192/6)

typedef __attribute__((ext_vector_type(8))) short short8;
typedef __attribute__((ext_vector_type(4))) float float4v;

// Host-precomputed positional-basis constants (capture-time only)
struct PosConsts {
    float  inv_hl[32];   // 2^-t, t = 3 + f*(11-3)/31
    int    widthI[32];   // 2^(i+1)-1 clamped (central-mask widths)
    float  c1[32];       // conc-1 (exact small integers)
    float  rateF[32];    // rate = (g+1)/16 (exact dyadic)
    double gc[32];       // -lgamma(conc) + conc*log(rate)
    double maxp;
};

__device__ __forceinline__ float bf2f(unsigned short u) {
    return __uint_as_float(((unsigned int)u) << 16);
}
__device__ __forceinline__ unsigned short f2bf(float f) {
    unsigned int u = __float_as_uint(f);
    u += 0x7FFFu + ((u >> 16) & 1u);   // RNE
    return (unsigned short)(u >> 16);
}
// HW packed f32x2 -> bf16x2 (RNE, identical to f2bf pair; 1 VALU op vs ~8)
__device__ __forceinline__ unsigned int cvtpk(float lo, float hi) {
    unsigned int r;
    asm("v_cvt_pk_bf16_f32 %0, %1, %2" : "=v"(r) : "v"(lo), "v"(hi));
    return r;
}
__device__ __forceinline__ unsigned int pack2bf(float lo, float hi) {
    return cvtpk(lo, hi);
}
__device__ __forceinline__ float ldf(const void* p, int isF32, size_t idx) {
    return isF32 ? ((const float*)p)[idx] : bf2f(((const unsigned short*)p)[idx]);
}
// async global->LDS, 16B per lane; LDS dest = base + lane*16 (wave-uniform base!)
__device__ __forceinline__ void gll16(const unsigned short* g, unsigned short* l) {
    __builtin_amdgcn_global_load_lds(
        (const __attribute__((address_space(1))) unsigned int*)g,
        (__attribute__((address_space(3))) unsigned int*)l, 16, 0, 0);
}

// ---------------------------------------------------------------------------
// Workspace layout (bytes) — unchanged (35.7 MB).
// ---------------------------------------------------------------------------
constexpr size_t OFF_FLAG = 0;                                   // uint
constexpr size_t OFF_POS  = 256;                                 // bf16 [8][4096][64]
constexpr size_t OFF_Q    = OFF_POS + (size_t)H_*4096*64*2;
constexpr size_t OFF_K    = OFF_Q   + (size_t)B_*H_*N_*64*2;
constexpr size_t OFF_V    = OFF_K   + (size_t)B_*H_*N_*64*2;     // bf16 [b*h][64 d][2048 j] (TRANSPOSED)
constexpr size_t OFF_WOT  = OFF_V   + (size_t)B_*H_*N_*64*2;     // bf16 [1536][512]
constexpr size_t OFF_XB   = OFF_WOT + (size_t)DIM_*512*2;        // bf16 [4096][1536]
constexpr size_t OFF_AO   = OFF_XB;                              // bf16 [4096][512] (alias head of XB)
constexpr size_t OFF_OP   = OFF_AO + (size_t)4096*512*2;         // bf16 [3][16][32][64][64]
constexpr size_t OFF_LP   = OFF_OP + (size_t)3*16*32*4096*2;     // f32  [3][16][32][64]
constexpr size_t OFF_WT   = OFF_XB + (size_t)4096*DIM_*2;        // bf16 [3][512][1536]
static_assert(OFF_LP + (size_t)3*16*32*64*4 <= OFF_WT + (size_t)3*512*DIM_*2, "ws overflow");

// ---------------------------------------------------------------------------
// 1) prep_kernel: fused detect + cvtx + cvtw + posproj (one dispatch).
//    Roles: [0,1024) cvtx; [1024,4096) cvtw; [4096,4224) posproj (32 rows/blk).
//    Round-4: posproj restructured — host constants, float transcendentals on
//    double-computed args, 32 rows/block (4x Wrel reuse, 128 FMA per 4 loads).
// ---------------------------------------------------------------------------
__global__ __launch_bounds__(512) void prep_kernel(PosConsts pc,
                                                   const void* __restrict__ x,
                                                   const void* __restrict__ Wq, const void* __restrict__ Wk,
                                                   const void* __restrict__ Wv, const void* __restrict__ Wo,
                                                   const void* __restrict__ Wrel,
                                                   unsigned int* __restrict__ flags,
                                                   unsigned short* __restrict__ Xb,
                                                   unsigned short* __restrict__ Wt,
                                                   unsigned short* __restrict__ Wot,
                                                   unsigned short* __restrict__ posb) {
    __shared__ __align__(16) char smraw[32 * 192 * 4];   // 24576B: cnt / tile / eb overlay
    const int tid = threadIdx.x;
    const int bid = blockIdx.x;

    // ---- self-detect dtype (all blocks; ~1 cache line, L2 broadcast) ----
    int* cnt = (int*)smraw;
    int ok = 0;
    if (tid < 256) {
        unsigned short u = ((const unsigned short*)x)[2 * tid];
        int e = (u >> 7) & 0xFF;
        ok = (u == 0) || (e >= 95 && e <= 140);
    }
    cnt[tid] = ok;
    __syncthreads();
    for (int s = 256; s > 0; s >>= 1) {
        if (tid < s) cnt[tid] += cnt[tid + s];
        __syncthreads();
    }
    const int f32 = !(cnt[0] >= 192);
    __syncthreads();   // done with cnt before smem reuse
    if (bid == 0 && tid == 0) flags[0] = (unsigned int)f32;

    if (bid < 1024) {
        // ---- role A: x -> bf16 contiguous ----
        const size_t total = (size_t)4096 * DIM_;
        size_t i = ((size_t)bid * 512 + tid) * 8;
        const size_t stride = (size_t)1024 * 512 * 8;
        if (f32) {
            for (; i < total; i += stride) {
                float4v a = *reinterpret_cast<const float4v*>((const float*)x + i);
                float4v b = *reinterpret_cast<const float4v*>((const float*)x + i + 4);
                uint4 o;
                o.x = pack2bf(a[0], a[1]); o.y = pack2bf(a[2], a[3]);
                o.z = pack2bf(b[0], b[1]); o.w = pack2bf(b[2], b[3]);
                *reinterpret_cast<uint4*>(Xb + i) = o;
            }
        } else {
            for (; i < total; i += stride)
                *reinterpret_cast<uint4*>(Xb + i) =
                    *reinterpret_cast<const uint4*>((const unsigned short*)x + i);
        }
    } else if (bid < 4096) {
        // ---- role B: weight transposes -> bf16 [N][K] ----
        unsigned short (*tile)[33] = (unsigned short(*)[33])smraw;
        const int idx = bid - 1024;
        const int z = idx / 768, rem = idx % 768;
        const int bx = rem & 15, by = rem >> 4;
        const void* src = z == 0 ? Wq : (z == 1 ? Wk : (z == 2 ? Wv : Wo));
        unsigned short* dst = (z < 3) ? (Wt + (size_t)z * 512 * DIM_) : Wot;
        const int R = (z < 3) ? DIM_ : 512;
        const int C = (z < 3) ? 512 : DIM_;
        const int x0 = ((z < 3) ? bx : by) * 32;
        const int y0 = ((z < 3) ? by : bx) * 32;
        const int tx = tid & 31, ty = tid >> 5;   // ty 0..15
#pragma unroll
        for (int i = 0; i < 2; ++i)
            tile[ty + i * 16][tx] = f2bf(ldf(src, f32, (size_t)(y0 + ty + i * 16) * C + x0 + tx));
        __syncthreads();
#pragma unroll
        for (int i = 0; i < 2; ++i)
            dst[(size_t)(x0 + ty + i * 16) * R + y0 + tx] = tile[tx][ty + i * 16];
    } else {
        // ---- role C: positional basis + projection (32 rows/block) ----
        float* eb = (float*)smraw;    // [32][192]
        const int j0 = (bid - 4096) * 32;
        const int c  = tid;   // 0..511
        for (int u = c; u < 32 * 96; u += 512) {
            int rr = u / 96, f = u - rr * 96;
            int j = j0 + rr;
            float v = 0.f, sg = 0.f;
            if (j < NPOS) {
                int dd  = j - (N_ - 1);
                int adI = dd < 0 ? -dd : dd;
                float val;
                if (f < 32) {
                    // exp2(-ad * 2^-t): arg exact in f32 range, expf-class error ~1e-7
                    val = exp2f(-(float)adI * pc.inv_hl[f]);
                } else if (f < 64) {
                    val = (adI < pc.widthI[f - 32]) ? 1.f : 0.f;
                } else {
                    int g = f - 64;
                    if (adI == 0) {
                        val = (float)(1e-8 / pc.maxp);
                    } else {
                        // argument in double (exact FMA math), single float exp
                        double lp = (double)pc.c1[g] * log((double)adI)
                                  - (double)pc.rateF[g] * (double)adI + pc.gc[g];
                        double p = (double)expf((float)lp) + 1e-8;
                        val = (float)(p / pc.maxp);
                    }
                }
                v  = val;
                sg = (dd > 0) ? 1.f : ((dd < 0) ? -1.f : 0.f);
            }
            eb[rr * 192 + f]      = v;
            eb[rr * 192 + 96 + f] = sg * v;
        }
        __syncthreads();
        float acc[32];
#pragma unroll
        for (int rr = 0; rr < 32; ++rr) acc[rr] = 0.f;
        for (int k = 0; k < 192; k += 4) {
            float w0 = ldf(Wrel, f32, (size_t)(k + 0) * 512 + c);
            float w1 = ldf(Wrel, f32, (size_t)(k + 1) * 512 + c);
            float w2 = ldf(Wrel, f32, (size_t)(k + 2) * 512 + c);
            float w3 = ldf(Wrel, f32, (size_t)(k + 3) * 512 + c);
#pragma unroll
            for (int rr = 0; rr < 32; ++rr) {
                float4v e = *reinterpret_cast<const float4v*>(&eb[rr * 192 + k]);
                acc[rr] += e[0] * w0;
                acc[rr] += e[1] * w1;
                acc[rr] += e[2] * w2;
                acc[rr] += e[3] * w3;
            }
        }
        int h = c >> 6, dcol = c & 63;
        for (int rr = 0; rr < 32; ++rr) {
            int j = j0 + rr;
            if (j < NPOS)
                posb[((size_t)h * 4096 + j) * 64 + dcol] = f2bf(acc[rr]);
        }
    }
}

// ---------------------------------------------------------------------------
// 128x128 GEMM core (m97 structure): A [M][K] bf16 rm, Bt [N][K] bf16 rm.
// BK=32, 4 waves. Wave w: rows (w>>1)*64 + mi*16, cols (w&1)*64 + ni*16.
// 16 MFMA : 4 gll16 per wave-iter.
// ---------------------------------------------------------------------------
__device__ __forceinline__ void gemm128_core(const unsigned short* __restrict__ A,
                                             const unsigned short* __restrict__ Bt,
                                             int K, int row0, int col0,
                                             unsigned short* As, unsigned short* Bs,
                                             float4v acc[4][4]) {
    const int tid = threadIdx.x, lane = tid & 63, w = tid >> 6;
    const int l15 = lane & 15, q8 = (lane >> 4) * 8;
    const int mr0 = (w >> 1) * 64, nc0 = (w & 1) * 64;
    const int sr = lane >> 2, sc8 = (lane & 3) * 8;
    for (int k0 = 0; k0 < K; k0 += 32) {
        __syncthreads();
        gll16(&A [(size_t)(row0 + w * 32 + sr) * K + k0 + sc8],      &As[w * 1024]);
        gll16(&A [(size_t)(row0 + w * 32 + 16 + sr) * K + k0 + sc8], &As[w * 1024 + 512]);
        gll16(&Bt[(size_t)(col0 + w * 32 + sr) * K + k0 + sc8],      &Bs[w * 1024]);
        gll16(&Bt[(size_t)(col0 + w * 32 + 16 + sr) * K + k0 + sc8], &Bs[w * 1024 + 512]);
        __syncthreads();
        short8 a[4], b[4];
#pragma unroll
        for (int mi = 0; mi < 4; ++mi)
            a[mi] = *reinterpret_cast<const short8*>(&As[(mr0 + mi * 16 + l15) * 32 + q8]);
#pragma unroll
        for (int ni = 0; ni < 4; ++ni)
            b[ni] = *reinterpret_cast<const short8*>(&Bs[(nc0 + ni * 16 + l15) * 32 + q8]);
#pragma unroll
        for (int mi = 0; mi < 4; ++mi)
#pragma unroll
            for (int ni = 0; ni < 4; ++ni)
                acc[mi][ni] = __builtin_amdgcn_mfma_f32_16x16x32_bf16(a[mi], b[ni], acc[mi][ni], 0, 0, 0);
    }
}

// ---------------------------------------------------------------------------
// 2) QKV single dispatch: Wt [1536 n][1536 k]; mode = n>>9. grid (12,32).
//    V (mode 2) is written TRANSPOSED: vbuf[(bh*64+d)*2048 + j] (uint2 packed).
// ---------------------------------------------------------------------------
__global__ __launch_bounds__(256) void qkv_kernel(const unsigned short* __restrict__ Xb,
                                                  const unsigned short* __restrict__ Wt,
                                                  unsigned short* __restrict__ qbuf,
                                                  unsigned short* __restrict__ kbuf,
                                                  unsigned short* __restrict__ vbuf) {
    __shared__ __align__(16) unsigned short As[128 * 32];
    __shared__ __align__(16) unsigned short Bs[128 * 32];
    const int row0 = blockIdx.y * 128, col0 = blockIdx.x * 128;
    float4v acc[4][4];
#pragma unroll
    for (int mi = 0; mi < 4; ++mi)
#pragma unroll
        for (int ni = 0; ni < 4; ++ni) acc[mi][ni] = (float4v){0.f, 0.f, 0.f, 0.f};
    gemm128_core(Xb, Wt, DIM_, row0, col0, As, Bs, acc);
    const int lane = threadIdx.x & 63, w = threadIdx.x >> 6;
    const int l15 = lane & 15, quad = lane >> 4;
    const int mr0 = (w >> 1) * 64, nc0 = (w & 1) * 64;
#pragma unroll
    for (int mi = 0; mi < 4; ++mi)
#pragma unroll
        for (int ni = 0; ni < 4; ++ni) {
            int n = col0 + nc0 + ni * 16 + l15;
            int mode = n >> 9, nn = n & 511;
            int hh = nn >> 6, dd = nn & 63;
            int mb = row0 + mr0 + mi * 16 + quad * 4;   // 4 consecutive rows mb..mb+3
            int bb = mb >> 11, ii = mb & 2047;          // no 2048-crossing within r
            if (mode == 2) {
                union { unsigned short us[4]; uint2 u2; } pk;
                unsigned int p0 = cvtpk(acc[mi][ni][0], acc[mi][ni][1]);
                unsigned int p1 = cvtpk(acc[mi][ni][2], acc[mi][ni][3]);
                pk.u2 = (uint2){p0, p1};
                *reinterpret_cast<uint2*>(
                    &vbuf[((size_t)(bb * 8 + hh) * 64 + dd) * 2048 + ii]) = pk.u2;
            } else {
                unsigned short* Obuf = (mode == 0) ? qbuf : kbuf;
                float scale = (mode == 0) ? 0.125f : 1.0f;
#pragma unroll
                for (int r = 0; r < 4; ++r)
                    Obuf[((size_t)(bb * 8 + hh) * N_ + ii + r) * 64 + dd] = f2bf(acc[mi][ni][r] * scale);
            }
        }
}

// ---------------------------------------------------------------------------
// 3) MFMA flash attention, j-split z=3. Round-4: swizzle REVERTED (K/V/pos
//    working set is L3-resident; m160: swizzle costs ~2% when L3-fit).
//    Grid back to (32,16,3), round-2 structure otherwise.
// ---------------------------------------------------------------------------
#define SLD 72    // bf16 tile row stride (144B: 16B-aligned, conflict-benign)
#define RST 68    // ring row stride (136B: 8B-aligned for uint2 reads at m0)

__device__ __forceinline__ void stage64(const unsigned short* __restrict__ g,
                                        unsigned short* __restrict__ s, int tid) {
    // 64x64 bf16 tile, global row stride 64 -> LDS row stride SLD
    int r = tid >> 2, d0 = (tid & 3) * 16;
    const uint4* p = reinterpret_cast<const uint4*>(g + (size_t)r * 64 + d0);
    *reinterpret_cast<uint4*>(&s[r * SLD + d0])     = p[0];
    *reinterpret_cast<uint4*>(&s[r * SLD + d0 + 8]) = p[1];
}

__global__ __launch_bounds__(256) void attn_kernel(const unsigned int* __restrict__ flags,
                                                   const unsigned short* __restrict__ qb,
                                                   const unsigned short* __restrict__ kb,
                                                   const unsigned short* __restrict__ vb,   // [bh][d][j]
                                                   const unsigned short* __restrict__ posb,
                                                   const void* __restrict__ rcb,
                                                   const void* __restrict__ rpb,
                                                   unsigned short* __restrict__ Opart,
                                                   float* __restrict__ lpart) {
    __shared__ __align__(16) unsigned short Ks[64 * SLD];    // [j][d]
    __shared__ __align__(16) unsigned short Ps[64 * SLD];    // [t][d]
    __shared__ __align__(16) unsigned short Vt[64 * SLD];    // [d][j]
    __shared__ __align__(16) unsigned short Pp[64 * SLD];    // [i][j] (wave-private rows)
    __shared__ __align__(8)  unsigned short Rb[128 * RST];   // skewed rel ring [(t+m)&127][m]

    const int f32 = (int)flags[0];
    const int tid = threadIdx.x;
    const int it = blockIdx.x, bh = blockIdx.y, z = blockIdx.z;
    const int h = bh & 7;
    const int i0 = it * 64;
    const size_t qoff = (size_t)bh * N_ * 64;
    const size_t voff = (size_t)bh * 64 * 2048;
    const size_t poff = (size_t)h * 4096 * 64;
    const int lane = tid & 63, w = tid >> 6;
    const int l15 = lane & 15, quad = lane >> 4, q8 = quad * 8;
    const int m0 = w * 16 + quad * 4;
    const int sr = tid >> 2, sc = (tid & 3) * 16;

    // ---- Q fragments (contiguous 16B in global, once per block), biases folded ----
    short8 afc[2], afr[2];
#pragma unroll
    for (int kc = 0; kc < 2; ++kc) {
        uint4 qv = *reinterpret_cast<const uint4*>(
            &qb[qoff + (size_t)(i0 + w * 16 + l15) * 64 + kc * 32 + q8]);
        unsigned int uu[4] = {qv.x, qv.y, qv.z, qv.w};
        unsigned int cw[4], rw[4];
#pragma unroll
        for (int e = 0; e < 4; ++e) {
            int k = h * 64 + kc * 32 + q8 + 2 * e;
            float lo = __uint_as_float(uu[e] << 16);
            float hi = __uint_as_float(uu[e] & 0xffff0000u);
            cw[e] = pack2bf(lo + ldf(rcb, f32, k), hi + ldf(rcb, f32, k + 1));
            rw[e] = pack2bf(lo + ldf(rpb, f32, k), hi + ldf(rpb, f32, k + 1));
        }
        union { uint4 u; short8 s; } cv, rv2;
        cv.u  = (uint4){cw[0], cw[1], cw[2], cw[3]};
        rv2.u = (uint4){rw[0], rw[1], rw[2], rw[3]};
        afc[kc] = cv.s;
        afr[kc] = rv2.s;
    }

    float4v Oa[4];
#pragma unroll
    for (int nb = 0; nb < 4; ++nb) Oa[nb] = (float4v){0.f, 0.f, 0.f, 0.f};
    float lsum[4] = {0.f, 0.f, 0.f, 0.f};

    const int base0 = 1984 - i0;
    const int t0 = z * 11, t1 = (z == 2) ? 32 : (t0 + 11);
    const int cs0 = base0 + t0 * 64;

    // ---- prologue 1: seed ring from pos chunk cs0 ----
    stage64(&posb[poff + (size_t)cs0 * 64], Ps, tid);
    __syncthreads();
    {
        float4v R[4];
#pragma unroll
        for (int nb = 0; nb < 4; ++nb) R[nb] = (float4v){0.f, 0.f, 0.f, 0.f};
        __builtin_amdgcn_s_setprio(1);
#pragma unroll
        for (int kc = 0; kc < 2; ++kc)
#pragma unroll
            for (int nb = 0; nb < 4; ++nb) {
                short8 pb = *reinterpret_cast<const short8*>(&Ps[(nb * 16 + l15) * SLD + kc * 32 + q8]);
                R[nb] = __builtin_amdgcn_mfma_f32_16x16x32_bf16(afr[kc], pb, R[nb], 0, 0, 0);
            }
        __builtin_amdgcn_s_setprio(0);
#pragma unroll
        for (int nb = 0; nb < 4; ++nb) {
            int ta = cs0 + nb * 16 + l15;
            unsigned int pk0 = cvtpk(R[nb][0], R[nb][1]);
            unsigned int pk1 = cvtpk(R[nb][2], R[nb][3]);
            Rb[(size_t)((ta + m0 + 0) & 127) * RST + m0 + 0] = (unsigned short)pk0;
            Rb[(size_t)((ta + m0 + 1) & 127) * RST + m0 + 1] = (unsigned short)(pk0 >> 16);
            Rb[(size_t)((ta + m0 + 2) & 127) * RST + m0 + 2] = (unsigned short)pk1;
            Rb[(size_t)((ta + m0 + 3) & 127) * RST + m0 + 3] = (unsigned short)(pk1 >> 16);
        }
    }
    __syncthreads();   // all waves done reading Ps before restage

    // ---- prologue 2: stage tile t0 (K, pos cs0+64, V-transposed) ----
    stage64(&kb[qoff + (size_t)(t0 * 64) * 64], Ks, tid);
    stage64(&posb[poff + (size_t)(cs0 + 64) * 64], Ps, tid);
    {
        const unsigned short* gv = &vb[voff + (size_t)sr * 2048 + t0 * 64 + sc];
        *reinterpret_cast<uint4*>(&Vt[sr * SLD + sc])     = *reinterpret_cast<const uint4*>(gv);
        *reinterpret_cast<uint4*>(&Vt[sr * SLD + sc + 8]) = *reinterpret_cast<const uint4*>(gv + 8);
    }
    __syncthreads();

    for (int jt = t0; jt < t1; ++jt) {
        const int j0 = jt * 64, basej = base0 + j0;
        const bool hasn = (jt + 1 < t1);

        // ---- issue next-tile global loads, then FENCE so they can't sink ----
        uint4 kr0, kr1, pr0, pr1, vr0, vr1;
        if (hasn) {
            const unsigned short* gk = &kb[qoff + (size_t)(j0 + 64 + sr) * 64 + sc];
            kr0 = *reinterpret_cast<const uint4*>(gk);
            kr1 = *reinterpret_cast<const uint4*>(gk + 8);
            const unsigned short* gp = &posb[poff + (size_t)(basej + 128 + sr) * 64 + sc];
            pr0 = *reinterpret_cast<const uint4*>(gp);
            pr1 = *reinterpret_cast<const uint4*>(gp + 8);
            const unsigned short* gv = &vb[voff + (size_t)sr * 2048 + j0 + 64 + sc];
            vr0 = *reinterpret_cast<const uint4*>(gv);
            vr1 = *reinterpret_cast<const uint4*>(gv + 8);
            __builtin_amdgcn_sched_barrier(0);
        }

        // ---- rel GEMM from Ps -> 64 new ring cols at basej+64 (skewed store) ----
        {
            float4v R[4];
#pragma unroll
            for (int nb = 0; nb < 4; ++nb) R[nb] = (float4v){0.f, 0.f, 0.f, 0.f};
            __builtin_amdgcn_s_setprio(1);
#pragma unroll
            for (int kc = 0; kc < 2; ++kc)
#pragma unroll
                for (int nb = 0; nb < 4; ++nb) {
                    short8 pb = *reinterpret_cast<const short8*>(&Ps[(nb * 16 + l15) * SLD + kc * 32 + q8]);
                    R[nb] = __builtin_amdgcn_mfma_f32_16x16x32_bf16(afr[kc], pb, R[nb], 0, 0, 0);
                }
            __builtin_amdgcn_s_setprio(0);
            const int tb = basej + 64;
#pragma unroll
            for (int nb = 0; nb < 4; ++nb) {
                int ta = tb + nb * 16 + l15;
                unsigned int pk0 = cvtpk(R[nb][0], R[nb][1]);
                unsigned int pk1 = cvtpk(R[nb][2], R[nb][3]);
                Rb[(size_t)((ta + m0 + 0) & 127) * RST + m0 + 0] = (unsigned short)pk0;
                Rb[(size_t)((ta + m0 + 1) & 127) * RST + m0 + 1] = (unsigned short)(pk0 >> 16);
                Rb[(size_t)((ta + m0 + 2) & 127) * RST + m0 + 2] = (unsigned short)pk1;
                Rb[(size_t)((ta + m0 + 3) & 127) * RST + m0 + 3] = (unsigned short)(pk1 >> 16);
            }
        }

        // ---- content GEMM: Sacc = Qc · K^T (frags from LDS) ----
        float4v Sacc[4];
#pragma unroll
        for (int nb = 0; nb < 4; ++nb) Sacc[nb] = (float4v){0.f, 0.f, 0.f, 0.f};
        __builtin_amdgcn_s_setprio(1);
#pragma unroll
        for (int kc = 0; kc < 2; ++kc)
#pragma unroll
            for (int nb = 0; nb < 4; ++nb) {
                short8 kf = *reinterpret_cast<const short8*>(&Ks[(nb * 16 + l15) * SLD + kc * 32 + q8]);
                Sacc[nb] = __builtin_amdgcn_mfma_f32_16x16x32_bf16(afc[kc], kf, Sacc[nb], 0, 0, 0);
            }
        __builtin_amdgcn_s_setprio(0);

        // ---- vector gather of rel diagonal, exp, pack P via cvt_pk ----
        float pv4[4][4];
#pragma unroll
        for (int nb = 0; nb < 4; ++nb) {
            const int jl = nb * 16 + l15;
            const int row = (basej + 63 + jl) & 127;
            union { uint2 u2; unsigned short us[4]; } rv;
            rv.u2 = *reinterpret_cast<const uint2*>(&Rb[(size_t)row * RST + m0]);
#pragma unroll
            for (int r = 0; r < 4; ++r) {
                float p = __expf(Sacc[nb][r] + bf2f(rv.us[r]));
                pv4[nb][r] = p;
                lsum[r] += p;
            }
        }
#pragma unroll
        for (int r = 0; r < 4; ++r) {
            unsigned short* prow = &Pp[(m0 + r) * SLD + l15];
#pragma unroll
            for (int np = 0; np < 2; ++np) {
                unsigned int pk = cvtpk(pv4[2 * np][r], pv4[2 * np + 1][r]);
                prow[(2 * np) * 16]     = (unsigned short)pk;
                prow[(2 * np + 1) * 16] = (unsigned short)(pk >> 16);
            }
        }

        // ---- PV GEMM: Oa += P · V (Pp rows wave-private) ----
        __builtin_amdgcn_s_setprio(1);
#pragma unroll
        for (int kc = 0; kc < 2; ++kc) {
            short8 pf = *reinterpret_cast<const short8*>(&Pp[(w * 16 + l15) * SLD + kc * 32 + q8]);
#pragma unroll
            for (int nb = 0; nb < 4; ++nb) {
                short8 vf = *reinterpret_cast<const short8*>(&Vt[(nb * 16 + l15) * SLD + kc * 32 + q8]);
                Oa[nb] = __builtin_amdgcn_mfma_f32_16x16x32_bf16(pf, vf, Oa[nb], 0, 0, 0);
            }
        }
        __builtin_amdgcn_s_setprio(0);

        // ---- drain prefetch, publish next tile to LDS ----
        if (hasn) {
            __syncthreads();   // all waves done reading Ks/Ps/Vt
            *reinterpret_cast<uint4*>(&Ks[sr * SLD + sc])     = kr0;
            *reinterpret_cast<uint4*>(&Ks[sr * SLD + sc + 8]) = kr1;
            *reinterpret_cast<uint4*>(&Ps[sr * SLD + sc])     = pr0;
            *reinterpret_cast<uint4*>(&Ps[sr * SLD + sc + 8]) = pr1;
            *reinterpret_cast<uint4*>(&Vt[sr * SLD + sc])     = vr0;
            *reinterpret_cast<uint4*>(&Vt[sr * SLD + sc + 8]) = vr1;
            __syncthreads();
        }
    }

    // ---- reduce row sums, write partials (coalesced via Pp round-trip) ----
#pragma unroll
    for (int r = 0; r < 4; ++r)
#pragma unroll
        for (int off = 1; off < 16; off <<= 1) lsum[r] += __shfl_xor(lsum[r], off);
    const size_t pslot = (size_t)(z * 16 + bh) * 32 + it;
    const size_t obase = pslot * 4096;
#pragma unroll
    for (int nb = 0; nb < 4; ++nb) {
        unsigned int pk0 = cvtpk(Oa[nb][0], Oa[nb][1]);
        unsigned int pk1 = cvtpk(Oa[nb][2], Oa[nb][3]);
        unsigned short* prow = &Pp[m0 * SLD + nb * 16 + l15];
        prow[0 * SLD] = (unsigned short)pk0;
        prow[1 * SLD] = (unsigned short)(pk0 >> 16);
        prow[2 * SLD] = (unsigned short)pk1;
        prow[3 * SLD] = (unsigned short)(pk1 >> 16);
    }
    {
        const int rr2 = w * 16 + (lane >> 2), cc2 = (lane & 3) * 16;
        uint4 o0 = *reinterpret_cast<const uint4*>(&Pp[rr2 * SLD + cc2]);
        uint4 o1 = *reinterpret_cast<const uint4*>(&Pp[rr2 * SLD + cc2 + 8]);
        *reinterpret_cast<uint4*>(&Opart[obase + (size_t)rr2 * 64 + cc2])     = o0;
        *reinterpret_cast<uint4*>(&Opart[obase + (size_t)rr2 * 64 + cc2 + 8]) = o1;
    }
    if (l15 == 0) {
#pragma unroll
        for (int r = 0; r < 4; ++r) lpart[pslot * 64 + m0 + r] = lsum[r];
    }
}

// ---------------------------------------------------------------------------
// 4) Combine j-split partials, normalize, write ao[b][i][h*64+d] bf16.
// ---------------------------------------------------------------------------
__global__ __launch_bounds__(256) void combine_kernel(const unsigned short* __restrict__ Opart,
                                                      const float* __restrict__ lpart,
                                                      unsigned short* __restrict__ ao) {
    const int it = blockIdx.x, bh = blockIdx.y;
    const int h = bh & 7, b = bh >> 3, i0 = it * 64;
    const int tid = threadIdx.x;
    const int row = tid >> 2, c0 = (tid & 3) * 16;
    float o[16];
#pragma unroll
    for (int e = 0; e < 16; ++e) o[e] = 0.f;
    float l = 0.f;
#pragma unroll
    for (int z = 0; z < 3; ++z) {
        const size_t pslot = (size_t)(z * 16 + bh) * 32 + it;
        const size_t ob = pslot * 4096 + (size_t)row * 64 + c0;
        uint4 a = *reinterpret_cast<const uint4*>(&Opart[ob]);
        uint4 b4 = *reinterpret_cast<const uint4*>(&Opart[ob + 8]);
        unsigned int uu[8] = {a.x, a.y, a.z, a.w, b4.x, b4.y, b4.z, b4.w};
#pragma unroll
        for (int e = 0; e < 8; ++e) {
            o[2 * e]     += __uint_as_float(uu[e] << 16);
            o[2 * e + 1] += __uint_as_float(uu[e] & 0xffff0000u);
        }
        l += lpart[pslot * 64 + row];
    }
    float inv = 1.0f / l;
    unsigned int ou[8];
#pragma unroll
    for (int e = 0; e < 8; ++e) ou[e] = pack2bf(o[2 * e] * inv, o[2 * e + 1] * inv);
    unsigned short* dst = &ao[((size_t)b * N_ + i0 + row) * 512 + h * 64 + c0];
    *reinterpret_cast<uint4*>(dst)     = (uint4){ou[0], ou[1], ou[2], ou[3]};
    *reinterpret_cast<uint4*>(dst + 8) = (uint4){ou[4], ou[5], ou[6], ou[7]};
}

// ---------------------------------------------------------------------------
// 5) out = ao @ Wo + bo (output dtype per flag). grid (12, 32).
// ---------------------------------------------------------------------------
__global__ __launch_bounds__(256) void outproj_kernel(const unsigned int* __restrict__ flags,
                                                      const unsigned short* __restrict__ AO,
                                                      const unsigned short* __restrict__ Wot,
                                                      const void* __restrict__ bo,
                                                      void* __restrict__ out) {
    __shared__ __align__(16) unsigned short As[128 * 32];
    __shared__ __align__(16) unsigned short Bs[128 * 32];
    const int f32 = (int)flags[0];
    const int row0 = blockIdx.y * 128, col0 = blockIdx.x * 128;
    float4v acc[4][4];
#pragma unroll
    for (int mi = 0; mi < 4; ++mi)
#pragma unroll
        for (int ni = 0; ni < 4; ++ni) acc[mi][ni] = (float4v){0.f, 0.f, 0.f, 0.f};
    gemm128_core(AO, Wot, 512, row0, col0, As, Bs, acc);
    const int lane = threadIdx.x & 63, w = threadIdx.x >> 6;
    const int l15 = lane & 15, quad = lane >> 4;
    const int mr0 = (w >> 1) * 64, nc0 = (w & 1) * 64;
#pragma unroll
    for (int mi = 0; mi < 4; ++mi)
#pragma unroll
        for (int ni = 0; ni < 4; ++ni) {
            int n = col0 + nc0 + ni * 16 + l15;
            float bias = ldf(bo, f32, n);
#pragma unroll
            for (int r = 0; r < 4; ++r) {
                int m = row0 + mr0 + mi * 16 + quad * 4 + r;
                float v = acc[mi][ni][r] + bias;
                if (f32) ((float*)out)[(size_t)m * DIM_ + n] = v;
                else     ((unsigned short*)out)[(size_t)m * DIM_ + n] = f2bf(v);
            }
        }
}

// ---------------------------------------------------------------------------
extern "C" void kernel_launch(void* const* d_in, const int* in_sizes, int n_in,
                              void* d_out, int out_size, void* d_ws, size_t ws_size,
                              hipStream_t stream) {
    const void* x    = d_in[0];
    const void* Wq   = d_in[1];
    const void* Wk   = d_in[2];
    const void* Wv   = d_in[3];
    const void* Wo   = d_in[4];
    const void* bo   = d_in[5];
    const void* Wrel = d_in[6];
    const void* rcb  = d_in[7];
    const void* rpb  = d_in[8];

    char* ws = (char*)d_ws;
    unsigned int*   flags = (unsigned int*)(ws + OFF_FLAG);
    unsigned short* posb  = (unsigned short*)(ws + OFF_POS);
    unsigned short* qbuf  = (unsigned short*)(ws + OFF_Q);
    unsigned short* kbuf  = (unsigned short*)(ws + OFF_K);
    unsigned short* vbuf  = (unsigned short*)(ws + OFF_V);
    unsigned short* Wot   = (unsigned short*)(ws + OFF_WOT);
    unsigned short* Xb    = (unsigned short*)(ws + OFF_XB);
    unsigned short* ao    = (unsigned short*)(ws + OFF_AO);
    unsigned short* Opart = (unsigned short*)(ws + OFF_OP);
    float*          lpart = (float*)(ws + OFF_LP);
    unsigned short* Wt    = (unsigned short*)(ws + OFF_WT);

    // Host-side constants (capture-time only; pure functions of problem consts)
    PosConsts pc;
    double maxp = 0.0;
    for (int g = 0; g < NB_; ++g) {
        double mean = 64.0 * (g + 1);
        double conc = (mean / 32.0) * (mean / 32.0);
        double rate = mean / 1024.0;
        double lgc  = std::lgamma(conc);
        double clr  = conc * std::log(rate);
        for (int ad = 1; ad < N_; ++ad) {
            double lp = (conc - 1.0) * std::log((double)ad) - rate * (double)ad - lgc + clr;
            double p  = std::exp(lp) + 1e-8;
            if (p > maxp) maxp = p;
        }
        pc.c1[g]    = (float)(conc - 1.0);   // exact small integer
        pc.rateF[g] = (float)rate;           // exact dyadic
        pc.gc[g]    = -lgc + clr;
    }
    pc.maxp = maxp;
    const double max_range = std::log((double)N_) / std::log(2.0);   // 11.0
    for (int f = 0; f < 32; ++f) {
        double t = 3.0 + (double)f * (max_range - 3.0) / 31.0;
        pc.inv_hl[f] = (float)std::exp2(-t);
        int e = f + 1;   // central-mask exponent for class index f
        pc.widthI[f] = (e >= 12) ? 0x7FFFFFFF : ((1 << e) - 1);   // adI<=2047: clamp exact
    }

    prep_kernel<<<dim3(4224), dim3(512), 0, stream>>>(pc, x, Wq, Wk, Wv, Wo, Wrel,
                                                      flags, Xb, Wt, Wot, posb);
    qkv_kernel<<<dim3(12, 32), dim3(256), 0, stream>>>(Xb, Wt, qbuf, kbuf, vbuf);
    attn_kernel<<<dim3(32, 16, 3), dim3(256), 0, stream>>>(flags, qbuf, kbuf, vbuf, posb, rcb, rpb, Opart, lpart);
    combine_kernel<<<dim3(32, 16), dim3(256), 0, stream>>>(Opart, lpart, ao);
    outproj_kernel<<<dim3(12, 32), dim3(256), 0, stream>>>(flags, ao, Wot, bo, d_out);
}

// Round 5
// 263.439 us; speedup vs baseline: 1.2780x; 1.2780x over previous
//
#include <hip/hip_runtime.h>
#include <stdint.h>
#include <cmath>

// Problem constants
#define B_    2
#define N_    2048
#define DIM_  1536
#define H_    8
#define NPOS  (2*N_ - 1)   // 4095 (posb padded to 4096 rows; pad row never gathered)
#define NB_   32           // basis per class (192/6)

typedef __attribute__((ext_vector_type(8))) short short8;
typedef __attribute__((ext_vector_type(4))) float float4v;

// Host-precomputed positional-basis constants (capture-time only)
struct PosConsts {
    float  inv_hl[32];   // 2^-t, t = 3 + f*(11-3)/31
    int    widthI[32];   // 2^(i+1)-1 clamped (central-mask widths)
    float  c1[32];       // conc-1 (exact small integers)
    float  rateF[32];    // rate = (g+1)/16 (exact dyadic)
    double gc[32];       // -lgamma(conc) + conc*log(rate)
    double maxp;
};

__device__ __forceinline__ float bf2f(unsigned short u) {
    return __uint_as_float(((unsigned int)u) << 16);
}
__device__ __forceinline__ unsigned short f2bf(float f) {
    unsigned int u = __float_as_uint(f);
    u += 0x7FFFu + ((u >> 16) & 1u);   // RNE
    return (unsigned short)(u >> 16);
}
// HW packed f32x2 -> bf16x2 (RNE, identical to f2bf pair; 1 VALU op vs ~8)
__device__ __forceinline__ unsigned int cvtpk(float lo, float hi) {
    unsigned int r;
    asm("v_cvt_pk_bf16_f32 %0, %1, %2" : "=v"(r) : "v"(lo), "v"(hi));
    return r;
}
__device__ __forceinline__ unsigned int pack2bf(float lo, float hi) {
    return cvtpk(lo, hi);
}
__device__ __forceinline__ float ldf(const void* p, int isF32, size_t idx) {
    return isF32 ? ((const float*)p)[idx] : bf2f(((const unsigned short*)p)[idx]);
}
// async global->LDS, 16B per lane; LDS dest = base + lane*16 (wave-uniform base!)
__device__ __forceinline__ void gll16(const unsigned short* g, unsigned short* l) {
    __builtin_amdgcn_global_load_lds(
        (const __attribute__((address_space(1))) unsigned int*)g,
        (__attribute__((address_space(3))) unsigned int*)l, 16, 0, 0);
}

// ---------------------------------------------------------------------------
// Workspace layout (bytes) — unchanged (35.7 MB).
// ---------------------------------------------------------------------------
constexpr size_t OFF_FLAG = 0;                                   // uint
constexpr size_t OFF_POS  = 256;                                 // bf16 [8][4096][64]
constexpr size_t OFF_Q    = OFF_POS + (size_t)H_*4096*64*2;
constexpr size_t OFF_K    = OFF_Q   + (size_t)B_*H_*N_*64*2;
constexpr size_t OFF_V    = OFF_K   + (size_t)B_*H_*N_*64*2;     // bf16 [b*h][64 d][2048 j] (TRANSPOSED)
constexpr size_t OFF_WOT  = OFF_V   + (size_t)B_*H_*N_*64*2;     // bf16 [1536][512]
constexpr size_t OFF_XB   = OFF_WOT + (size_t)DIM_*512*2;        // bf16 [4096][1536]
constexpr size_t OFF_AO   = OFF_XB;                              // bf16 [4096][512] (alias head of XB)
constexpr size_t OFF_OP   = OFF_AO + (size_t)4096*512*2;         // bf16 [3][16][32][64][64]
constexpr size_t OFF_LP   = OFF_OP + (size_t)3*16*32*4096*2;     // f32  [3][16][32][64]
constexpr size_t OFF_WT   = OFF_XB + (size_t)4096*DIM_*2;        // bf16 [3][512][1536]
static_assert(OFF_LP + (size_t)3*16*32*64*4 <= OFF_WT + (size_t)3*512*DIM_*2, "ws overflow");

// ---------------------------------------------------------------------------
// 1) prep_kernel: fused detect + posproj + cvtw + cvtx (one dispatch).
//    Round-5: role C FIRST (dispatches at t=0, overlaps A/B instead of
//    trailing); C = 256 blocks x 16 rows, acc[16] fully unrolled (round-4's
//    acc[32] + non-unrolled writeback spilled to scratch: VGPR 92->32 tell).
//    Roles: [0,256) posproj; [256,3328) cvtw; [3328,4352) cvtx.
// ---------------------------------------------------------------------------
__global__ __launch_bounds__(512) void prep_kernel(PosConsts pc,
                                                   const void* __restrict__ x,
                                                   const void* __restrict__ Wq, const void* __restrict__ Wk,
                                                   const void* __restrict__ Wv, const void* __restrict__ Wo,
                                                   const void* __restrict__ Wrel,
                                                   unsigned int* __restrict__ flags,
                                                   unsigned short* __restrict__ Xb,
                                                   unsigned short* __restrict__ Wt,
                                                   unsigned short* __restrict__ Wot,
                                                   unsigned short* __restrict__ posb) {
    __shared__ __align__(16) char smraw[16 * 192 * 4];   // 12288B: cnt / tile / eb overlay
    const int tid = threadIdx.x;
    const int bid = blockIdx.x;

    // ---- self-detect dtype (all blocks; ~1 cache line, L2 broadcast) ----
    int* cnt = (int*)smraw;
    int ok = 0;
    if (tid < 256) {
        unsigned short u = ((const unsigned short*)x)[2 * tid];
        int e = (u >> 7) & 0xFF;
        ok = (u == 0) || (e >= 95 && e <= 140);
    }
    cnt[tid] = ok;
    __syncthreads();
    for (int s = 256; s > 0; s >>= 1) {
        if (tid < s) cnt[tid] += cnt[tid + s];
        __syncthreads();
    }
    const int f32 = !(cnt[0] >= 192);
    __syncthreads();   // done with cnt before smem reuse
    if (bid == 0 && tid == 0) flags[0] = (unsigned int)f32;

    if (bid < 256) {
        // ---- role C: positional basis + projection (16 rows/block, FIRST) ----
        float* eb = (float*)smraw;    // [16][192]
        const int j0 = bid * 16;
        const int c  = tid;   // 0..511
        for (int u = c; u < 16 * 96; u += 512) {
            int rr = u / 96, f = u - rr * 96;
            int j = j0 + rr;
            float v = 0.f, sg = 0.f;
            if (j < NPOS) {
                int dd  = j - (N_ - 1);
                int adI = dd < 0 ? -dd : dd;
                float val;
                if (f < 32) {
                    val = exp2f(-(float)adI * pc.inv_hl[f]);
                } else if (f < 64) {
                    val = (adI < pc.widthI[f - 32]) ? 1.f : 0.f;
                } else {
                    int g = f - 64;
                    if (adI == 0) {
                        val = (float)(1e-8 / pc.maxp);
                    } else {
                        double lp = (double)pc.c1[g] * log((double)adI)
                                  - (double)pc.rateF[g] * (double)adI + pc.gc[g];
                        double p = (double)expf((float)lp) + 1e-8;
                        val = (float)(p / pc.maxp);
                    }
                }
                v  = val;
                sg = (dd > 0) ? 1.f : ((dd < 0) ? -1.f : 0.f);
            }
            eb[rr * 192 + f]      = v;
            eb[rr * 192 + 96 + f] = sg * v;
        }
        __syncthreads();
        float acc[16];
#pragma unroll
        for (int rr = 0; rr < 16; ++rr) acc[rr] = 0.f;
        for (int k = 0; k < 192; k += 4) {
            float w0 = ldf(Wrel, f32, (size_t)(k + 0) * 512 + c);
            float w1 = ldf(Wrel, f32, (size_t)(k + 1) * 512 + c);
            float w2 = ldf(Wrel, f32, (size_t)(k + 2) * 512 + c);
            float w3 = ldf(Wrel, f32, (size_t)(k + 3) * 512 + c);
#pragma unroll
            for (int rr = 0; rr < 16; ++rr) {
                float4v e = *reinterpret_cast<const float4v*>(&eb[rr * 192 + k]);
                acc[rr] += e[0] * w0;
                acc[rr] += e[1] * w1;
                acc[rr] += e[2] * w2;
                acc[rr] += e[3] * w3;
            }
        }
        int h = c >> 6, dcol = c & 63;
#pragma unroll
        for (int rr = 0; rr < 16; ++rr) {
            int j = j0 + rr;
            if (j < NPOS)
                posb[((size_t)h * 4096 + j) * 64 + dcol] = f2bf(acc[rr]);
        }
    } else if (bid < 3328) {
        // ---- role B: weight transposes -> bf16 [N][K] ----
        unsigned short (*tile)[33] = (unsigned short(*)[33])smraw;
        const int idx = bid - 256;
        const int z = idx / 768, rem = idx % 768;
        const int bx = rem & 15, by = rem >> 4;
        const void* src = z == 0 ? Wq : (z == 1 ? Wk : (z == 2 ? Wv : Wo));
        unsigned short* dst = (z < 3) ? (Wt + (size_t)z * 512 * DIM_) : Wot;
        const int R = (z < 3) ? DIM_ : 512;
        const int C = (z < 3) ? 512 : DIM_;
        const int x0 = ((z < 3) ? bx : by) * 32;
        const int y0 = ((z < 3) ? by : bx) * 32;
        const int tx = tid & 31, ty = tid >> 5;   // ty 0..15
#pragma unroll
        for (int i = 0; i < 2; ++i)
            tile[ty + i * 16][tx] = f2bf(ldf(src, f32, (size_t)(y0 + ty + i * 16) * C + x0 + tx));
        __syncthreads();
#pragma unroll
        for (int i = 0; i < 2; ++i)
            dst[(size_t)(x0 + ty + i * 16) * R + y0 + tx] = tile[tx][ty + i * 16];
    } else {
        // ---- role A: x -> bf16 contiguous ----
        const int ab = bid - 3328;   // 0..1023
        const size_t total = (size_t)4096 * DIM_;
        size_t i = ((size_t)ab * 512 + tid) * 8;
        const size_t stride = (size_t)1024 * 512 * 8;
        if (f32) {
            for (; i < total; i += stride) {
                float4v a = *reinterpret_cast<const float4v*>((const float*)x + i);
                float4v b = *reinterpret_cast<const float4v*>((const float*)x + i + 4);
                uint4 o;
                o.x = pack2bf(a[0], a[1]); o.y = pack2bf(a[2], a[3]);
                o.z = pack2bf(b[0], b[1]); o.w = pack2bf(b[2], b[3]);
                *reinterpret_cast<uint4*>(Xb + i) = o;
            }
        } else {
            for (; i < total; i += stride)
                *reinterpret_cast<uint4*>(Xb + i) =
                    *reinterpret_cast<const uint4*>((const unsigned short*)x + i);
        }
    }
}

// ---------------------------------------------------------------------------
// 128x128 GEMM core (m97 structure): A [M][K] bf16 rm, Bt [N][K] bf16 rm.
// BK=32, 4 waves. Wave w: rows (w>>1)*64 + mi*16, cols (w&1)*64 + ni*16.
// 16 MFMA : 4 gll16 per wave-iter.
// ---------------------------------------------------------------------------
__device__ __forceinline__ void gemm128_core(const unsigned short* __restrict__ A,
                                             const unsigned short* __restrict__ Bt,
                                             int K, int row0, int col0,
                                             unsigned short* As, unsigned short* Bs,
                                             float4v acc[4][4]) {
    const int tid = threadIdx.x, lane = tid & 63, w = tid >> 6;
    const int l15 = lane & 15, q8 = (lane >> 4) * 8;
    const int mr0 = (w >> 1) * 64, nc0 = (w & 1) * 64;
    const int sr = lane >> 2, sc8 = (lane & 3) * 8;
    for (int k0 = 0; k0 < K; k0 += 32) {
        __syncthreads();
        gll16(&A [(size_t)(row0 + w * 32 + sr) * K + k0 + sc8],      &As[w * 1024]);
        gll16(&A [(size_t)(row0 + w * 32 + 16 + sr) * K + k0 + sc8], &As[w * 1024 + 512]);
        gll16(&Bt[(size_t)(col0 + w * 32 + sr) * K + k0 + sc8],      &Bs[w * 1024]);
        gll16(&Bt[(size_t)(col0 + w * 32 + 16 + sr) * K + k0 + sc8], &Bs[w * 1024 + 512]);
        __syncthreads();
        short8 a[4], b[4];
#pragma unroll
        for (int mi = 0; mi < 4; ++mi)
            a[mi] = *reinterpret_cast<const short8*>(&As[(mr0 + mi * 16 + l15) * 32 + q8]);
#pragma unroll
        for (int ni = 0; ni < 4; ++ni)
            b[ni] = *reinterpret_cast<const short8*>(&Bs[(nc0 + ni * 16 + l15) * 32 + q8]);
#pragma unroll
        for (int mi = 0; mi < 4; ++mi)
#pragma unroll
            for (int ni = 0; ni < 4; ++ni)
                acc[mi][ni] = __builtin_amdgcn_mfma_f32_16x16x32_bf16(a[mi], b[ni], acc[mi][ni], 0, 0, 0);
    }
}

// ---------------------------------------------------------------------------
// 2) QKV single dispatch: Wt [1536 n][1536 k]; mode = n>>9. grid (12,32).
//    V (mode 2) is written TRANSPOSED: vbuf[(bh*64+d)*2048 + j] (uint2 packed).
// ---------------------------------------------------------------------------
__global__ __launch_bounds__(256) void qkv_kernel(const unsigned short* __restrict__ Xb,
                                                  const unsigned short* __restrict__ Wt,
                                                  unsigned short* __restrict__ qbuf,
                                                  unsigned short* __restrict__ kbuf,
                                                  unsigned short* __restrict__ vbuf) {
    __shared__ __align__(16) unsigned short As[128 * 32];
    __shared__ __align__(16) unsigned short Bs[128 * 32];
    const int row0 = blockIdx.y * 128, col0 = blockIdx.x * 128;
    float4v acc[4][4];
#pragma unroll
    for (int mi = 0; mi < 4; ++mi)
#pragma unroll
        for (int ni = 0; ni < 4; ++ni) acc[mi][ni] = (float4v){0.f, 0.f, 0.f, 0.f};
    gemm128_core(Xb, Wt, DIM_, row0, col0, As, Bs, acc);
    const int lane = threadIdx.x & 63, w = threadIdx.x >> 6;
    const int l15 = lane & 15, quad = lane >> 4;
    const int mr0 = (w >> 1) * 64, nc0 = (w & 1) * 64;
#pragma unroll
    for (int mi = 0; mi < 4; ++mi)
#pragma unroll
        for (int ni = 0; ni < 4; ++ni) {
            int n = col0 + nc0 + ni * 16 + l15;
            int mode = n >> 9, nn = n & 511;
            int hh = nn >> 6, dd = nn & 63;
            int mb = row0 + mr0 + mi * 16 + quad * 4;   // 4 consecutive rows mb..mb+3
            int bb = mb >> 11, ii = mb & 2047;          // no 2048-crossing within r
            if (mode == 2) {
                union { unsigned short us[4]; uint2 u2; } pk;
                unsigned int p0 = cvtpk(acc[mi][ni][0], acc[mi][ni][1]);
                unsigned int p1 = cvtpk(acc[mi][ni][2], acc[mi][ni][3]);
                pk.u2 = (uint2){p0, p1};
                *reinterpret_cast<uint2*>(
                    &vbuf[((size_t)(bb * 8 + hh) * 64 + dd) * 2048 + ii]) = pk.u2;
            } else {
                unsigned short* Obuf = (mode == 0) ? qbuf : kbuf;
                float scale = (mode == 0) ? 0.125f : 1.0f;
#pragma unroll
                for (int r = 0; r < 4; ++r)
                    Obuf[((size_t)(bb * 8 + hh) * N_ + ii + r) * 64 + dd] = f2bf(acc[mi][ni][r] * scale);
            }
        }
}

// ---------------------------------------------------------------------------
// 3) MFMA flash attention, j-split z=3 (round-2 structure, stable 83.5 us).
// ---------------------------------------------------------------------------
#define SLD 72    // bf16 tile row stride (144B: 16B-aligned, conflict-benign)
#define RST 68    // ring row stride (136B: 8B-aligned for uint2 reads at m0)

__device__ __forceinline__ void stage64(const unsigned short* __restrict__ g,
                                        unsigned short* __restrict__ s, int tid) {
    // 64x64 bf16 tile, global row stride 64 -> LDS row stride SLD
    int r = tid >> 2, d0 = (tid & 3) * 16;
    const uint4* p = reinterpret_cast<const uint4*>(g + (size_t)r * 64 + d0);
    *reinterpret_cast<uint4*>(&s[r * SLD + d0])     = p[0];
    *reinterpret_cast<uint4*>(&s[r * SLD + d0 + 8]) = p[1];
}

__global__ __launch_bounds__(256) void attn_kernel(const unsigned int* __restrict__ flags,
                                                   const unsigned short* __restrict__ qb,
                                                   const unsigned short* __restrict__ kb,
                                                   const unsigned short* __restrict__ vb,   // [bh][d][j]
                                                   const unsigned short* __restrict__ posb,
                                                   const void* __restrict__ rcb,
                                                   const void* __restrict__ rpb,
                                                   unsigned short* __restrict__ Opart,
                                                   float* __restrict__ lpart) {
    __shared__ __align__(16) unsigned short Ks[64 * SLD];    // [j][d]
    __shared__ __align__(16) unsigned short Ps[64 * SLD];    // [t][d]
    __shared__ __align__(16) unsigned short Vt[64 * SLD];    // [d][j]
    __shared__ __align__(16) unsigned short Pp[64 * SLD];    // [i][j] (wave-private rows)
    __shared__ __align__(8)  unsigned short Rb[128 * RST];   // skewed rel ring [(t+m)&127][m]

    const int f32 = (int)flags[0];
    const int tid = threadIdx.x;
    const int it = blockIdx.x, bh = blockIdx.y, z = blockIdx.z;
    const int h = bh & 7;
    const int i0 = it * 64;
    const size_t qoff = (size_t)bh * N_ * 64;
    const size_t voff = (size_t)bh * 64 * 2048;
    const size_t poff = (size_t)h * 4096 * 64;
    const int lane = tid & 63, w = tid >> 6;
    const int l15 = lane & 15, quad = lane >> 4, q8 = quad * 8;
    const int m0 = w * 16 + quad * 4;
    const int sr = tid >> 2, sc = (tid & 3) * 16;

    // ---- Q fragments (contiguous 16B in global, once per block), biases folded ----
    short8 afc[2], afr[2];
#pragma unroll
    for (int kc = 0; kc < 2; ++kc) {
        uint4 qv = *reinterpret_cast<const uint4*>(
            &qb[qoff + (size_t)(i0 + w * 16 + l15) * 64 + kc * 32 + q8]);
        unsigned int uu[4] = {qv.x, qv.y, qv.z, qv.w};
        unsigned int cw[4], rw[4];
#pragma unroll
        for (int e = 0; e < 4; ++e) {
            int k = h * 64 + kc * 32 + q8 + 2 * e;
            float lo = __uint_as_float(uu[e] << 16);
            float hi = __uint_as_float(uu[e] & 0xffff0000u);
            cw[e] = pack2bf(lo + ldf(rcb, f32, k), hi + ldf(rcb, f32, k + 1));
            rw[e] = pack2bf(lo + ldf(rpb, f32, k), hi + ldf(rpb, f32, k + 1));
        }
        union { uint4 u; short8 s; } cv, rv2;
        cv.u  = (uint4){cw[0], cw[1], cw[2], cw[3]};
        rv2.u = (uint4){rw[0], rw[1], rw[2], rw[3]};
        afc[kc] = cv.s;
        afr[kc] = rv2.s;
    }

    float4v Oa[4];
#pragma unroll
    for (int nb = 0; nb < 4; ++nb) Oa[nb] = (float4v){0.f, 0.f, 0.f, 0.f};
    float lsum[4] = {0.f, 0.f, 0.f, 0.f};

    const int base0 = 1984 - i0;
    const int t0 = z * 11, t1 = (z == 2) ? 32 : (t0 + 11);
    const int cs0 = base0 + t0 * 64;

    // ---- prologue 1: seed ring from pos chunk cs0 ----
    stage64(&posb[poff + (size_t)cs0 * 64], Ps, tid);
    __syncthreads();
    {
        float4v R[4];
#pragma unroll
        for (int nb = 0; nb < 4; ++nb) R[nb] = (float4v){0.f, 0.f, 0.f, 0.f};
        __builtin_amdgcn_s_setprio(1);
#pragma unroll
        for (int kc = 0; kc < 2; ++kc)
#pragma unroll
            for (int nb = 0; nb < 4; ++nb) {
                short8 pb = *reinterpret_cast<const short8*>(&Ps[(nb * 16 + l15) * SLD + kc * 32 + q8]);
                R[nb] = __builtin_amdgcn_mfma_f32_16x16x32_bf16(afr[kc], pb, R[nb], 0, 0, 0);
            }
        __builtin_amdgcn_s_setprio(0);
#pragma unroll
        for (int nb = 0; nb < 4; ++nb) {
            int ta = cs0 + nb * 16 + l15;
            unsigned int pk0 = cvtpk(R[nb][0], R[nb][1]);
            unsigned int pk1 = cvtpk(R[nb][2], R[nb][3]);
            Rb[(size_t)((ta + m0 + 0) & 127) * RST + m0 + 0] = (unsigned short)pk0;
            Rb[(size_t)((ta + m0 + 1) & 127) * RST + m0 + 1] = (unsigned short)(pk0 >> 16);
            Rb[(size_t)((ta + m0 + 2) & 127) * RST + m0 + 2] = (unsigned short)pk1;
            Rb[(size_t)((ta + m0 + 3) & 127) * RST + m0 + 3] = (unsigned short)(pk1 >> 16);
        }
    }
    __syncthreads();   // all waves done reading Ps before restage

    // ---- prologue 2: stage tile t0 (K, pos cs0+64, V-transposed) ----
    stage64(&kb[qoff + (size_t)(t0 * 64) * 64], Ks, tid);
    stage64(&posb[poff + (size_t)(cs0 + 64) * 64], Ps, tid);
    {
        const unsigned short* gv = &vb[voff + (size_t)sr * 2048 + t0 * 64 + sc];
        *reinterpret_cast<uint4*>(&Vt[sr * SLD + sc])     = *reinterpret_cast<const uint4*>(gv);
        *reinterpret_cast<uint4*>(&Vt[sr * SLD + sc + 8]) = *reinterpret_cast<const uint4*>(gv + 8);
    }
    __syncthreads();

    for (int jt = t0; jt < t1; ++jt) {
        const int j0 = jt * 64, basej = base0 + j0;
        const bool hasn = (jt + 1 < t1);

        // ---- issue next-tile global loads, then FENCE so they can't sink ----
        uint4 kr0, kr1, pr0, pr1, vr0, vr1;
        if (hasn) {
            const unsigned short* gk = &kb[qoff + (size_t)(j0 + 64 + sr) * 64 + sc];
            kr0 = *reinterpret_cast<const uint4*>(gk);
            kr1 = *reinterpret_cast<const uint4*>(gk + 8);
            const unsigned short* gp = &posb[poff + (size_t)(basej + 128 + sr) * 64 + sc];
            pr0 = *reinterpret_cast<const uint4*>(gp);
            pr1 = *reinterpret_cast<const uint4*>(gp + 8);
            const unsigned short* gv = &vb[voff + (size_t)sr * 2048 + j0 + 64 + sc];
            vr0 = *reinterpret_cast<const uint4*>(gv);
            vr1 = *reinterpret_cast<const uint4*>(gv + 8);
            __builtin_amdgcn_sched_barrier(0);
        }

        // ---- rel GEMM from Ps -> 64 new ring cols at basej+64 (skewed store) ----
        {
            float4v R[4];
#pragma unroll
            for (int nb = 0; nb < 4; ++nb) R[nb] = (float4v){0.f, 0.f, 0.f, 0.f};
            __builtin_amdgcn_s_setprio(1);
#pragma unroll
            for (int kc = 0; kc < 2; ++kc)
#pragma unroll
                for (int nb = 0; nb < 4; ++nb) {
                    short8 pb = *reinterpret_cast<const short8*>(&Ps[(nb * 16 + l15) * SLD + kc * 32 + q8]);
                    R[nb] = __builtin_amdgcn_mfma_f32_16x16x32_bf16(afr[kc], pb, R[nb], 0, 0, 0);
                }
            __builtin_amdgcn_s_setprio(0);
            const int tb = basej + 64;
#pragma unroll
            for (int nb = 0; nb < 4; ++nb) {
                int ta = tb + nb * 16 + l15;
                unsigned int pk0 = cvtpk(R[nb][0], R[nb][1]);
                unsigned int pk1 = cvtpk(R[nb][2], R[nb][3]);
                Rb[(size_t)((ta + m0 + 0) & 127) * RST + m0 + 0] = (unsigned short)pk0;
                Rb[(size_t)((ta + m0 + 1) & 127) * RST + m0 + 1] = (unsigned short)(pk0 >> 16);
                Rb[(size_t)((ta + m0 + 2) & 127) * RST + m0 + 2] = (unsigned short)pk1;
                Rb[(size_t)((ta + m0 + 3) & 127) * RST + m0 + 3] = (unsigned short)(pk1 >> 16);
            }
        }

        // ---- content GEMM: Sacc = Qc · K^T (frags from LDS) ----
        float4v Sacc[4];
#pragma unroll
        for (int nb = 0; nb < 4; ++nb) Sacc[nb] = (float4v){0.f, 0.f, 0.f, 0.f};
        __builtin_amdgcn_s_setprio(1);
#pragma unroll
        for (int kc = 0; kc < 2; ++kc)
#pragma unroll
            for (int nb = 0; nb < 4; ++nb) {
                short8 kf = *reinterpret_cast<const short8*>(&Ks[(nb * 16 + l15) * SLD + kc * 32 + q8]);
                Sacc[nb] = __builtin_amdgcn_mfma_f32_16x16x32_bf16(afc[kc], kf, Sacc[nb], 0, 0, 0);
            }
        __builtin_amdgcn_s_setprio(0);

        // ---- vector gather of rel diagonal, exp, pack P via cvt_pk ----
        float pv4[4][4];
#pragma unroll
        for (int nb = 0; nb < 4; ++nb) {
            const int jl = nb * 16 + l15;
            const int row = (basej + 63 + jl) & 127;
            union { uint2 u2; unsigned short us[4]; } rv;
            rv.u2 = *reinterpret_cast<const uint2*>(&Rb[(size_t)row * RST + m0]);
#pragma unroll
            for (int r = 0; r < 4; ++r) {
                float p = __expf(Sacc[nb][r] + bf2f(rv.us[r]));
                pv4[nb][r] = p;
                lsum[r] += p;
            }
        }
#pragma unroll
        for (int r = 0; r < 4; ++r) {
            unsigned short* prow = &Pp[(m0 + r) * SLD + l15];
#pragma unroll
            for (int np = 0; np < 2; ++np) {
                unsigned int pk = cvtpk(pv4[2 * np][r], pv4[2 * np + 1][r]);
                prow[(2 * np) * 16]     = (unsigned short)pk;
                prow[(2 * np + 1) * 16] = (unsigned short)(pk >> 16);
            }
        }

        // ---- PV GEMM: Oa += P · V (Pp rows wave-private) ----
        __builtin_amdgcn_s_setprio(1);
#pragma unroll
        for (int kc = 0; kc < 2; ++kc) {
            short8 pf = *reinterpret_cast<const short8*>(&Pp[(w * 16 + l15) * SLD + kc * 32 + q8]);
#pragma unroll
            for (int nb = 0; nb < 4; ++nb) {
                short8 vf = *reinterpret_cast<const short8*>(&Vt[(nb * 16 + l15) * SLD + kc * 32 + q8]);
                Oa[nb] = __builtin_amdgcn_mfma_f32_16x16x32_bf16(pf, vf, Oa[nb], 0, 0, 0);
            }
        }
        __builtin_amdgcn_s_setprio(0);

        // ---- drain prefetch, publish next tile to LDS ----
        if (hasn) {
            __syncthreads();   // all waves done reading Ks/Ps/Vt
            *reinterpret_cast<uint4*>(&Ks[sr * SLD + sc])     = kr0;
            *reinterpret_cast<uint4*>(&Ks[sr * SLD + sc + 8]) = kr1;
            *reinterpret_cast<uint4*>(&Ps[sr * SLD + sc])     = pr0;
            *reinterpret_cast<uint4*>(&Ps[sr * SLD + sc + 8]) = pr1;
            *reinterpret_cast<uint4*>(&Vt[sr * SLD + sc])     = vr0;
            *reinterpret_cast<uint4*>(&Vt[sr * SLD + sc + 8]) = vr1;
            __syncthreads();
        }
    }

    // ---- reduce row sums, write partials (coalesced via Pp round-trip) ----
#pragma unroll
    for (int r = 0; r < 4; ++r)
#pragma unroll
        for (int off = 1; off < 16; off <<= 1) lsum[r] += __shfl_xor(lsum[r], off);
    const size_t pslot = (size_t)(z * 16 + bh) * 32 + it;
    const size_t obase = pslot * 4096;
#pragma unroll
    for (int nb = 0; nb < 4; ++nb) {
        unsigned int pk0 = cvtpk(Oa[nb][0], Oa[nb][1]);
        unsigned int pk1 = cvtpk(Oa[nb][2], Oa[nb][3]);
        unsigned short* prow = &Pp[m0 * SLD + nb * 16 + l15];
        prow[0 * SLD] = (unsigned short)pk0;
        prow[1 * SLD] = (unsigned short)(pk0 >> 16);
        prow[2 * SLD] = (unsigned short)pk1;
        prow[3 * SLD] = (unsigned short)(pk1 >> 16);
    }
    {
        const int rr2 = w * 16 + (lane >> 2), cc2 = (lane & 3) * 16;
        uint4 o0 = *reinterpret_cast<const uint4*>(&Pp[rr2 * SLD + cc2]);
        uint4 o1 = *reinterpret_cast<const uint4*>(&Pp[rr2 * SLD + cc2 + 8]);
        *reinterpret_cast<uint4*>(&Opart[obase + (size_t)rr2 * 64 + cc2])     = o0;
        *reinterpret_cast<uint4*>(&Opart[obase + (size_t)rr2 * 64 + cc2 + 8]) = o1;
    }
    if (l15 == 0) {
#pragma unroll
        for (int r = 0; r < 4; ++r) lpart[pslot * 64 + m0 + r] = lsum[r];
    }
}

// ---------------------------------------------------------------------------
// 4) Combine j-split partials, normalize, write ao[b][i][h*64+d] bf16.
// ---------------------------------------------------------------------------
__global__ __launch_bounds__(256) void combine_kernel(const unsigned short* __restrict__ Opart,
                                                      const float* __restrict__ lpart,
                                                      unsigned short* __restrict__ ao) {
    const int it = blockIdx.x, bh = blockIdx.y;
    const int h = bh & 7, b = bh >> 3, i0 = it * 64;
    const int tid = threadIdx.x;
    const int row = tid >> 2, c0 = (tid & 3) * 16;
    float o[16];
#pragma unroll
    for (int e = 0; e < 16; ++e) o[e] = 0.f;
    float l = 0.f;
#pragma unroll
    for (int z = 0; z < 3; ++z) {
        const size_t pslot = (size_t)(z * 16 + bh) * 32 + it;
        const size_t ob = pslot * 4096 + (size_t)row * 64 + c0;
        uint4 a = *reinterpret_cast<const uint4*>(&Opart[ob]);
        uint4 b4 = *reinterpret_cast<const uint4*>(&Opart[ob + 8]);
        unsigned int uu[8] = {a.x, a.y, a.z, a.w, b4.x, b4.y, b4.z, b4.w};
#pragma unroll
        for (int e = 0; e < 8; ++e) {
            o[2 * e]     += __uint_as_float(uu[e] << 16);
            o[2 * e + 1] += __uint_as_float(uu[e] & 0xffff0000u);
        }
        l += lpart[pslot * 64 + row];
    }
    float inv = 1.0f / l;
    unsigned int ou[8];
#pragma unroll
    for (int e = 0; e < 8; ++e) ou[e] = pack2bf(o[2 * e] * inv, o[2 * e + 1] * inv);
    unsigned short* dst = &ao[((size_t)b * N_ + i0 + row) * 512 + h * 64 + c0];
    *reinterpret_cast<uint4*>(dst)     = (uint4){ou[0], ou[1], ou[2], ou[3]};
    *reinterpret_cast<uint4*>(dst + 8) = (uint4){ou[4], ou[5], ou[6], ou[7]};
}

// ---------------------------------------------------------------------------
// 5) out = ao @ Wo + bo (output dtype per flag). grid (12, 32).
// ---------------------------------------------------------------------------
__global__ __launch_bounds__(256) void outproj_kernel(const unsigned int* __restrict__ flags,
                                                      const unsigned short* __restrict__ AO,
                                                      const unsigned short* __restrict__ Wot,
                                                      const void* __restrict__ bo,
                                                      void* __restrict__ out) {
    __shared__ __align__(16) unsigned short As[128 * 32];
    __shared__ __align__(16) unsigned short Bs[128 * 32];
    const int f32 = (int)flags[0];
    const int row0 = blockIdx.y * 128, col0 = blockIdx.x * 128;
    float4v acc[4][4];
#pragma unroll
    for (int mi = 0; mi < 4; ++mi)
#pragma unroll
        for (int ni = 0; ni < 4; ++ni) acc[mi][ni] = (float4v){0.f, 0.f, 0.f, 0.f};
    gemm128_core(AO, Wot, 512, row0, col0, As, Bs, acc);
    const int lane = threadIdx.x & 63, w = threadIdx.x >> 6;
    const int l15 = lane & 15, quad = lane >> 4;
    const int mr0 = (w >> 1) * 64, nc0 = (w & 1) * 64;
#pragma unroll
    for (int mi = 0; mi < 4; ++mi)
#pragma unroll
        for (int ni = 0; ni < 4; ++ni) {
            int n = col0 + nc0 + ni * 16 + l15;
            float bias = ldf(bo, f32, n);
#pragma unroll
            for (int r = 0; r < 4; ++r) {
                int m = row0 + mr0 + mi * 16 + quad * 4 + r;
                float v = acc[mi][ni][r] + bias;
                if (f32) ((float*)out)[(size_t)m * DIM_ + n] = v;
                else     ((unsigned short*)out)[(size_t)m * DIM_ + n] = f2bf(v);
            }
        }
}

// ---------------------------------------------------------------------------
extern "C" void kernel_launch(void* const* d_in, const int* in_sizes, int n_in,
                              void* d_out, int out_size, void* d_ws, size_t ws_size,
                              hipStream_t stream) {
    const void* x    = d_in[0];
    const void* Wq   = d_in[1];
    const void* Wk   = d_in[2];
    const void* Wv   = d_in[3];
    const void* Wo   = d_in[4];
    const void* bo   = d_in[5];
    const void* Wrel = d_in[6];
    const void* rcb  = d_in[7];
    const void* rpb  = d_in[8];

    char* ws = (char*)d_ws;
    unsigned int*   flags = (unsigned int*)(ws + OFF_FLAG);
    unsigned short* posb  = (unsigned short*)(ws + OFF_POS);
    unsigned short* qbuf  = (unsigned short*)(ws + OFF_Q);
    unsigned short* kbuf  = (unsigned short*)(ws + OFF_K);
    unsigned short* vbuf  = (unsigned short*)(ws + OFF_V);
    unsigned short* Wot   = (unsigned short*)(ws + OFF_WOT);
    unsigned short* Xb    = (unsigned short*)(ws + OFF_XB);
    unsigned short* ao    = (unsigned short*)(ws + OFF_AO);
    unsigned short* Opart = (unsigned short*)(ws + OFF_OP);
    float*          lpart = (float*)(ws + OFF_LP);
    unsigned short* Wt    = (unsigned short*)(ws + OFF_WT);

    // Host-side constants (capture-time only; pure functions of problem consts)
    PosConsts pc;
    double maxp = 0.0;
    for (int g = 0; g < NB_; ++g) {
        double mean = 64.0 * (g + 1);
        double conc = (mean / 32.0) * (mean / 32.0);
        double rate = mean / 1024.0;
        double lgc  = std::lgamma(conc);
        double clr  = conc * std::log(rate);
        for (int ad = 1; ad < N_; ++ad) {
            double lp = (conc - 1.0) * std::log((double)ad) - rate * (double)ad - lgc + clr;
            double p  = std::exp(lp) + 1e-8;
            if (p > maxp) maxp = p;
        }
        pc.c1[g]    = (float)(conc - 1.0);   // exact small integer
        pc.rateF[g] = (float)rate;           // exact dyadic
        pc.gc[g]    = -lgc + clr;
    }
    pc.maxp = maxp;
    const double max_range = std::log((double)N_) / std::log(2.0);   // 11.0
    for (int f = 0; f < 32; ++f) {
        double t = 3.0 + (double)f * (max_range - 3.0) / 31.0;
        pc.inv_hl[f] = (float)std::exp2(-t);
        int e = f + 1;   // central-mask exponent for class index f
        pc.widthI[f] = (e >= 12) ? 0x7FFFFFFF : ((1 << e) - 1);   // adI<=2047: clamp exact
    }

    prep_kernel<<<dim3(4352), dim3(512), 0, stream>>>(pc, x, Wq, Wk, Wv, Wo, Wrel,
                                                      flags, Xb, Wt, Wot, posb);
    qkv_kernel<<<dim3(12, 32), dim3(256), 0, stream>>>(Xb, Wt, qbuf, kbuf, vbuf);
    attn_kernel<<<dim3(32, 16, 3), dim3(256), 0, stream>>>(flags, qbuf, kbuf, vbuf, posb, rcb, rpb, Opart, lpart);
    combine_kernel<<<dim3(32, 16), dim3(256), 0, stream>>>(Opart, lpart, ao);
    outproj_kernel<<<dim3(12, 32), dim3(256), 0, stream>>>(flags, ao, Wot, bo, d_out);
}

// Round 6
// 259.576 us; speedup vs baseline: 1.2970x; 1.0149x over previous
//
#include <hip/hip_runtime.h>
#include <stdint.h>
#include <cmath>

// Problem constants
#define B_    2
#define N_    2048
#define DIM_  1536
#define H_    8
#define NPOS  (2*N_ - 1)   // 4095 (posb padded to 4096 rows; pad row never gathered)
#define NB_   32           // basis per class (192/6)

typedef __attribute__((ext_vector_type(8))) short short8;
typedef __attribute__((ext_vector_type(4))) float float4v;

// Host-precomputed positional-basis constants (capture-time only)
struct PosConsts {
    float  inv_hl[32];   // 2^-t, t = 3 + f*(11-3)/31
    int    widthI[32];   // 2^(i+1)-1 clamped (central-mask widths)
    float  c1[32];       // conc-1 (exact small integers)
    float  rateF[32];    // rate = (g+1)/16 (exact dyadic)
    double gc[32];       // -lgamma(conc) + conc*log(rate)
    double maxp;
};

__device__ __forceinline__ float bf2f(unsigned short u) {
    return __uint_as_float(((unsigned int)u) << 16);
}
__device__ __forceinline__ unsigned short f2bf(float f) {
    unsigned int u = __float_as_uint(f);
    u += 0x7FFFu + ((u >> 16) & 1u);   // RNE
    return (unsigned short)(u >> 16);
}
// HW packed f32x2 -> bf16x2 (RNE, identical to f2bf pair; 1 VALU op vs ~8)
__device__ __forceinline__ unsigned int cvtpk(float lo, float hi) {
    unsigned int r;
    asm("v_cvt_pk_bf16_f32 %0, %1, %2" : "=v"(r) : "v"(lo), "v"(hi));
    return r;
}
__device__ __forceinline__ unsigned int pack2bf(float lo, float hi) {
    return cvtpk(lo, hi);
}
__device__ __forceinline__ float ldf(const void* p, int isF32, size_t idx) {
    return isF32 ? ((const float*)p)[idx] : bf2f(((const unsigned short*)p)[idx]);
}
// async global->LDS, 16B per lane; LDS dest = wave-uniform base (+lane*16 by HW);
// global src is per-lane.
__device__ __forceinline__ void gll16(const unsigned short* g, unsigned short* l) {
    __builtin_amdgcn_global_load_lds(
        (const __attribute__((address_space(1))) unsigned int*)g,
        (__attribute__((address_space(3))) unsigned int*)l, 16, 0, 0);
}

// ---------------------------------------------------------------------------
// Workspace layout (bytes) — unchanged (35.7 MB).
// ---------------------------------------------------------------------------
constexpr size_t OFF_FLAG = 0;                                   // uint
constexpr size_t OFF_POS  = 256;                                 // bf16 [8][4096][64] (SWIZZLED cols)
constexpr size_t OFF_Q    = OFF_POS + (size_t)H_*4096*64*2;
constexpr size_t OFF_K    = OFF_Q   + (size_t)B_*H_*N_*64*2;     // SWIZZLED cols
constexpr size_t OFF_V    = OFF_K   + (size_t)B_*H_*N_*64*2;     // bf16 [b*h][64 d][2048 j] transposed, SWIZZLED j
constexpr size_t OFF_WOT  = OFF_V   + (size_t)B_*H_*N_*64*2;     // bf16 [1536][512]
constexpr size_t OFF_XB   = OFF_WOT + (size_t)DIM_*512*2;        // bf16 [4096][1536]
constexpr size_t OFF_AO   = OFF_XB;                              // bf16 [4096][512] (alias head of XB)
constexpr size_t OFF_OP   = OFF_AO + (size_t)4096*512*2;         // bf16 [3][16][32][64][64]
constexpr size_t OFF_LP   = OFF_OP + (size_t)3*16*32*4096*2;     // f32  [3][16][32][64]
constexpr size_t OFF_WT   = OFF_XB + (size_t)4096*DIM_*2;        // bf16 [3][512][1536]
static_assert(OFF_LP + (size_t)3*16*32*64*4 <= OFF_WT + (size_t)3*512*DIM_*2, "ws overflow");

// ---------------------------------------------------------------------------
// 1) prep_kernel: fused detect + posproj + cvtw + cvtx (one dispatch).
//    Roles: [0,256) posproj; [256,3328) cvtw; [3328,4352) cvtx.
//    Round-6: posb written with the attn LDS swizzle (col ^= ((j&7)<<3)) so
//    attn can stage it with global_load_lds into linear LDS (rule #21 pattern).
// ---------------------------------------------------------------------------
__global__ __launch_bounds__(512) void prep_kernel(PosConsts pc,
                                                   const void* __restrict__ x,
                                                   const void* __restrict__ Wq, const void* __restrict__ Wk,
                                                   const void* __restrict__ Wv, const void* __restrict__ Wo,
                                                   const void* __restrict__ Wrel,
                                                   unsigned int* __restrict__ flags,
                                                   unsigned short* __restrict__ Xb,
                                                   unsigned short* __restrict__ Wt,
                                                   unsigned short* __restrict__ Wot,
                                                   unsigned short* __restrict__ posb) {
    __shared__ __align__(16) char smraw[16 * 192 * 4];   // 12288B: cnt / tile / eb overlay
    const int tid = threadIdx.x;
    const int bid = blockIdx.x;

    // ---- self-detect dtype (all blocks; ~1 cache line, L2 broadcast) ----
    int* cnt = (int*)smraw;
    int ok = 0;
    if (tid < 256) {
        unsigned short u = ((const unsigned short*)x)[2 * tid];
        int e = (u >> 7) & 0xFF;
        ok = (u == 0) || (e >= 95 && e <= 140);
    }
    cnt[tid] = ok;
    __syncthreads();
    for (int s = 256; s > 0; s >>= 1) {
        if (tid < s) cnt[tid] += cnt[tid + s];
        __syncthreads();
    }
    const int f32 = !(cnt[0] >= 192);
    __syncthreads();   // done with cnt before smem reuse
    if (bid == 0 && tid == 0) flags[0] = (unsigned int)f32;

    if (bid < 256) {
        // ---- role C: positional basis + projection (16 rows/block, FIRST) ----
        float* eb = (float*)smraw;    // [16][192]
        const int j0 = bid * 16;
        const int c  = tid;   // 0..511
        for (int u = c; u < 16 * 96; u += 512) {
            int rr = u / 96, f = u - rr * 96;
            int j = j0 + rr;
            float v = 0.f, sg = 0.f;
            if (j < NPOS) {
                int dd  = j - (N_ - 1);
                int adI = dd < 0 ? -dd : dd;
                float val;
                if (f < 32) {
                    val = exp2f(-(float)adI * pc.inv_hl[f]);
                } else if (f < 64) {
                    val = (adI < pc.widthI[f - 32]) ? 1.f : 0.f;
                } else {
                    int g = f - 64;
                    if (adI == 0) {
                        val = (float)(1e-8 / pc.maxp);
                    } else {
                        double lp = (double)pc.c1[g] * log((double)adI)
                                  - (double)pc.rateF[g] * (double)adI + pc.gc[g];
                        double p = (double)expf((float)lp) + 1e-8;
                        val = (float)(p / pc.maxp);
                    }
                }
                v  = val;
                sg = (dd > 0) ? 1.f : ((dd < 0) ? -1.f : 0.f);
            }
            eb[rr * 192 + f]      = v;
            eb[rr * 192 + 96 + f] = sg * v;
        }
        __syncthreads();
        float acc[16];
#pragma unroll
        for (int rr = 0; rr < 16; ++rr) acc[rr] = 0.f;
        for (int k = 0; k < 192; k += 4) {
            float w0 = ldf(Wrel, f32, (size_t)(k + 0) * 512 + c);
            float w1 = ldf(Wrel, f32, (size_t)(k + 1) * 512 + c);
            float w2 = ldf(Wrel, f32, (size_t)(k + 2) * 512 + c);
            float w3 = ldf(Wrel, f32, (size_t)(k + 3) * 512 + c);
#pragma unroll
            for (int rr = 0; rr < 16; ++rr) {
                float4v e = *reinterpret_cast<const float4v*>(&eb[rr * 192 + k]);
                acc[rr] += e[0] * w0;
                acc[rr] += e[1] * w1;
                acc[rr] += e[2] * w2;
                acc[rr] += e[3] * w3;
            }
        }
        int h = c >> 6, dcol = c & 63;
#pragma unroll
        for (int rr = 0; rr < 16; ++rr) {
            int j = j0 + rr;
            if (j < NPOS)
                posb[((size_t)h * 4096 + j) * 64 + (dcol ^ ((j & 7) << 3))] = f2bf(acc[rr]);
        }
    } else if (bid < 3328) {
        // ---- role B: weight transposes -> bf16 [N][K] ----
        unsigned short (*tile)[33] = (unsigned short(*)[33])smraw;
        const int idx = bid - 256;
        const int z = idx / 768, rem = idx % 768;
        const int bx = rem & 15, by = rem >> 4;
        const void* src = z == 0 ? Wq : (z == 1 ? Wk : (z == 2 ? Wv : Wo));
        unsigned short* dst = (z < 3) ? (Wt + (size_t)z * 512 * DIM_) : Wot;
        const int R = (z < 3) ? DIM_ : 512;
        const int C = (z < 3) ? 512 : DIM_;
        const int x0 = ((z < 3) ? bx : by) * 32;
        const int y0 = ((z < 3) ? by : bx) * 32;
        const int tx = tid & 31, ty = tid >> 5;   // ty 0..15
#pragma unroll
        for (int i = 0; i < 2; ++i)
            tile[ty + i * 16][tx] = f2bf(ldf(src, f32, (size_t)(y0 + ty + i * 16) * C + x0 + tx));
        __syncthreads();
#pragma unroll
        for (int i = 0; i < 2; ++i)
            dst[(size_t)(x0 + ty + i * 16) * R + y0 + tx] = tile[tx][ty + i * 16];
    } else {
        // ---- role A: x -> bf16 contiguous ----
        const int ab = bid - 3328;   // 0..1023
        const size_t total = (size_t)4096 * DIM_;
        size_t i = ((size_t)ab * 512 + tid) * 8;
        const size_t stride = (size_t)1024 * 512 * 8;
        if (f32) {
            for (; i < total; i += stride) {
                float4v a = *reinterpret_cast<const float4v*>((const float*)x + i);
                float4v b = *reinterpret_cast<const float4v*>((const float*)x + i + 4);
                uint4 o;
                o.x = pack2bf(a[0], a[1]); o.y = pack2bf(a[2], a[3]);
                o.z = pack2bf(b[0], b[1]); o.w = pack2bf(b[2], b[3]);
                *reinterpret_cast<uint4*>(Xb + i) = o;
            }
        } else {
            for (; i < total; i += stride)
                *reinterpret_cast<uint4*>(Xb + i) =
                    *reinterpret_cast<const uint4*>((const unsigned short*)x + i);
        }
    }
}

// ---------------------------------------------------------------------------
// 128x128 GEMM core (m97 structure): A [M][K] bf16 rm, Bt [N][K] bf16 rm.
// ---------------------------------------------------------------------------
__device__ __forceinline__ void gemm128_core(const unsigned short* __restrict__ A,
                                             const unsigned short* __restrict__ Bt,
                                             int K, int row0, int col0,
                                             unsigned short* As, unsigned short* Bs,
                                             float4v acc[4][4]) {
    const int tid = threadIdx.x, lane = tid & 63, w = tid >> 6;
    const int l15 = lane & 15, q8 = (lane >> 4) * 8;
    const int mr0 = (w >> 1) * 64, nc0 = (w & 1) * 64;
    const int sr = lane >> 2, sc8 = (lane & 3) * 8;
    for (int k0 = 0; k0 < K; k0 += 32) {
        __syncthreads();
        gll16(&A [(size_t)(row0 + w * 32 + sr) * K + k0 + sc8],      &As[w * 1024]);
        gll16(&A [(size_t)(row0 + w * 32 + 16 + sr) * K + k0 + sc8], &As[w * 1024 + 512]);
        gll16(&Bt[(size_t)(col0 + w * 32 + sr) * K + k0 + sc8],      &Bs[w * 1024]);
        gll16(&Bt[(size_t)(col0 + w * 32 + 16 + sr) * K + k0 + sc8], &Bs[w * 1024 + 512]);
        __syncthreads();
        short8 a[4], b[4];
#pragma unroll
        for (int mi = 0; mi < 4; ++mi)
            a[mi] = *reinterpret_cast<const short8*>(&As[(mr0 + mi * 16 + l15) * 32 + q8]);
#pragma unroll
        for (int ni = 0; ni < 4; ++ni)
            b[ni] = *reinterpret_cast<const short8*>(&Bs[(nc0 + ni * 16 + l15) * 32 + q8]);
#pragma unroll
        for (int mi = 0; mi < 4; ++mi)
#pragma unroll
            for (int ni = 0; ni < 4; ++ni)
                acc[mi][ni] = __builtin_amdgcn_mfma_f32_16x16x32_bf16(a[mi], b[ni], acc[mi][ni], 0, 0, 0);
    }
}

// ---------------------------------------------------------------------------
// 2) QKV single dispatch. Round-6: K (mode 1) and V (mode 2) written with the
//    attn LDS swizzle pre-applied in GLOBAL memory (rule #21: linear-LDS dest
//    for global_load_lds + pre-swizzled source). Q (mode 0) unswizzled (read
//    directly per-lane by attn).
//      kbuf: col dd -> dd ^ ((token&7)<<3)
//      vbuf: [bh][d][j]; j-within-64 -> ^ ((d&7)<<3)  (uint2 stays intact,
//            XOR touches bits 3-5 only; base j multiple of 4)
// ---------------------------------------------------------------------------
__global__ __launch_bounds__(256) void qkv_kernel(const unsigned short* __restrict__ Xb,
                                                  const unsigned short* __restrict__ Wt,
                                                  unsigned short* __restrict__ qbuf,
                                                  unsigned short* __restrict__ kbuf,
                                                  unsigned short* __restrict__ vbuf) {
    __shared__ __align__(16) unsigned short As[128 * 32];
    __shared__ __align__(16) unsigned short Bs[128 * 32];
    const int row0 = blockIdx.y * 128, col0 = blockIdx.x * 128;
    float4v acc[4][4];
#pragma unroll
    for (int mi = 0; mi < 4; ++mi)
#pragma unroll
        for (int ni = 0; ni < 4; ++ni) acc[mi][ni] = (float4v){0.f, 0.f, 0.f, 0.f};
    gemm128_core(Xb, Wt, DIM_, row0, col0, As, Bs, acc);
    const int lane = threadIdx.x & 63, w = threadIdx.x >> 6;
    const int l15 = lane & 15, quad = lane >> 4;
    const int mr0 = (w >> 1) * 64, nc0 = (w & 1) * 64;
#pragma unroll
    for (int mi = 0; mi < 4; ++mi)
#pragma unroll
        for (int ni = 0; ni < 4; ++ni) {
            int n = col0 + nc0 + ni * 16 + l15;
            int mode = n >> 9, nn = n & 511;
            int hh = nn >> 6, dd = nn & 63;
            int mb = row0 + mr0 + mi * 16 + quad * 4;   // 4 consecutive rows mb..mb+3
            int bb = mb >> 11, ii = mb & 2047;          // no 2048-crossing within r
            if (mode == 2) {
                union { unsigned short us[4]; uint2 u2; } pk;
                unsigned int p0 = cvtpk(acc[mi][ni][0], acc[mi][ni][1]);
                unsigned int p1 = cvtpk(acc[mi][ni][2], acc[mi][ni][3]);
                pk.u2 = (uint2){p0, p1};
                int jb = (ii & ~63) | ((ii & 63) ^ ((dd & 7) << 3));
                *reinterpret_cast<uint2*>(
                    &vbuf[((size_t)(bb * 8 + hh) * 64 + dd) * 2048 + jb]) = pk.u2;
            } else if (mode == 1) {
#pragma unroll
                for (int r = 0; r < 4; ++r) {
                    int tok = ii + r;
                    kbuf[((size_t)(bb * 8 + hh) * N_ + tok) * 64 + (dd ^ ((tok & 7) << 3))]
                        = f2bf(acc[mi][ni][r]);
                }
            } else {
#pragma unroll
                for (int r = 0; r < 4; ++r)
                    qbuf[((size_t)(bb * 8 + hh) * N_ + ii + r) * 64 + dd] = f2bf(acc[mi][ni][r] * 0.125f);
            }
        }
}

// ---------------------------------------------------------------------------
// 3) MFMA flash attention, j-split z=3.
//    Round-6 restructure (T3-lite): double-buffered Ks/Ps/Vt staged via
//    global_load_lds (linear LDS, pre-swizzled global). ONE barrier per tile:
//      loop u: { syncthreads (drains gll16 for buf[p]); issue gll16 tile u+1
//                -> buf[p^1]; compute from buf[p] }
//    LDS 75776 B -> 2 blocks/CU (was 3; trade for barrier halving + async).
//    Fragment reads use col ^ ((l15&7)<<3) — bank-uniform (8 lanes/granule).
// ---------------------------------------------------------------------------
#define SLD 72    // Pp row stride (VALU-written buffer keeps padding)
#define RST 68    // ring row stride (136B: 8B-aligned for uint2 reads at m0)

__device__ __forceinline__ void stage_lin(const unsigned short* __restrict__ g,
                                          unsigned short* s, int tid, int w) {
    // 8192B contiguous global tile -> 8192B linear LDS (2 calls x 4096B)
    gll16(g + tid * 8,        s + w * 512);
    gll16(g + 2048 + tid * 8, s + 2048 + w * 512);
}
__device__ __forceinline__ void stage_vt(const unsigned short* __restrict__ vbase,
                                         int jbase, unsigned short* s, int tid, int w) {
    // V tile: 64 rows (d) stride 2048 in global -> 64x64 linear LDS
    {
        int L = tid * 8;        int d = L >> 6, cb = L & 63;
        gll16(vbase + (size_t)d * 2048 + jbase + cb, s + w * 512);
    }
    {
        int L = 2048 + tid * 8; int d = L >> 6, cb = L & 63;
        gll16(vbase + (size_t)d * 2048 + jbase + cb, s + 2048 + w * 512);
    }
}

__global__ __launch_bounds__(256) void attn_kernel(const unsigned int* __restrict__ flags,
                                                   const unsigned short* __restrict__ qb,
                                                   const unsigned short* __restrict__ kb,   // swizzled
                                                   const unsigned short* __restrict__ vb,   // [bh][d][j] swizzled
                                                   const unsigned short* __restrict__ posb, // swizzled
                                                   const void* __restrict__ rcb,
                                                   const void* __restrict__ rpb,
                                                   unsigned short* __restrict__ Opart,
                                                   float* __restrict__ lpart) {
    __shared__ __align__(16) unsigned short Ks[2][4096];     // [j][d] linear
    __shared__ __align__(16) unsigned short Ps[2][4096];     // [t][d] linear
    __shared__ __align__(16) unsigned short Vt[2][4096];     // [d][j] linear
    __shared__ __align__(16) unsigned short Pp[64 * SLD];    // [i][j] (wave-private rows)
    __shared__ __align__(8)  unsigned short Rb[128 * RST];   // skewed rel ring [(t+m)&127][m]

    const int f32 = (int)flags[0];
    const int tid = threadIdx.x;
    const int it = blockIdx.x, bh = blockIdx.y, z = blockIdx.z;
    const int h = bh & 7;
    const int i0 = it * 64;
    const size_t qoff = (size_t)bh * N_ * 64;
    const size_t poff = (size_t)h * 4096 * 64;
    const unsigned short* vbase = vb + (size_t)bh * 64 * 2048;
    const int lane = tid & 63, w = tid >> 6;
    const int l15 = lane & 15, quad = lane >> 4, q8 = quad * 8;
    const int m0 = w * 16 + quad * 4;
    const int swz = (l15 & 7) << 3;

    // ---- Q fragments (qbuf unswizzled, direct 16B loads), biases folded ----
    short8 afc[2], afr[2];
#pragma unroll
    for (int kc = 0; kc < 2; ++kc) {
        uint4 qv = *reinterpret_cast<const uint4*>(
            &qb[qoff + (size_t)(i0 + w * 16 + l15) * 64 + kc * 32 + q8]);
        unsigned int uu[4] = {qv.x, qv.y, qv.z, qv.w};
        unsigned int cw[4], rw[4];
#pragma unroll
        for (int e = 0; e < 4; ++e) {
            int k = h * 64 + kc * 32 + q8 + 2 * e;
            float lo = __uint_as_float(uu[e] << 16);
            float hi = __uint_as_float(uu[e] & 0xffff0000u);
            cw[e] = pack2bf(lo + ldf(rcb, f32, k), hi + ldf(rcb, f32, k + 1));
            rw[e] = pack2bf(lo + ldf(rpb, f32, k), hi + ldf(rpb, f32, k + 1));
        }
        union { uint4 u; short8 s; } cv, rv2;
        cv.u  = (uint4){cw[0], cw[1], cw[2], cw[3]};
        rv2.u = (uint4){rw[0], rw[1], rw[2], rw[3]};
        afc[kc] = cv.s;
        afr[kc] = rv2.s;
    }

    float4v Oa[4];
#pragma unroll
    for (int nb = 0; nb < 4; ++nb) Oa[nb] = (float4v){0.f, 0.f, 0.f, 0.f};
    float lsum[4] = {0.f, 0.f, 0.f, 0.f};

    const int base0 = 1984 - i0;
    const int t0 = z * 11, t1 = (z == 2) ? 32 : (t0 + 11);
    const int NT = t1 - t0;
    const int cs0 = base0 + t0 * 64;

    // ---- prologue 1: direct stage pos chunk cs0 -> Ps[0] (verbatim rows) ----
    {
        int r = tid >> 2, c16 = (tid & 3) * 16;
        const uint4* psrc = reinterpret_cast<const uint4*>(&posb[poff + (size_t)(cs0 + r) * 64 + c16]);
        *reinterpret_cast<uint4*>(&Ps[0][r * 64 + c16])     = psrc[0];
        *reinterpret_cast<uint4*>(&Ps[0][r * 64 + c16 + 8]) = psrc[1];
    }
    __syncthreads();
    // ---- seed ring from Ps[0] (swizzled fragment reads) ----
    {
        float4v R[4];
#pragma unroll
        for (int nb = 0; nb < 4; ++nb) R[nb] = (float4v){0.f, 0.f, 0.f, 0.f};
        __builtin_amdgcn_s_setprio(1);
#pragma unroll
        for (int kc = 0; kc < 2; ++kc)
#pragma unroll
            for (int nb = 0; nb < 4; ++nb) {
                short8 pb = *reinterpret_cast<const short8*>(
                    &Ps[0][(nb * 16 + l15) * 64 + ((kc * 32 + q8) ^ swz)]);
                R[nb] = __builtin_amdgcn_mfma_f32_16x16x32_bf16(afr[kc], pb, R[nb], 0, 0, 0);
            }
        __builtin_amdgcn_s_setprio(0);
#pragma unroll
        for (int nb = 0; nb < 4; ++nb) {
            int ta = cs0 + nb * 16 + l15;
            unsigned int pk0 = cvtpk(R[nb][0], R[nb][1]);
            unsigned int pk1 = cvtpk(R[nb][2], R[nb][3]);
            Rb[(size_t)((ta + m0 + 0) & 127) * RST + m0 + 0] = (unsigned short)pk0;
            Rb[(size_t)((ta + m0 + 1) & 127) * RST + m0 + 1] = (unsigned short)(pk0 >> 16);
            Rb[(size_t)((ta + m0 + 2) & 127) * RST + m0 + 2] = (unsigned short)pk1;
            Rb[(size_t)((ta + m0 + 3) & 127) * RST + m0 + 3] = (unsigned short)(pk1 >> 16);
        }
    }
    __syncthreads();   // all waves done reading Ps[0] before gll16 overwrites it

    // ---- prologue 2: async stage tile 0 (K0, pos chunk1, V0) into buf 0 ----
    stage_lin(&kb[qoff + (size_t)(t0 * 64) * 64], Ks[0], tid, w);
    stage_lin(&posb[poff + (size_t)(cs0 + 64) * 64], Ps[0], tid, w);
    stage_vt(vbase, t0 * 64, Vt[0], tid, w);

    for (int u = 0; u < NT; ++u) {
        const int p = u & 1;
        const int j0 = (t0 + u) * 64, basej = base0 + j0;
        __syncthreads();   // drains gll16s filling buf[p]; orders prev readers of buf[p^1]

        // ---- issue next-tile gll16s into buf[p^1] (land during compute) ----
        if (u + 1 < NT) {
            stage_lin(&kb[qoff + (size_t)(j0 + 64) * 64], Ks[p ^ 1], tid, w);
            stage_lin(&posb[poff + (size_t)(cs0 + (u + 2) * 64) * 64], Ps[p ^ 1], tid, w);
            stage_vt(vbase, j0 + 64, Vt[p ^ 1], tid, w);
        }

        // ---- rel GEMM from Ps[p] -> 64 new ring cols at basej+64 ----
        {
            float4v R[4];
#pragma unroll
            for (int nb = 0; nb < 4; ++nb) R[nb] = (float4v){0.f, 0.f, 0.f, 0.f};
            __builtin_amdgcn_s_setprio(1);
#pragma unroll
            for (int kc = 0; kc < 2; ++kc)
#pragma unroll
                for (int nb = 0; nb < 4; ++nb) {
                    short8 pb = *reinterpret_cast<const short8*>(
                        &Ps[p][(nb * 16 + l15) * 64 + ((kc * 32 + q8) ^ swz)]);
                    R[nb] = __builtin_amdgcn_mfma_f32_16x16x32_bf16(afr[kc], pb, R[nb], 0, 0, 0);
                }
            __builtin_amdgcn_s_setprio(0);
            const int tb = basej + 64;
#pragma unroll
            for (int nb = 0; nb < 4; ++nb) {
                int ta = tb + nb * 16 + l15;
                unsigned int pk0 = cvtpk(R[nb][0], R[nb][1]);
                unsigned int pk1 = cvtpk(R[nb][2], R[nb][3]);
                Rb[(size_t)((ta + m0 + 0) & 127) * RST + m0 + 0] = (unsigned short)pk0;
                Rb[(size_t)((ta + m0 + 1) & 127) * RST + m0 + 1] = (unsigned short)(pk0 >> 16);
                Rb[(size_t)((ta + m0 + 2) & 127) * RST + m0 + 2] = (unsigned short)pk1;
                Rb[(size_t)((ta + m0 + 3) & 127) * RST + m0 + 3] = (unsigned short)(pk1 >> 16);
            }
        }

        // ---- content GEMM: Sacc = Qc · K^T from Ks[p] ----
        float4v Sacc[4];
#pragma unroll
        for (int nb = 0; nb < 4; ++nb) Sacc[nb] = (float4v){0.f, 0.f, 0.f, 0.f};
        __builtin_amdgcn_s_setprio(1);
#pragma unroll
        for (int kc = 0; kc < 2; ++kc)
#pragma unroll
            for (int nb = 0; nb < 4; ++nb) {
                short8 kf = *reinterpret_cast<const short8*>(
                    &Ks[p][(nb * 16 + l15) * 64 + ((kc * 32 + q8) ^ swz)]);
                Sacc[nb] = __builtin_amdgcn_mfma_f32_16x16x32_bf16(afc[kc], kf, Sacc[nb], 0, 0, 0);
            }
        __builtin_amdgcn_s_setprio(0);

        // ---- vector gather of rel diagonal, exp, pack P via cvt_pk ----
        float pv4[4][4];
#pragma unroll
        for (int nb = 0; nb < 4; ++nb) {
            const int jl = nb * 16 + l15;
            const int row = (basej + 63 + jl) & 127;
            union { uint2 u2; unsigned short us[4]; } rv;
            rv.u2 = *reinterpret_cast<const uint2*>(&Rb[(size_t)row * RST + m0]);
#pragma unroll
            for (int r = 0; r < 4; ++r) {
                float p2 = __expf(Sacc[nb][r] + bf2f(rv.us[r]));
                pv4[nb][r] = p2;
                lsum[r] += p2;
            }
        }
#pragma unroll
        for (int r = 0; r < 4; ++r) {
            unsigned short* prow = &Pp[(m0 + r) * SLD + l15];
#pragma unroll
            for (int np = 0; np < 2; ++np) {
                unsigned int pk = cvtpk(pv4[2 * np][r], pv4[2 * np + 1][r]);
                prow[(2 * np) * 16]     = (unsigned short)pk;
                prow[(2 * np + 1) * 16] = (unsigned short)(pk >> 16);
            }
        }

        // ---- PV GEMM: Oa += P · V from Vt[p] ----
        __builtin_amdgcn_s_setprio(1);
#pragma unroll
        for (int kc = 0; kc < 2; ++kc) {
            short8 pf = *reinterpret_cast<const short8*>(&Pp[(w * 16 + l15) * SLD + kc * 32 + q8]);
#pragma unroll
            for (int nb = 0; nb < 4; ++nb) {
                short8 vf = *reinterpret_cast<const short8*>(
                    &Vt[p][(nb * 16 + l15) * 64 + ((kc * 32 + q8) ^ swz)]);
                Oa[nb] = __builtin_amdgcn_mfma_f32_16x16x32_bf16(pf, vf, Oa[nb], 0, 0, 0);
            }
        }
        __builtin_amdgcn_s_setprio(0);
    }

    // ---- reduce row sums, write partials (coalesced via Pp round-trip) ----
#pragma unroll
    for (int r = 0; r < 4; ++r)
#pragma unroll
        for (int off = 1; off < 16; off <<= 1) lsum[r] += __shfl_xor(lsum[r], off);
    const size_t pslot = (size_t)(z * 16 + bh) * 32 + it;
    const size_t obase = pslot * 4096;
#pragma unroll
    for (int nb = 0; nb < 4; ++nb) {
        unsigned int pk0 = cvtpk(Oa[nb][0], Oa[nb][1]);
        unsigned int pk1 = cvtpk(Oa[nb][2], Oa[nb][3]);
        unsigned short* prow = &Pp[m0 * SLD + nb * 16 + l15];
        prow[0 * SLD] = (unsigned short)pk0;
        prow[1 * SLD] = (unsigned short)(pk0 >> 16);
        prow[2 * SLD] = (unsigned short)pk1;
        prow[3 * SLD] = (unsigned short)(pk1 >> 16);
    }
    {
        const int rr2 = w * 16 + (lane >> 2), cc2 = (lane & 3) * 16;
        uint4 o0 = *reinterpret_cast<const uint4*>(&Pp[rr2 * SLD + cc2]);
        uint4 o1 = *reinterpret_cast<const uint4*>(&Pp[rr2 * SLD + cc2 + 8]);
        *reinterpret_cast<uint4*>(&Opart[obase + (size_t)rr2 * 64 + cc2])     = o0;
        *reinterpret_cast<uint4*>(&Opart[obase + (size_t)rr2 * 64 + cc2 + 8]) = o1;
    }
    if (l15 == 0) {
#pragma unroll
        for (int r = 0; r < 4; ++r) lpart[pslot * 64 + m0 + r] = lsum[r];
    }
}

// ---------------------------------------------------------------------------
// 4) Combine j-split partials, normalize, write ao[b][i][h*64+d] bf16.
// ---------------------------------------------------------------------------
__global__ __launch_bounds__(256) void combine_kernel(const unsigned short* __restrict__ Opart,
                                                      const float* __restrict__ lpart,
                                                      unsigned short* __restrict__ ao) {
    const int it = blockIdx.x, bh = blockIdx.y;
    const int h = bh & 7, b = bh >> 3, i0 = it * 64;
    const int tid = threadIdx.x;
    const int row = tid >> 2, c0 = (tid & 3) * 16;
    float o[16];
#pragma unroll
    for (int e = 0; e < 16; ++e) o[e] = 0.f;
    float l = 0.f;
#pragma unroll
    for (int z = 0; z < 3; ++z) {
        const size_t pslot = (size_t)(z * 16 + bh) * 32 + it;
        const size_t ob = pslot * 4096 + (size_t)row * 64 + c0;
        uint4 a = *reinterpret_cast<const uint4*>(&Opart[ob]);
        uint4 b4 = *reinterpret_cast<const uint4*>(&Opart[ob + 8]);
        unsigned int uu[8] = {a.x, a.y, a.z, a.w, b4.x, b4.y, b4.z, b4.w};
#pragma unroll
        for (int e = 0; e < 8; ++e) {
            o[2 * e]     += __uint_as_float(uu[e] << 16);
            o[2 * e + 1] += __uint_as_float(uu[e] & 0xffff0000u);
        }
        l += lpart[pslot * 64 + row];
    }
    float inv = 1.0f / l;
    unsigned int ou[8];
#pragma unroll
    for (int e = 0; e < 8; ++e) ou[e] = pack2bf(o[2 * e] * inv, o[2 * e + 1] * inv);
    unsigned short* dst = &ao[((size_t)b * N_ + i0 + row) * 512 + h * 64 + c0];
    *reinterpret_cast<uint4*>(dst)     = (uint4){ou[0], ou[1], ou[2], ou[3]};
    *reinterpret_cast<uint4*>(dst + 8) = (uint4){ou[4], ou[5], ou[6], ou[7]};
}

// ---------------------------------------------------------------------------
// 5) out = ao @ Wo + bo (output dtype per flag). grid (12, 32).
// ---------------------------------------------------------------------------
__global__ __launch_bounds__(256) void outproj_kernel(const unsigned int* __restrict__ flags,
                                                      const unsigned short* __restrict__ AO,
                                                      const unsigned short* __restrict__ Wot,
                                                      const void* __restrict__ bo,
                                                      void* __restrict__ out) {
    __shared__ __align__(16) unsigned short As[128 * 32];
    __shared__ __align__(16) unsigned short Bs[128 * 32];
    const int f32 = (int)flags[0];
    const int row0 = blockIdx.y * 128, col0 = blockIdx.x * 128;
    float4v acc[4][4];
#pragma unroll
    for (int mi = 0; mi < 4; ++mi)
#pragma unroll
        for (int ni = 0; ni < 4; ++ni) acc[mi][ni] = (float4v){0.f, 0.f, 0.f, 0.f};
    gemm128_core(AO, Wot, 512, row0, col0, As, Bs, acc);
    const int lane = threadIdx.x & 63, w = threadIdx.x >> 6;
    const int l15 = lane & 15, quad = lane >> 4;
    const int mr0 = (w >> 1) * 64, nc0 = (w & 1) * 64;
#pragma unroll
    for (int mi = 0; mi < 4; ++mi)
#pragma unroll
        for (int ni = 0; ni < 4; ++ni) {
            int n = col0 + nc0 + ni * 16 + l15;
            float bias = ldf(bo, f32, n);
#pragma unroll
            for (int r = 0; r < 4; ++r) {
                int m = row0 + mr0 + mi * 16 + quad * 4 + r;
                float v = acc[mi][ni][r] + bias;
                if (f32) ((float*)out)[(size_t)m * DIM_ + n] = v;
                else     ((unsigned short*)out)[(size_t)m * DIM_ + n] = f2bf(v);
            }
        }
}

// ---------------------------------------------------------------------------
extern "C" void kernel_launch(void* const* d_in, const int* in_sizes, int n_in,
                              void* d_out, int out_size, void* d_ws, size_t ws_size,
                              hipStream_t stream) {
    const void* x    = d_in[0];
    const void* Wq   = d_in[1];
    const void* Wk   = d_in[2];
    const void* Wv   = d_in[3];
    const void* Wo   = d_in[4];
    const void* bo   = d_in[5];
    const void* Wrel = d_in[6];
    const void* rcb  = d_in[7];
    const void* rpb  = d_in[8];

    char* ws = (char*)d_ws;
    unsigned int*   flags = (unsigned int*)(ws + OFF_FLAG);
    unsigned short* posb  = (unsigned short*)(ws + OFF_POS);
    unsigned short* qbuf  = (unsigned short*)(ws + OFF_Q);
    unsigned short* kbuf  = (unsigned short*)(ws + OFF_K);
    unsigned short* vbuf  = (unsigned short*)(ws + OFF_V);
    unsigned short* Wot   = (unsigned short*)(ws + OFF_WOT);
    unsigned short* Xb    = (unsigned short*)(ws + OFF_XB);
    unsigned short* ao    = (unsigned short*)(ws + OFF_AO);
    unsigned short* Opart = (unsigned short*)(ws + OFF_OP);
    float*          lpart = (float*)(ws + OFF_LP);
    unsigned short* Wt    = (unsigned short*)(ws + OFF_WT);

    // Host-side constants (capture-time only; pure functions of problem consts)
    PosConsts pc;
    double maxp = 0.0;
    for (int g = 0; g < NB_; ++g) {
        double mean = 64.0 * (g + 1);
        double conc = (mean / 32.0) * (mean / 32.0);
        double rate = mean / 1024.0;
        double lgc  = std::lgamma(conc);
        double clr  = conc * std::log(rate);
        for (int ad = 1; ad < N_; ++ad) {
            double lp = (conc - 1.0) * std::log((double)ad) - rate * (double)ad - lgc + clr;
            double p  = std::exp(lp) + 1e-8;
            if (p > maxp) maxp = p;
        }
        pc.c1[g]    = (float)(conc - 1.0);   // exact small integer
        pc.rateF[g] = (float)rate;           // exact dyadic
        pc.gc[g]    = -lgc + clr;
    }
    pc.maxp = maxp;
    const double max_range = std::log((double)N_) / std::log(2.0);   // 11.0
    for (int f = 0; f < 32; ++f) {
        double t = 3.0 + (double)f * (max_range - 3.0) / 31.0;
        pc.inv_hl[f] = (float)std::exp2(-t);
        int e = f + 1;   // central-mask exponent for class index f
        pc.widthI[f] = (e >= 12) ? 0x7FFFFFFF : ((1 << e) - 1);   // adI<=2047: clamp exact
    }

    prep_kernel<<<dim3(4352), dim3(512), 0, stream>>>(pc, x, Wq, Wk, Wv, Wo, Wrel,
                                                      flags, Xb, Wt, Wot, posb);
    qkv_kernel<<<dim3(12, 32), dim3(256), 0, stream>>>(Xb, Wt, qbuf, kbuf, vbuf);
    attn_kernel<<<dim3(32, 16, 3), dim3(256), 0, stream>>>(flags, qbuf, kbuf, vbuf, posb, rcb, rpb, Opart, lpart);
    combine_kernel<<<dim3(32, 16), dim3(256), 0, stream>>>(Opart, lpart, ao);
    outproj_kernel<<<dim3(12, 32), dim3(256), 0, stream>>>(flags, ao, Wot, bo, d_out);
}

// Round 8
// 247.924 us; speedup vs baseline: 1.3579x; 1.0470x over previous
//
#include <hip/hip_runtime.h>
#include <stdint.h>
#include <cmath>

// Problem constants
#define B_    2
#define N_    2048
#define DIM_  1536
#define H_    8
#define NPOS  (2*N_ - 1)   // 4095 (posb padded to 4096 rows; pad row never gathered)
#define NB_   32           // basis per class (192/6)

typedef __attribute__((ext_vector_type(8))) short short8;
typedef __attribute__((ext_vector_type(4))) float float4v;

// Host-precomputed positional-basis constants (capture-time only)
struct PosConsts {
    float  inv_hl[32];   // 2^-t, t = 3 + f*(11-3)/31
    int    widthI[32];   // 2^(i+1)-1 clamped (central-mask widths)
    float  c1[32];       // conc-1 (exact small integers)
    float  rateF[32];    // rate = (g+1)/16 (exact dyadic)
    double gc[32];       // -lgamma(conc) + conc*log(rate)
    double maxp;
};

__device__ __forceinline__ float bf2f(unsigned short u) {
    return __uint_as_float(((unsigned int)u) << 16);
}
__device__ __forceinline__ unsigned short f2bf(float f) {
    unsigned int u = __float_as_uint(f);
    u += 0x7FFFu + ((u >> 16) & 1u);   // RNE
    return (unsigned short)(u >> 16);
}
// HW packed f32x2 -> bf16x2 (RNE, identical to f2bf pair; 1 VALU op vs ~8)
__device__ __forceinline__ unsigned int cvtpk(float lo, float hi) {
    unsigned int r;
    asm("v_cvt_pk_bf16_f32 %0, %1, %2" : "=v"(r) : "v"(lo), "v"(hi));
    return r;
}
__device__ __forceinline__ unsigned int pack2bf(float lo, float hi) {
    return cvtpk(lo, hi);
}
__device__ __forceinline__ float ldf(const void* p, int isF32, size_t idx) {
    return isF32 ? ((const float*)p)[idx] : bf2f(((const unsigned short*)p)[idx]);
}
// async global->LDS, 16B per lane; LDS dest = wave-uniform base (+lane*16 by HW);
// global src is per-lane.
__device__ __forceinline__ void gll16(const unsigned short* g, unsigned short* l) {
    __builtin_amdgcn_global_load_lds(
        (const __attribute__((address_space(1))) unsigned int*)g,
        (__attribute__((address_space(3))) unsigned int*)l, 16, 0, 0);
}

// ---------------------------------------------------------------------------
// Workspace layout (bytes) — unchanged (35.7 MB).
// ---------------------------------------------------------------------------
constexpr size_t OFF_FLAG = 0;                                   // uint
constexpr size_t OFF_POS  = 256;                                 // bf16 [8][4096][64] (SWIZZLED, key j&7)
constexpr size_t OFF_Q    = OFF_POS + (size_t)H_*4096*64*2;
constexpr size_t OFF_K    = OFF_Q   + (size_t)B_*H_*N_*64*2;     // SWIZZLED cols (key tok&7)
constexpr size_t OFF_V    = OFF_K   + (size_t)B_*H_*N_*64*2;     // bf16 [b*h][64 d][2048 j] transposed, SWIZZLED j (key d&7)
constexpr size_t OFF_WOT  = OFF_V   + (size_t)B_*H_*N_*64*2;     // bf16 [1536][512]
constexpr size_t OFF_XB   = OFF_WOT + (size_t)DIM_*512*2;        // bf16 [4096][1536]
constexpr size_t OFF_AO   = OFF_XB;                              // bf16 [4096][512] (alias head of XB)
constexpr size_t OFF_OP   = OFF_AO + (size_t)4096*512*2;         // (unused this round)
constexpr size_t OFF_LP   = OFF_OP + (size_t)3*16*32*4096*2;     // (unused this round)
constexpr size_t OFF_WT   = OFF_XB + (size_t)4096*DIM_*2;        // bf16 [3][512][1536]
static_assert(OFF_LP + (size_t)3*16*32*64*4 <= OFF_WT + (size_t)3*512*DIM_*2, "ws overflow");

// ---------------------------------------------------------------------------
// 1) prep_kernel: fused detect + posproj + cvtw + cvtx (one dispatch).
//    Roles: [0,256) posproj; [256,3328) cvtw; [3328,4352) cvtx.
//    posb swizzle key (j&7) — attn stages pos chunks at 64-aligned starts.
// ---------------------------------------------------------------------------
__global__ __launch_bounds__(512) void prep_kernel(PosConsts pc,
                                                   const void* __restrict__ x,
                                                   const void* __restrict__ Wq, const void* __restrict__ Wk,
                                                   const void* __restrict__ Wv, const void* __restrict__ Wo,
                                                   const void* __restrict__ Wrel,
                                                   unsigned int* __restrict__ flags,
                                                   unsigned short* __restrict__ Xb,
                                                   unsigned short* __restrict__ Wt,
                                                   unsigned short* __restrict__ Wot,
                                                   unsigned short* __restrict__ posb) {
    __shared__ __align__(16) char smraw[16 * 192 * 4];   // 12288B: cnt / tile / eb overlay
    const int tid = threadIdx.x;
    const int bid = blockIdx.x;

    // ---- self-detect dtype (all blocks; ~1 cache line, L2 broadcast) ----
    int* cnt = (int*)smraw;
    int ok = 0;
    if (tid < 256) {
        unsigned short u = ((const unsigned short*)x)[2 * tid];
        int e = (u >> 7) & 0xFF;
        ok = (u == 0) || (e >= 95 && e <= 140);
    }
    cnt[tid] = ok;
    __syncthreads();
    for (int s = 256; s > 0; s >>= 1) {
        if (tid < s) cnt[tid] += cnt[tid + s];
        __syncthreads();
    }
    const int f32 = !(cnt[0] >= 192);
    __syncthreads();   // done with cnt before smem reuse
    if (bid == 0 && tid == 0) flags[0] = (unsigned int)f32;

    if (bid < 256) {
        // ---- role C: positional basis + projection (16 rows/block, FIRST) ----
        float* eb = (float*)smraw;    // [16][192]
        const int j0 = bid * 16;
        const int c  = tid;   // 0..511
        for (int u = c; u < 16 * 96; u += 512) {
            int rr = u / 96, f = u - rr * 96;
            int j = j0 + rr;
            float v = 0.f, sg = 0.f;
            if (j < NPOS) {
                int dd  = j - (N_ - 1);
                int adI = dd < 0 ? -dd : dd;
                float val;
                if (f < 32) {
                    val = exp2f(-(float)adI * pc.inv_hl[f]);
                } else if (f < 64) {
                    val = (adI < pc.widthI[f - 32]) ? 1.f : 0.f;
                } else {
                    int g = f - 64;
                    if (adI == 0) {
                        val = (float)(1e-8 / pc.maxp);
                    } else {
                        double lp = (double)pc.c1[g] * log((double)adI)
                                  - (double)pc.rateF[g] * (double)adI + pc.gc[g];
                        double p = (double)expf((float)lp) + 1e-8;
                        val = (float)(p / pc.maxp);
                    }
                }
                v  = val;
                sg = (dd > 0) ? 1.f : ((dd < 0) ? -1.f : 0.f);
            }
            eb[rr * 192 + f]      = v;
            eb[rr * 192 + 96 + f] = sg * v;
        }
        __syncthreads();
        float acc[16];
#pragma unroll
        for (int rr = 0; rr < 16; ++rr) acc[rr] = 0.f;
        for (int k = 0; k < 192; k += 4) {
            float w0 = ldf(Wrel, f32, (size_t)(k + 0) * 512 + c);
            float w1 = ldf(Wrel, f32, (size_t)(k + 1) * 512 + c);
            float w2 = ldf(Wrel, f32, (size_t)(k + 2) * 512 + c);
            float w3 = ldf(Wrel, f32, (size_t)(k + 3) * 512 + c);
#pragma unroll
            for (int rr = 0; rr < 16; ++rr) {
                float4v e = *reinterpret_cast<const float4v*>(&eb[rr * 192 + k]);
                acc[rr] += e[0] * w0;
                acc[rr] += e[1] * w1;
                acc[rr] += e[2] * w2;
                acc[rr] += e[3] * w3;
            }
        }
        int h = c >> 6, dcol = c & 63;
#pragma unroll
        for (int rr = 0; rr < 16; ++rr) {
            int j = j0 + rr;
            if (j < NPOS)
                posb[((size_t)h * 4096 + j) * 64 + (dcol ^ ((j & 7) << 3))] = f2bf(acc[rr]);
        }
    } else if (bid < 3328) {
        // ---- role B: weight transposes -> bf16 [N][K] ----
        unsigned short (*tile)[33] = (unsigned short(*)[33])smraw;
        const int idx = bid - 256;
        const int z = idx / 768, rem = idx % 768;
        const int bx = rem & 15, by = rem >> 4;
        const void* src = z == 0 ? Wq : (z == 1 ? Wk : (z == 2 ? Wv : Wo));
        unsigned short* dst = (z < 3) ? (Wt + (size_t)z * 512 * DIM_) : Wot;
        const int R = (z < 3) ? DIM_ : 512;
        const int C = (z < 3) ? 512 : DIM_;
        const int x0 = ((z < 3) ? bx : by) * 32;
        const int y0 = ((z < 3) ? by : bx) * 32;
        const int tx = tid & 31, ty = tid >> 5;   // ty 0..15
#pragma unroll
        for (int i = 0; i < 2; ++i)
            tile[ty + i * 16][tx] = f2bf(ldf(src, f32, (size_t)(y0 + ty + i * 16) * C + x0 + tx));
        __syncthreads();
#pragma unroll
        for (int i = 0; i < 2; ++i)
            dst[(size_t)(x0 + ty + i * 16) * R + y0 + tx] = tile[tx][ty + i * 16];
    } else {
        // ---- role A: x -> bf16 contiguous ----
        const int ab = bid - 3328;   // 0..1023
        const size_t total = (size_t)4096 * DIM_;
        size_t i = ((size_t)ab * 512 + tid) * 8;
        const size_t stride = (size_t)1024 * 512 * 8;
        if (f32) {
            for (; i < total; i += stride) {
                float4v a = *reinterpret_cast<const float4v*>((const float*)x + i);
                float4v b = *reinterpret_cast<const float4v*>((const float*)x + i + 4);
                uint4 o;
                o.x = pack2bf(a[0], a[1]); o.y = pack2bf(a[2], a[3]);
                o.z = pack2bf(b[0], b[1]); o.w = pack2bf(b[2], b[3]);
                *reinterpret_cast<uint4*>(Xb + i) = o;
            }
        } else {
            for (; i < total; i += stride)
                *reinterpret_cast<uint4*>(Xb + i) =
                    *reinterpret_cast<const uint4*>((const unsigned short*)x + i);
        }
    }
}

// ---------------------------------------------------------------------------
// 128x128 GEMM core (m97 structure): A [M][K] bf16 rm, Bt [N][K] bf16 rm.
// ---------------------------------------------------------------------------
__device__ __forceinline__ void gemm128_core(const unsigned short* __restrict__ A,
                                             const unsigned short* __restrict__ Bt,
                                             int K, int row0, int col0,
                                             unsigned short* As, unsigned short* Bs,
                                             float4v acc[4][4]) {
    const int tid = threadIdx.x, lane = tid & 63, w = tid >> 6;
    const int l15 = lane & 15, q8 = (lane >> 4) * 8;
    const int mr0 = (w >> 1) * 64, nc0 = (w & 1) * 64;
    const int sr = lane >> 2, sc8 = (lane & 3) * 8;
    for (int k0 = 0; k0 < K; k0 += 32) {
        __syncthreads();
        gll16(&A [(size_t)(row0 + w * 32 + sr) * K + k0 + sc8],      &As[w * 1024]);
        gll16(&A [(size_t)(row0 + w * 32 + 16 + sr) * K + k0 + sc8], &As[w * 1024 + 512]);
        gll16(&Bt[(size_t)(col0 + w * 32 + sr) * K + k0 + sc8],      &Bs[w * 1024]);
        gll16(&Bt[(size_t)(col0 + w * 32 + 16 + sr) * K + k0 + sc8], &Bs[w * 1024 + 512]);
        __syncthreads();
        short8 a[4], b[4];
#pragma unroll
        for (int mi = 0; mi < 4; ++mi)
            a[mi] = *reinterpret_cast<const short8*>(&As[(mr0 + mi * 16 + l15) * 32 + q8]);
#pragma unroll
        for (int ni = 0; ni < 4; ++ni)
            b[ni] = *reinterpret_cast<const short8*>(&Bs[(nc0 + ni * 16 + l15) * 32 + q8]);
#pragma unroll
        for (int mi = 0; mi < 4; ++mi)
#pragma unroll
            for (int ni = 0; ni < 4; ++ni)
                acc[mi][ni] = __builtin_amdgcn_mfma_f32_16x16x32_bf16(a[mi], b[ni], acc[mi][ni], 0, 0, 0);
    }
}

// ---------------------------------------------------------------------------
// 2) QKV single dispatch. K/V written with the attn LDS swizzle pre-applied
//    in GLOBAL memory (rule #21). Q unswizzled.
//      kbuf: col dd -> dd ^ ((token&7)<<3)
//      vbuf: [bh][d][j]; j-within-64 -> ^ ((d&7)<<3)
//    Round-8: Q/K epilogue bounced through per-wave [16][72] LDS scratch ->
//    2x uint4 global stores per row-group (was 64 scalar b16 stores/thread).
//    Mode is wave-uniform (64-col span aligned to the 512 boundary).
// ---------------------------------------------------------------------------
__global__ __launch_bounds__(256) void qkv_kernel(const unsigned short* __restrict__ Xb,
                                                  const unsigned short* __restrict__ Wt,
                                                  unsigned short* __restrict__ qbuf,
                                                  unsigned short* __restrict__ kbuf,
                                                  unsigned short* __restrict__ vbuf) {
    __shared__ __align__(16) unsigned short smem[2 * 128 * 32];   // As | Bs, reused as bounce
    unsigned short* As = smem;
    unsigned short* Bs = smem + 128 * 32;
    const int row0 = blockIdx.y * 128, col0 = blockIdx.x * 128;
    float4v acc[4][4];
#pragma unroll
    for (int mi = 0; mi < 4; ++mi)
#pragma unroll
        for (int ni = 0; ni < 4; ++ni) acc[mi][ni] = (float4v){0.f, 0.f, 0.f, 0.f};
    gemm128_core(Xb, Wt, DIM_, row0, col0, As, Bs, acc);
    __syncthreads();   // all waves done with As/Bs before bounce reuse

    const int lane = threadIdx.x & 63, w = threadIdx.x >> 6;
    const int l15 = lane & 15, quad = lane >> 4;
    const int mr0 = (w >> 1) * 64, nc0 = (w & 1) * 64;
    const int n0 = col0 + nc0;            // wave-uniform 64-col span start
    const int mode = n0 >> 9;             // 0=Q 1=K 2=V (uniform per wave)
    const int hh = (n0 & 511) >> 6;       // head (uniform per wave)

    if (mode == 2) {
        // ---- V: transposed + swizzled, uint2 per (mi,ni) (as before) ----
#pragma unroll
        for (int mi = 0; mi < 4; ++mi)
#pragma unroll
            for (int ni = 0; ni < 4; ++ni) {
                int dd = ni * 16 + l15;
                int mb = row0 + mr0 + mi * 16 + quad * 4;
                int bb = mb >> 11, ii = mb & 2047;
                union { unsigned short us[4]; uint2 u2; } pk;
                unsigned int p0 = cvtpk(acc[mi][ni][0], acc[mi][ni][1]);
                unsigned int p1 = cvtpk(acc[mi][ni][2], acc[mi][ni][3]);
                pk.u2 = (uint2){p0, p1};
                int jb = (ii & ~63) | ((ii & 63) ^ ((dd & 7) << 3));
                *reinterpret_cast<uint2*>(
                    &vbuf[((size_t)(bb * 8 + hh) * 64 + dd) * 2048 + jb]) = pk.u2;
            }
    } else {
        // ---- Q/K: bounce via per-wave [16][72] LDS -> vector global stores ----
        unsigned short* Obuf = (mode == 0) ? qbuf : kbuf;
        const float scale = (mode == 0) ? 0.125f : 1.0f;
        unsigned short* Lw = smem + w * 16 * 72;   // 4 waves x 2304B = 9216B <= 16KB
        const int r16 = lane >> 2, c4 = (lane & 3) * 16;
#pragma unroll
        for (int mi = 0; mi < 4; ++mi) {
#pragma unroll
            for (int ni = 0; ni < 4; ++ni)
#pragma unroll
                for (int r = 0; r < 4; ++r)
                    Lw[(quad * 4 + r) * 72 + ni * 16 + l15] = f2bf(acc[mi][ni][r] * scale);
            // same-wave RAW through LDS; compiler inserts lgkmcnt waits
            int mb = row0 + mr0 + mi * 16 + r16;
            int bb = mb >> 11, tok = mb & 2047;
            unsigned short* gp = &Obuf[((size_t)(bb * 8 + hh) * N_ + tok) * 64];
            uint4 v0 = *reinterpret_cast<const uint4*>(&Lw[r16 * 72 + c4]);
            uint4 v1 = *reinterpret_cast<const uint4*>(&Lw[r16 * 72 + c4 + 8]);
            int swz2 = (mode == 1) ? ((tok & 7) << 3) : 0;
            *reinterpret_cast<uint4*>(gp + (c4 ^ swz2))       = v0;
            *reinterpret_cast<uint4*>(gp + ((c4 + 8) ^ swz2)) = v1;
        }
    }
}

// ---------------------------------------------------------------------------
// 3) MFMA flash attention, z=1 (no j-split). Round-6 inner structure
//    (double-buffered gll16 staging, skewed ring, swizzled frag reads),
//    NT=32 tiles/block. Grid (32,16) = 512 blocks = exactly 2/CU, one
//    residency round. Row sums complete per block -> normalize inline and
//    write ao directly (combine kernel ELIMINATED).
// ---------------------------------------------------------------------------
#define SLD 72    // Pp row stride (VALU-written buffer keeps padding)
#define RST 68    // ring row stride (136B: 8B-aligned for uint2 reads at m0)

__device__ __forceinline__ void stage_lin(const unsigned short* __restrict__ g,
                                          unsigned short* s, int tid, int w) {
    // 8192B contiguous global tile -> 8192B linear LDS (2 calls x 4096B)
    gll16(g + tid * 8,        s + w * 512);
    gll16(g + 2048 + tid * 8, s + 2048 + w * 512);
}
__device__ __forceinline__ void stage_vt(const unsigned short* __restrict__ vbase,
                                         int jbase, unsigned short* s, int tid, int w) {
    // V tile: 64 rows (d) stride 2048 in global -> 64x64 linear LDS
    {
        int L = tid * 8;        int d = L >> 6, cb = L & 63;
        gll16(vbase + (size_t)d * 2048 + jbase + cb, s + w * 512);
    }
    {
        int L = 2048 + tid * 8; int d = L >> 6, cb = L & 63;
        gll16(vbase + (size_t)d * 2048 + jbase + cb, s + 2048 + w * 512);
    }
}

__global__ __launch_bounds__(256) void attn_kernel(const unsigned int* __restrict__ flags,
                                                   const unsigned short* __restrict__ qb,
                                                   const unsigned short* __restrict__ kb,   // swizzled
                                                   const unsigned short* __restrict__ vb,   // [bh][d][j] swizzled
                                                   const unsigned short* __restrict__ posb, // swizzled key j&7
                                                   const void* __restrict__ rcb,
                                                   const void* __restrict__ rpb,
                                                   unsigned short* __restrict__ ao) {
    __shared__ __align__(16) unsigned short Ks[2][4096];     // [j][d] linear
    __shared__ __align__(16) unsigned short Ps[2][4096];     // [t][d] linear
    __shared__ __align__(16) unsigned short Vt[2][4096];     // [d][j] linear
    __shared__ __align__(16) unsigned short Pp[64 * SLD];    // [i][j] (wave-private rows)
    __shared__ __align__(8)  unsigned short Rb[128 * RST];   // skewed rel ring [(t+m)&127][m]

    const int f32 = (int)flags[0];
    const int tid = threadIdx.x;
    const int it = blockIdx.x, bh = blockIdx.y;
    const int h = bh & 7, b = bh >> 3;
    const int i0 = it * 64;
    const size_t qoff = (size_t)bh * N_ * 64;
    const size_t poff = (size_t)h * 4096 * 64;
    const unsigned short* vbase = vb + (size_t)bh * 64 * 2048;
    const int lane = tid & 63, w = tid >> 6;
    const int l15 = lane & 15, quad = lane >> 4, q8 = quad * 8;
    const int m0 = w * 16 + quad * 4;
    const int swz = (l15 & 7) << 3;

    // ---- Q fragments (qbuf unswizzled, direct 16B loads), biases folded ----
    short8 afc[2], afr[2];
#pragma unroll
    for (int kc = 0; kc < 2; ++kc) {
        uint4 qv = *reinterpret_cast<const uint4*>(
            &qb[qoff + (size_t)(i0 + w * 16 + l15) * 64 + kc * 32 + q8]);
        unsigned int uu[4] = {qv.x, qv.y, qv.z, qv.w};
        unsigned int cw[4], rw[4];
#pragma unroll
        for (int e = 0; e < 4; ++e) {
            int k = h * 64 + kc * 32 + q8 + 2 * e;
            float lo = __uint_as_float(uu[e] << 16);
            float hi = __uint_as_float(uu[e] & 0xffff0000u);
            cw[e] = pack2bf(lo + ldf(rcb, f32, k), hi + ldf(rcb, f32, k + 1));
            rw[e] = pack2bf(lo + ldf(rpb, f32, k), hi + ldf(rpb, f32, k + 1));
        }
        union { uint4 u; short8 s; } cv, rv2;
        cv.u  = (uint4){cw[0], cw[1], cw[2], cw[3]};
        rv2.u = (uint4){rw[0], rw[1], rw[2], rw[3]};
        afc[kc] = cv.s;
        afr[kc] = rv2.s;
    }

    float4v Oa[4];
#pragma unroll
    for (int nb = 0; nb < 4; ++nb) Oa[nb] = (float4v){0.f, 0.f, 0.f, 0.f};
    float lsum[4] = {0.f, 0.f, 0.f, 0.f};

    const int base0 = 1984 - i0;
    const int NT = 32;
    const int cs0 = base0;

    // ---- prologue 1: direct stage pos chunk cs0 -> Ps[0] (verbatim rows) ----
    {
        int r = tid >> 2, c16 = (tid & 3) * 16;
        const uint4* psrc = reinterpret_cast<const uint4*>(&posb[poff + (size_t)(cs0 + r) * 64 + c16]);
        *reinterpret_cast<uint4*>(&Ps[0][r * 64 + c16])     = psrc[0];
        *reinterpret_cast<uint4*>(&Ps[0][r * 64 + c16 + 8]) = psrc[1];
    }
    __syncthreads();
    // ---- seed ring from Ps[0] (swizzled fragment reads) ----
    {
        float4v R[4];
#pragma unroll
        for (int nb = 0; nb < 4; ++nb) R[nb] = (float4v){0.f, 0.f, 0.f, 0.f};
        __builtin_amdgcn_s_setprio(1);
#pragma unroll
        for (int kc = 0; kc < 2; ++kc)
#pragma unroll
            for (int nb = 0; nb < 4; ++nb) {
                short8 pb = *reinterpret_cast<const short8*>(
                    &Ps[0][(nb * 16 + l15) * 64 + ((kc * 32 + q8) ^ swz)]);
                R[nb] = __builtin_amdgcn_mfma_f32_16x16x32_bf16(afr[kc], pb, R[nb], 0, 0, 0);
            }
        __builtin_amdgcn_s_setprio(0);
#pragma unroll
        for (int nb = 0; nb < 4; ++nb) {
            int ta = cs0 + nb * 16 + l15;
            unsigned int pk0 = cvtpk(R[nb][0], R[nb][1]);
            unsigned int pk1 = cvtpk(R[nb][2], R[nb][3]);
            Rb[(size_t)((ta + m0 + 0) & 127) * RST + m0 + 0] = (unsigned short)pk0;
            Rb[(size_t)((ta + m0 + 1) & 127) * RST + m0 + 1] = (unsigned short)(pk0 >> 16);
            Rb[(size_t)((ta + m0 + 2) & 127) * RST + m0 + 2] = (unsigned short)pk1;
            Rb[(size_t)((ta + m0 + 3) & 127) * RST + m0 + 3] = (unsigned short)(pk1 >> 16);
        }
    }
    __syncthreads();   // all waves done reading Ps[0] before gll16 overwrites it

    // ---- prologue 2: async stage tile 0 (K0, pos chunk1, V0) into buf 0 ----
    stage_lin(&kb[qoff], Ks[0], tid, w);
    stage_lin(&posb[poff + (size_t)(cs0 + 64) * 64], Ps[0], tid, w);
    stage_vt(vbase, 0, Vt[0], tid, w);

    for (int u = 0; u < NT; ++u) {
        const int p = u & 1;
        const int j0 = u * 64, basej = base0 + j0;
        __syncthreads();   // drains gll16s filling buf[p]; orders prev readers of buf[p^1]

        // ---- issue next-tile gll16s into buf[p^1] (land during compute) ----
        if (u + 1 < NT) {
            stage_lin(&kb[qoff + (size_t)(j0 + 64) * 64], Ks[p ^ 1], tid, w);
            stage_lin(&posb[poff + (size_t)(cs0 + (u + 2) * 64) * 64], Ps[p ^ 1], tid, w);
            stage_vt(vbase, j0 + 64, Vt[p ^ 1], tid, w);
        }

        // ---- rel GEMM from Ps[p] -> 64 new ring cols at basej+64 ----
        {
            float4v R[4];
#pragma unroll
            for (int nb = 0; nb < 4; ++nb) R[nb] = (float4v){0.f, 0.f, 0.f, 0.f};
            __builtin_amdgcn_s_setprio(1);
#pragma unroll
            for (int kc = 0; kc < 2; ++kc)
#pragma unroll
                for (int nb = 0; nb < 4; ++nb) {
                    short8 pb = *reinterpret_cast<const short8*>(
                        &Ps[p][(nb * 16 + l15) * 64 + ((kc * 32 + q8) ^ swz)]);
                    R[nb] = __builtin_amdgcn_mfma_f32_16x16x32_bf16(afr[kc], pb, R[nb], 0, 0, 0);
                }
            __builtin_amdgcn_s_setprio(0);
            const int tb = basej + 64;
#pragma unroll
            for (int nb = 0; nb < 4; ++nb) {
                int ta = tb + nb * 16 + l15;
                unsigned int pk0 = cvtpk(R[nb][0], R[nb][1]);
                unsigned int pk1 = cvtpk(R[nb][2], R[nb][3]);
                Rb[(size_t)((ta + m0 + 0) & 127) * RST + m0 + 0] = (unsigned short)pk0;
                Rb[(size_t)((ta + m0 + 1) & 127) * RST + m0 + 1] = (unsigned short)(pk0 >> 16);
                Rb[(size_t)((ta + m0 + 2) & 127) * RST + m0 + 2] = (unsigned short)pk1;
                Rb[(size_t)((ta + m0 + 3) & 127) * RST + m0 + 3] = (unsigned short)(pk1 >> 16);
            }
        }

        // ---- content GEMM: Sacc = Qc · K^T from Ks[p] ----
        float4v Sacc[4];
#pragma unroll
        for (int nb = 0; nb < 4; ++nb) Sacc[nb] = (float4v){0.f, 0.f, 0.f, 0.f};
        __builtin_amdgcn_s_setprio(1);
#pragma unroll
        for (int kc = 0; kc < 2; ++kc)
#pragma unroll
            for (int nb = 0; nb < 4; ++nb) {
                short8 kf = *reinterpret_cast<const short8*>(
                    &Ks[p][(nb * 16 + l15) * 64 + ((kc * 32 + q8) ^ swz)]);
                Sacc[nb] = __builtin_amdgcn_mfma_f32_16x16x32_bf16(afc[kc], kf, Sacc[nb], 0, 0, 0);
            }
        __builtin_amdgcn_s_setprio(0);

        // ---- vector gather of rel diagonal, exp, pack P via cvt_pk ----
        float pv4[4][4];
#pragma unroll
        for (int nb = 0; nb < 4; ++nb) {
            const int jl = nb * 16 + l15;
            const int row = (basej + 63 + jl) & 127;
            union { uint2 u2; unsigned short us[4]; } rv;
            rv.u2 = *reinterpret_cast<const uint2*>(&Rb[(size_t)row * RST + m0]);
#pragma unroll
            for (int r = 0; r < 4; ++r) {
                float p2 = __expf(Sacc[nb][r] + bf2f(rv.us[r]));
                pv4[nb][r] = p2;
                lsum[r] += p2;
            }
        }
#pragma unroll
        for (int r = 0; r < 4; ++r) {
            unsigned short* prow = &Pp[(m0 + r) * SLD + l15];
#pragma unroll
            for (int np = 0; np < 2; ++np) {
                unsigned int pk = cvtpk(pv4[2 * np][r], pv4[2 * np + 1][r]);
                prow[(2 * np) * 16]     = (unsigned short)pk;
                prow[(2 * np + 1) * 16] = (unsigned short)(pk >> 16);
            }
        }

        // ---- PV GEMM: Oa += P · V from Vt[p] ----
        __builtin_amdgcn_s_setprio(1);
#pragma unroll
        for (int kc = 0; kc < 2; ++kc) {
            short8 pf = *reinterpret_cast<const short8*>(&Pp[(w * 16 + l15) * SLD + kc * 32 + q8]);
#pragma unroll
            for (int nb = 0; nb < 4; ++nb) {
                short8 vf = *reinterpret_cast<const short8*>(
                    &Vt[p][(nb * 16 + l15) * 64 + ((kc * 32 + q8) ^ swz)]);
                Oa[nb] = __builtin_amdgcn_mfma_f32_16x16x32_bf16(pf, vf, Oa[nb], 0, 0, 0);
            }
        }
        __builtin_amdgcn_s_setprio(0);
    }

    // ---- complete row sums, normalize, write ao directly (no combine) ----
#pragma unroll
    for (int r = 0; r < 4; ++r) {
#pragma unroll
        for (int off = 1; off < 16; off <<= 1) lsum[r] += __shfl_xor(lsum[r], off);
        lsum[r] = 1.0f / lsum[r];
    }
#pragma unroll
    for (int nb = 0; nb < 4; ++nb) {
        unsigned int pk0 = cvtpk(Oa[nb][0] * lsum[0], Oa[nb][1] * lsum[1]);
        unsigned int pk1 = cvtpk(Oa[nb][2] * lsum[2], Oa[nb][3] * lsum[3]);
        unsigned short* prow = &Pp[m0 * SLD + nb * 16 + l15];
        prow[0 * SLD] = (unsigned short)pk0;
        prow[1 * SLD] = (unsigned short)(pk0 >> 16);
        prow[2 * SLD] = (unsigned short)pk1;
        prow[3 * SLD] = (unsigned short)(pk1 >> 16);
    }
    {
        const int rr2 = w * 16 + (lane >> 2), cc2 = (lane & 3) * 16;
        uint4 o0 = *reinterpret_cast<const uint4*>(&Pp[rr2 * SLD + cc2]);
        uint4 o1 = *reinterpret_cast<const uint4*>(&Pp[rr2 * SLD + cc2 + 8]);
        unsigned short* dst = &ao[((size_t)(b * N_ + i0 + rr2)) * 512 + h * 64 + cc2];
        *reinterpret_cast<uint4*>(dst)     = o0;
        *reinterpret_cast<uint4*>(dst + 8) = o1;
    }
}

// ---------------------------------------------------------------------------
// 4) out = ao @ Wo + bo (output dtype per flag). grid (12, 32).
// ---------------------------------------------------------------------------
__global__ __launch_bounds__(256) void outproj_kernel(const unsigned int* __restrict__ flags,
                                                      const unsigned short* __restrict__ AO,
                                                      const unsigned short* __restrict__ Wot,
                                                      const void* __restrict__ bo,
                                                      void* __restrict__ out) {
    __shared__ __align__(16) unsigned short As[128 * 32];
    __shared__ __align__(16) unsigned short Bs[128 * 32];
    const int f32 = (int)flags[0];
    const int row0 = blockIdx.y * 128, col0 = blockIdx.x * 128;
    float4v acc[4][4];
#pragma unroll
    for (int mi = 0; mi < 4; ++mi)
#pragma unroll
        for (int ni = 0; ni < 4; ++ni) acc[mi][ni] = (float4v){0.f, 0.f, 0.f, 0.f};
    gemm128_core(AO, Wot, 512, row0, col0, As, Bs, acc);
    const int lane = threadIdx.x & 63, w = threadIdx.x >> 6;
    const int l15 = lane & 15, quad = lane >> 4;
    const int mr0 = (w >> 1) * 64, nc0 = (w & 1) * 64;
#pragma unroll
    for (int mi = 0; mi < 4; ++mi)
#pragma unroll
        for (int ni = 0; ni < 4; ++ni) {
            int n = col0 + nc0 + ni * 16 + l15;
            float bias = ldf(bo, f32, n);
#pragma unroll
            for (int r = 0; r < 4; ++r) {
                int m = row0 + mr0 + mi * 16 + quad * 4 + r;
                float v = acc[mi][ni][r] + bias;
                if (f32) ((float*)out)[(size_t)m * DIM_ + n] = v;
                else     ((unsigned short*)out)[(size_t)m * DIM_ + n] = f2bf(v);
            }
        }
}

// ---------------------------------------------------------------------------
extern "C" void kernel_launch(void* const* d_in, const int* in_sizes, int n_in,
                              void* d_out, int out_size, void* d_ws, size_t ws_size,
                              hipStream_t stream) {
    const void* x    = d_in[0];
    const void* Wq   = d_in[1];
    const void* Wk   = d_in[2];
    const void* Wv   = d_in[3];
    const void* Wo   = d_in[4];
    const void* bo   = d_in[5];
    const void* Wrel = d_in[6];
    const void* rcb  = d_in[7];
    const void* rpb  = d_in[8];

    char* ws = (char*)d_ws;
    unsigned int*   flags = (unsigned int*)(ws + OFF_FLAG);
    unsigned short* posb  = (unsigned short*)(ws + OFF_POS);
    unsigned short* qbuf  = (unsigned short*)(ws + OFF_Q);
    unsigned short* kbuf  = (unsigned short*)(ws + OFF_K);
    unsigned short* vbuf  = (unsigned short*)(ws + OFF_V);
    unsigned short* Wot   = (unsigned short*)(ws + OFF_WOT);
    unsigned short* Xb    = (unsigned short*)(ws + OFF_XB);
    unsigned short* ao    = (unsigned short*)(ws + OFF_AO);
    unsigned short* Wt    = (unsigned short*)(ws + OFF_WT);

    // Host-side constants (capture-time only; pure functions of problem consts)
    PosConsts pc;
    double maxp = 0.0;
    for (int g = 0; g < NB_; ++g) {
        double mean = 64.0 * (g + 1);
        double conc = (mean / 32.0) * (mean / 32.0);
        double rate = mean / 1024.0;
        double lgc  = std::lgamma(conc);
        double clr  = conc * std::log(rate);
        for (int ad = 1; ad < N_; ++ad) {
            double lp = (conc - 1.0) * std::log((double)ad) - rate * (double)ad - lgc + clr;
            double p  = std::exp(lp) + 1e-8;
            if (p > maxp) maxp = p;
        }
        pc.c1[g]    = (float)(conc - 1.0);   // exact small integer
        pc.rateF[g] = (float)rate;           // exact dyadic
        pc.gc[g]    = -lgc + clr;
    }
    pc.maxp = maxp;
    const double max_range = std::log((double)N_) / std::log(2.0);   // 11.0
    for (int f = 0; f < 32; ++f) {
        double t = 3.0 + (double)f * (max_range - 3.0) / 31.0;
        pc.inv_hl[f] = (float)std::exp2(-t);
        int e = f + 1;   // central-mask exponent for class index f
        pc.widthI[f] = (e >= 12) ? 0x7FFFFFFF : ((1 << e) - 1);   // adI<=2047: clamp exact
    }

    prep_kernel<<<dim3(4352), dim3(512), 0, stream>>>(pc, x, Wq, Wk, Wv, Wo, Wrel,
                                                      flags, Xb, Wt, Wot, posb);
    qkv_kernel<<<dim3(12, 32), dim3(256), 0, stream>>>(Xb, Wt, qbuf, kbuf, vbuf);
    attn_kernel<<<dim3(32, 16), dim3(256), 0, stream>>>(flags, qbuf, kbuf, vbuf, posb, rcb, rpb, ao);
    outproj_kernel<<<dim3(12, 32), dim3(256), 0, stream>>>(flags, ao, Wot, bo, d_out);
}

// Round 9
// 247.794 us; speedup vs baseline: 1.3586x; 1.0005x over previous
//
#include <hip/hip_runtime.h>
#include <stdint.h>
#include <cmath>

// Problem constants
#define B_    2
#define N_    2048
#define DIM_  1536
#define H_    8
#define NPOS  (2*N_ - 1)   // 4095 (posb padded to 4096 rows; pad row never gathered)
#define NB_   32           // basis per class (192/6)

typedef __attribute__((ext_vector_type(8))) short short8;
typedef __attribute__((ext_vector_type(4))) float float4v;

// Host-precomputed positional-basis constants (capture-time only)
struct PosConsts {
    float  inv_hl[32];   // 2^-t, t = 3 + f*(11-3)/31
    int    widthI[32];   // 2^(i+1)-1 clamped (central-mask widths)
    float  c1[32];       // conc-1 (exact small integers)
    float  rateF[32];    // rate = (g+1)/16 (exact dyadic)
    double gc[32];       // -lgamma(conc) + conc*log(rate)
    double maxp;
};

__device__ __forceinline__ float bf2f(unsigned short u) {
    return __uint_as_float(((unsigned int)u) << 16);
}
__device__ __forceinline__ unsigned short f2bf(float f) {
    unsigned int u = __float_as_uint(f);
    u += 0x7FFFu + ((u >> 16) & 1u);   // RNE
    return (unsigned short)(u >> 16);
}
// HW packed f32x2 -> bf16x2 (RNE, identical to f2bf pair; 1 VALU op vs ~8)
__device__ __forceinline__ unsigned int cvtpk(float lo, float hi) {
    unsigned int r;
    asm("v_cvt_pk_bf16_f32 %0, %1, %2" : "=v"(r) : "v"(lo), "v"(hi));
    return r;
}
__device__ __forceinline__ unsigned int pack2bf(float lo, float hi) {
    return cvtpk(lo, hi);
}
__device__ __forceinline__ float ldf(const void* p, int isF32, size_t idx) {
    return isF32 ? ((const float*)p)[idx] : bf2f(((const unsigned short*)p)[idx]);
}
// async global->LDS, 16B per lane; LDS dest = wave-uniform base (+lane*16 by HW);
// global src is per-lane.
__device__ __forceinline__ void gll16(const unsigned short* g, unsigned short* l) {
    __builtin_amdgcn_global_load_lds(
        (const __attribute__((address_space(1))) unsigned int*)g,
        (__attribute__((address_space(3))) unsigned int*)l, 16, 0, 0);
}

// ---------------------------------------------------------------------------
// Workspace layout (bytes) — unchanged (35.7 MB).
// ---------------------------------------------------------------------------
constexpr size_t OFF_FLAG = 0;                                   // uint
constexpr size_t OFF_POS  = 256;                                 // bf16 [8][4096][64] (SWIZZLED, key j&7)
constexpr size_t OFF_Q    = OFF_POS + (size_t)H_*4096*64*2;
constexpr size_t OFF_K    = OFF_Q   + (size_t)B_*H_*N_*64*2;     // SWIZZLED cols (key tok&7)
constexpr size_t OFF_V    = OFF_K   + (size_t)B_*H_*N_*64*2;     // bf16 [b*h][64 d][2048 j] transposed, SWIZZLED j (key d&7)
constexpr size_t OFF_WOT  = OFF_V   + (size_t)B_*H_*N_*64*2;     // bf16 [1536][512]
constexpr size_t OFF_XB   = OFF_WOT + (size_t)DIM_*512*2;        // bf16 [4096][1536]
constexpr size_t OFF_AO   = OFF_XB;                              // bf16 [4096][512] (alias head of XB)
constexpr size_t OFF_OP   = OFF_AO + (size_t)4096*512*2;         // (unused)
constexpr size_t OFF_LP   = OFF_OP + (size_t)3*16*32*4096*2;     // (unused)
constexpr size_t OFF_WT   = OFF_XB + (size_t)4096*DIM_*2;        // bf16 [3][512][1536]
static_assert(OFF_LP + (size_t)3*16*32*64*4 <= OFF_WT + (size_t)3*512*DIM_*2, "ws overflow");

// ---------------------------------------------------------------------------
// 1) prep_kernel: fused detect + posproj + cvtw + cvtx (one dispatch).
//    Round-9: role B uses 64x64 transpose tiles (3072 -> 768 blocks; 4x work
//    per block, fewer latency-bound dispatch rounds). Grid 4352 -> 2048.
//    Roles: [0,256) posproj; [256,1024) cvtw 64x64; [1024,2048) cvtx.
// ---------------------------------------------------------------------------
__global__ __launch_bounds__(512) void prep_kernel(PosConsts pc,
                                                   const void* __restrict__ x,
                                                   const void* __restrict__ Wq, const void* __restrict__ Wk,
                                                   const void* __restrict__ Wv, const void* __restrict__ Wo,
                                                   const void* __restrict__ Wrel,
                                                   unsigned int* __restrict__ flags,
                                                   unsigned short* __restrict__ Xb,
                                                   unsigned short* __restrict__ Wt,
                                                   unsigned short* __restrict__ Wot,
                                                   unsigned short* __restrict__ posb) {
    __shared__ __align__(16) char smraw[16 * 192 * 4];   // 12288B: cnt / tile / eb overlay
    const int tid = threadIdx.x;
    const int bid = blockIdx.x;

    // ---- self-detect dtype (all blocks; ~1 cache line, L2 broadcast) ----
    int* cnt = (int*)smraw;
    int ok = 0;
    if (tid < 256) {
        unsigned short u = ((const unsigned short*)x)[2 * tid];
        int e = (u >> 7) & 0xFF;
        ok = (u == 0) || (e >= 95 && e <= 140);
    }
    cnt[tid] = ok;
    __syncthreads();
    for (int s = 256; s > 0; s >>= 1) {
        if (tid < s) cnt[tid] += cnt[tid + s];
        __syncthreads();
    }
    const int f32 = !(cnt[0] >= 192);
    __syncthreads();   // done with cnt before smem reuse
    if (bid == 0 && tid == 0) flags[0] = (unsigned int)f32;

    if (bid < 256) {
        // ---- role C: positional basis + projection (16 rows/block, FIRST) ----
        float* eb = (float*)smraw;    // [16][192]
        const int j0 = bid * 16;
        const int c  = tid;   // 0..511
        for (int u = c; u < 16 * 96; u += 512) {
            int rr = u / 96, f = u - rr * 96;
            int j = j0 + rr;
            float v = 0.f, sg = 0.f;
            if (j < NPOS) {
                int dd  = j - (N_ - 1);
                int adI = dd < 0 ? -dd : dd;
                float val;
                if (f < 32) {
                    val = exp2f(-(float)adI * pc.inv_hl[f]);
                } else if (f < 64) {
                    val = (adI < pc.widthI[f - 32]) ? 1.f : 0.f;
                } else {
                    int g = f - 64;
                    if (adI == 0) {
                        val = (float)(1e-8 / pc.maxp);
                    } else {
                        double lp = (double)pc.c1[g] * log((double)adI)
                                  - (double)pc.rateF[g] * (double)adI + pc.gc[g];
                        double p = (double)expf((float)lp) + 1e-8;
                        val = (float)(p / pc.maxp);
                    }
                }
                v  = val;
                sg = (dd > 0) ? 1.f : ((dd < 0) ? -1.f : 0.f);
            }
            eb[rr * 192 + f]      = v;
            eb[rr * 192 + 96 + f] = sg * v;
        }
        __syncthreads();
        float acc[16];
#pragma unroll
        for (int rr = 0; rr < 16; ++rr) acc[rr] = 0.f;
        for (int k = 0; k < 192; k += 4) {
            float w0 = ldf(Wrel, f32, (size_t)(k + 0) * 512 + c);
            float w1 = ldf(Wrel, f32, (size_t)(k + 1) * 512 + c);
            float w2 = ldf(Wrel, f32, (size_t)(k + 2) * 512 + c);
            float w3 = ldf(Wrel, f32, (size_t)(k + 3) * 512 + c);
#pragma unroll
            for (int rr = 0; rr < 16; ++rr) {
                float4v e = *reinterpret_cast<const float4v*>(&eb[rr * 192 + k]);
                acc[rr] += e[0] * w0;
                acc[rr] += e[1] * w1;
                acc[rr] += e[2] * w2;
                acc[rr] += e[3] * w3;
            }
        }
        int h = c >> 6, dcol = c & 63;
#pragma unroll
        for (int rr = 0; rr < 16; ++rr) {
            int j = j0 + rr;
            if (j < NPOS)
                posb[((size_t)h * 4096 + j) * 64 + (dcol ^ ((j & 7) << 3))] = f2bf(acc[rr]);
        }
    } else if (bid < 1024) {
        // ---- role B: weight transposes, 64x64 tiles -> bf16 [N][K] ----
        unsigned short (*tile)[66] = (unsigned short(*)[66])smraw;   // 8448 B
        const int idx = bid - 256;            // 0..767
        const int z = idx / 192, rem = idx % 192;
        const void* src = z == 0 ? Wq : (z == 1 ? Wk : (z == 2 ? Wv : Wo));
        unsigned short* dst = (z < 3) ? (Wt + (size_t)z * 512 * DIM_) : Wot;
        const int C     = (z < 3) ? 512 : DIM_;    // src cols (= dst rows)
        const int Rrows = (z < 3) ? DIM_ : 512;    // src rows (= dst cols)
        const int xt = C >> 6;
        const int bx = rem % xt, by = rem / xt;
        const int x0 = bx * 64, y0 = by * 64;
        const int tx2 = tid & 63, ty2 = tid >> 6;   // ty2 0..7
#pragma unroll
        for (int i = 0; i < 8; ++i)
            tile[ty2 + i * 8][tx2] = f2bf(ldf(src, f32, (size_t)(y0 + ty2 + i * 8) * C + x0 + tx2));
        __syncthreads();
#pragma unroll
        for (int i = 0; i < 8; ++i)
            dst[(size_t)(x0 + ty2 + i * 8) * Rrows + y0 + tx2] = tile[tx2][ty2 + i * 8];
    } else {
        // ---- role A: x -> bf16 contiguous ----
        const int ab = bid - 1024;   // 0..1023
        const size_t total = (size_t)4096 * DIM_;
        size_t i = ((size_t)ab * 512 + tid) * 8;
        const size_t stride = (size_t)1024 * 512 * 8;
        if (f32) {
            for (; i < total; i += stride) {
                float4v a = *reinterpret_cast<const float4v*>((const float*)x + i);
                float4v b = *reinterpret_cast<const float4v*>((const float*)x + i + 4);
                uint4 o;
                o.x = pack2bf(a[0], a[1]); o.y = pack2bf(a[2], a[3]);
                o.z = pack2bf(b[0], b[1]); o.w = pack2bf(b[2], b[3]);
                *reinterpret_cast<uint4*>(Xb + i) = o;
            }
        } else {
            for (; i < total; i += stride)
                *reinterpret_cast<uint4*>(Xb + i) =
                    *reinterpret_cast<const uint4*>((const unsigned short*)x + i);
        }
    }
}

// ---------------------------------------------------------------------------
// 64x128 GEMM core (rounds 0-5 proven): A [M][K] bf16 rm, Bt [N][K] bf16 rm.
// BK=32. Wave w: rows (w&1)*32 + mi*16, cols (w>>1)*64 + ni*16. 8 MFMA/iter.
// Round-9: back from 128x128 — grid doubles to 768 = exactly 3 blocks/CU
// (128x128's 384 blocks = 1.5/CU imbalance tax > per-block efficiency gain).
// ---------------------------------------------------------------------------
__device__ __forceinline__ void gemm64x128_core(const unsigned short* __restrict__ A,
                                                const unsigned short* __restrict__ Bt,
                                                int K, int row0, int col0,
                                                unsigned short* As, unsigned short* Bs,
                                                float4v acc[2][4]) {
    const int tid = threadIdx.x, lane = tid & 63, w = tid >> 6;
    const int l15 = lane & 15, q8 = (lane >> 4) * 8;
    const int mr0 = (w & 1) * 32, nc0 = (w >> 1) * 64;
    const int sr = lane >> 2, sc8 = (lane & 3) * 8;
    for (int k0 = 0; k0 < K; k0 += 32) {
        __syncthreads();
        gll16(&A [(size_t)(row0 + w * 16 + sr) * K + k0 + sc8],      &As[w * 512]);
        gll16(&Bt[(size_t)(col0 + w * 32 + sr) * K + k0 + sc8],      &Bs[w * 1024]);
        gll16(&Bt[(size_t)(col0 + w * 32 + 16 + sr) * K + k0 + sc8], &Bs[w * 1024 + 512]);
        __syncthreads();
        short8 a[2], b[4];
#pragma unroll
        for (int mi = 0; mi < 2; ++mi)
            a[mi] = *reinterpret_cast<const short8*>(&As[(mr0 + mi * 16 + l15) * 32 + q8]);
#pragma unroll
        for (int ni = 0; ni < 4; ++ni)
            b[ni] = *reinterpret_cast<const short8*>(&Bs[(nc0 + ni * 16 + l15) * 32 + q8]);
#pragma unroll
        for (int mi = 0; mi < 2; ++mi)
#pragma unroll
            for (int ni = 0; ni < 4; ++ni)
                acc[mi][ni] = __builtin_amdgcn_mfma_f32_16x16x32_bf16(a[mi], b[ni], acc[mi][ni], 0, 0, 0);
    }
}

// ---------------------------------------------------------------------------
// 2) QKV single dispatch, 64x128 tile, grid (12,64) = 768 blocks = 3/CU.
//    K/V written with the attn LDS swizzle pre-applied in GLOBAL memory
//    (rule #21). Q unswizzled. Q/K epilogue bounced through per-wave LDS ->
//    vector global stores (round-8 technique, mode wave-uniform).
// ---------------------------------------------------------------------------
__global__ __launch_bounds__(256) void qkv_kernel(const unsigned short* __restrict__ Xb,
                                                  const unsigned short* __restrict__ Wt,
                                                  unsigned short* __restrict__ qbuf,
                                                  unsigned short* __restrict__ kbuf,
                                                  unsigned short* __restrict__ vbuf) {
    __shared__ __align__(16) unsigned short smem[64 * 32 + 128 * 32];   // As | Bs, reused as bounce
    unsigned short* As = smem;
    unsigned short* Bs = smem + 64 * 32;
    const int row0 = blockIdx.y * 64, col0 = blockIdx.x * 128;
    float4v acc[2][4];
#pragma unroll
    for (int mi = 0; mi < 2; ++mi)
#pragma unroll
        for (int ni = 0; ni < 4; ++ni) acc[mi][ni] = (float4v){0.f, 0.f, 0.f, 0.f};
    gemm64x128_core(Xb, Wt, DIM_, row0, col0, As, Bs, acc);
    __syncthreads();   // all waves done with As/Bs before bounce reuse

    const int lane = threadIdx.x & 63, w = threadIdx.x >> 6;
    const int l15 = lane & 15, quad = lane >> 4;
    const int mr0 = (w & 1) * 32, nc0 = (w >> 1) * 64;
    const int n0 = col0 + nc0;            // wave-uniform 64-col span start
    const int mode = n0 >> 9;             // 0=Q 1=K 2=V (uniform per wave)
    const int hh = (n0 & 511) >> 6;       // head (uniform per wave)

    if (mode == 2) {
        // ---- V: transposed + swizzled, uint2 per (mi,ni) ----
#pragma unroll
        for (int mi = 0; mi < 2; ++mi)
#pragma unroll
            for (int ni = 0; ni < 4; ++ni) {
                int dd = ni * 16 + l15;
                int mb = row0 + mr0 + mi * 16 + quad * 4;
                int bb = mb >> 11, ii = mb & 2047;
                union { unsigned short us[4]; uint2 u2; } pk;
                unsigned int p0 = cvtpk(acc[mi][ni][0], acc[mi][ni][1]);
                unsigned int p1 = cvtpk(acc[mi][ni][2], acc[mi][ni][3]);
                pk.u2 = (uint2){p0, p1};
                int jb = (ii & ~63) | ((ii & 63) ^ ((dd & 7) << 3));
                *reinterpret_cast<uint2*>(
                    &vbuf[((size_t)(bb * 8 + hh) * 64 + dd) * 2048 + jb]) = pk.u2;
            }
    } else {
        // ---- Q/K: bounce via per-wave [16][72] LDS -> vector global stores ----
        unsigned short* Obuf = (mode == 0) ? qbuf : kbuf;
        const float scale = (mode == 0) ? 0.125f : 1.0f;
        unsigned short* Lw = smem + w * 16 * 72;   // 4 waves x 2304B = 9216B <= 12KB
        const int r16 = lane >> 2, c4 = (lane & 3) * 16;
#pragma unroll
        for (int mi = 0; mi < 2; ++mi) {
#pragma unroll
            for (int ni = 0; ni < 4; ++ni)
#pragma unroll
                for (int r = 0; r < 4; ++r)
                    Lw[(quad * 4 + r) * 72 + ni * 16 + l15] = f2bf(acc[mi][ni][r] * scale);
            // same-wave RAW through LDS; compiler inserts lgkmcnt waits
            int mb = row0 + mr0 + mi * 16 + r16;
            int bb = mb >> 11, tok = mb & 2047;
            unsigned short* gp = &Obuf[((size_t)(bb * 8 + hh) * N_ + tok) * 64];
            uint4 v0 = *reinterpret_cast<const uint4*>(&Lw[r16 * 72 + c4]);
            uint4 v1 = *reinterpret_cast<const uint4*>(&Lw[r16 * 72 + c4 + 8]);
            int swz2 = (mode == 1) ? ((tok & 7) << 3) : 0;
            *reinterpret_cast<uint4*>(gp + (c4 ^ swz2))       = v0;
            *reinterpret_cast<uint4*>(gp + ((c4 + 8) ^ swz2)) = v1;
        }
    }
}

// ---------------------------------------------------------------------------
// 3) MFMA flash attention, z=1 (no j-split) — byte-identical to round 8
//    (known-good 76.1 us): dbuf gll16 staging, skewed ring, swizzled frags,
//    NT=32, grid (32,16) = 512 = 2/CU, inline normalize, direct ao write.
// ---------------------------------------------------------------------------
#define SLD 72    // Pp row stride (VALU-written buffer keeps padding)
#define RST 68    // ring row stride (136B: 8B-aligned for uint2 reads at m0)

__device__ __forceinline__ void stage_lin(const unsigned short* __restrict__ g,
                                          unsigned short* s, int tid, int w) {
    gll16(g + tid * 8,        s + w * 512);
    gll16(g + 2048 + tid * 8, s + 2048 + w * 512);
}
__device__ __forceinline__ void stage_vt(const unsigned short* __restrict__ vbase,
                                         int jbase, unsigned short* s, int tid, int w) {
    {
        int L = tid * 8;        int d = L >> 6, cb = L & 63;
        gll16(vbase + (size_t)d * 2048 + jbase + cb, s + w * 512);
    }
    {
        int L = 2048 + tid * 8; int d = L >> 6, cb = L & 63;
        gll16(vbase + (size_t)d * 2048 + jbase + cb, s + 2048 + w * 512);
    }
}

__global__ __launch_bounds__(256) void attn_kernel(const unsigned int* __restrict__ flags,
                                                   const unsigned short* __restrict__ qb,
                                                   const unsigned short* __restrict__ kb,   // swizzled
                                                   const unsigned short* __restrict__ vb,   // [bh][d][j] swizzled
                                                   const unsigned short* __restrict__ posb, // swizzled key j&7
                                                   const void* __restrict__ rcb,
                                                   const void* __restrict__ rpb,
                                                   unsigned short* __restrict__ ao) {
    __shared__ __align__(16) unsigned short Ks[2][4096];     // [j][d] linear
    __shared__ __align__(16) unsigned short Ps[2][4096];     // [t][d] linear
    __shared__ __align__(16) unsigned short Vt[2][4096];     // [d][j] linear
    __shared__ __align__(16) unsigned short Pp[64 * SLD];    // [i][j] (wave-private rows)
    __shared__ __align__(8)  unsigned short Rb[128 * RST];   // skewed rel ring [(t+m)&127][m]

    const int f32 = (int)flags[0];
    const int tid = threadIdx.x;
    const int it = blockIdx.x, bh = blockIdx.y;
    const int h = bh & 7, b = bh >> 3;
    const int i0 = it * 64;
    const size_t qoff = (size_t)bh * N_ * 64;
    const size_t poff = (size_t)h * 4096 * 64;
    const unsigned short* vbase = vb + (size_t)bh * 64 * 2048;
    const int lane = tid & 63, w = tid >> 6;
    const int l15 = lane & 15, quad = lane >> 4, q8 = quad * 8;
    const int m0 = w * 16 + quad * 4;
    const int swz = (l15 & 7) << 3;

    // ---- Q fragments (qbuf unswizzled, direct 16B loads), biases folded ----
    short8 afc[2], afr[2];
#pragma unroll
    for (int kc = 0; kc < 2; ++kc) {
        uint4 qv = *reinterpret_cast<const uint4*>(
            &qb[qoff + (size_t)(i0 + w * 16 + l15) * 64 + kc * 32 + q8]);
        unsigned int uu[4] = {qv.x, qv.y, qv.z, qv.w};
        unsigned int cw[4], rw[4];
#pragma unroll
        for (int e = 0; e < 4; ++e) {
            int k = h * 64 + kc * 32 + q8 + 2 * e;
            float lo = __uint_as_float(uu[e] << 16);
            float hi = __uint_as_float(uu[e] & 0xffff0000u);
            cw[e] = pack2bf(lo + ldf(rcb, f32, k), hi + ldf(rcb, f32, k + 1));
            rw[e] = pack2bf(lo + ldf(rpb, f32, k), hi + ldf(rpb, f32, k + 1));
        }
        union { uint4 u; short8 s; } cv, rv2;
        cv.u  = (uint4){cw[0], cw[1], cw[2], cw[3]};
        rv2.u = (uint4){rw[0], rw[1], rw[2], rw[3]};
        afc[kc] = cv.s;
        afr[kc] = rv2.s;
    }

    float4v Oa[4];
#pragma unroll
    for (int nb = 0; nb < 4; ++nb) Oa[nb] = (float4v){0.f, 0.f, 0.f, 0.f};
    float lsum[4] = {0.f, 0.f, 0.f, 0.f};

    const int base0 = 1984 - i0;
    const int NT = 32;
    const int cs0 = base0;

    // ---- prologue 1: direct stage pos chunk cs0 -> Ps[0] (verbatim rows) ----
    {
        int r = tid >> 2, c16 = (tid & 3) * 16;
        const uint4* psrc = reinterpret_cast<const uint4*>(&posb[poff + (size_t)(cs0 + r) * 64 + c16]);
        *reinterpret_cast<uint4*>(&Ps[0][r * 64 + c16])     = psrc[0];
        *reinterpret_cast<uint4*>(&Ps[0][r * 64 + c16 + 8]) = psrc[1];
    }
    __syncthreads();
    // ---- seed ring from Ps[0] (swizzled fragment reads) ----
    {
        float4v R[4];
#pragma unroll
        for (int nb = 0; nb < 4; ++nb) R[nb] = (float4v){0.f, 0.f, 0.f, 0.f};
        __builtin_amdgcn_s_setprio(1);
#pragma unroll
        for (int kc = 0; kc < 2; ++kc)
#pragma unroll
            for (int nb = 0; nb < 4; ++nb) {
                short8 pb = *reinterpret_cast<const short8*>(
                    &Ps[0][(nb * 16 + l15) * 64 + ((kc * 32 + q8) ^ swz)]);
                R[nb] = __builtin_amdgcn_mfma_f32_16x16x32_bf16(afr[kc], pb, R[nb], 0, 0, 0);
            }
        __builtin_amdgcn_s_setprio(0);
#pragma unroll
        for (int nb = 0; nb < 4; ++nb) {
            int ta = cs0 + nb * 16 + l15;
            unsigned int pk0 = cvtpk(R[nb][0], R[nb][1]);
            unsigned int pk1 = cvtpk(R[nb][2], R[nb][3]);
            Rb[(size_t)((ta + m0 + 0) & 127) * RST + m0 + 0] = (unsigned short)pk0;
            Rb[(size_t)((ta + m0 + 1) & 127) * RST + m0 + 1] = (unsigned short)(pk0 >> 16);
            Rb[(size_t)((ta + m0 + 2) & 127) * RST + m0 + 2] = (unsigned short)pk1;
            Rb[(size_t)((ta + m0 + 3) & 127) * RST + m0 + 3] = (unsigned short)(pk1 >> 16);
        }
    }
    __syncthreads();   // all waves done reading Ps[0] before gll16 overwrites it

    // ---- prologue 2: async stage tile 0 (K0, pos chunk1, V0) into buf 0 ----
    stage_lin(&kb[qoff], Ks[0], tid, w);
    stage_lin(&posb[poff + (size_t)(cs0 + 64) * 64], Ps[0], tid, w);
    stage_vt(vbase, 0, Vt[0], tid, w);

    for (int u = 0; u < NT; ++u) {
        const int p = u & 1;
        const int j0 = u * 64, basej = base0 + j0;
        __syncthreads();   // drains gll16s filling buf[p]; orders prev readers of buf[p^1]

        // ---- issue next-tile gll16s into buf[p^1] (land during compute) ----
        if (u + 1 < NT) {
            stage_lin(&kb[qoff + (size_t)(j0 + 64) * 64], Ks[p ^ 1], tid, w);
            stage_lin(&posb[poff + (size_t)(cs0 + (u + 2) * 64) * 64], Ps[p ^ 1], tid, w);
            stage_vt(vbase, j0 + 64, Vt[p ^ 1], tid, w);
        }

        // ---- rel GEMM from Ps[p] -> 64 new ring cols at basej+64 ----
        {
            float4v R[4];
#pragma unroll
            for (int nb = 0; nb < 4; ++nb) R[nb] = (float4v){0.f, 0.f, 0.f, 0.f};
            __builtin_amdgcn_s_setprio(1);
#pragma unroll
            for (int kc = 0; kc < 2; ++kc)
#pragma unroll
                for (int nb = 0; nb < 4; ++nb) {
                    short8 pb = *reinterpret_cast<const short8*>(
                        &Ps[p][(nb * 16 + l15) * 64 + ((kc * 32 + q8) ^ swz)]);
                    R[nb] = __builtin_amdgcn_mfma_f32_16x16x32_bf16(afr[kc], pb, R[nb], 0, 0, 0);
                }
            __builtin_amdgcn_s_setprio(0);
            const int tb = basej + 64;
#pragma unroll
            for (int nb = 0; nb < 4; ++nb) {
                int ta = tb + nb * 16 + l15;
                unsigned int pk0 = cvtpk(R[nb][0], R[nb][1]);
                unsigned int pk1 = cvtpk(R[nb][2], R[nb][3]);
                Rb[(size_t)((ta + m0 + 0) & 127) * RST + m0 + 0] = (unsigned short)pk0;
                Rb[(size_t)((ta + m0 + 1) & 127) * RST + m0 + 1] = (unsigned short)(pk0 >> 16);
                Rb[(size_t)((ta + m0 + 2) & 127) * RST + m0 + 2] = (unsigned short)pk1;
                Rb[(size_t)((ta + m0 + 3) & 127) * RST + m0 + 3] = (unsigned short)(pk1 >> 16);
            }
        }

        // ---- content GEMM: Sacc = Qc · K^T from Ks[p] ----
        float4v Sacc[4];
#pragma unroll
        for (int nb = 0; nb < 4; ++nb) Sacc[nb] = (float4v){0.f, 0.f, 0.f, 0.f};
        __builtin_amdgcn_s_setprio(1);
#pragma unroll
        for (int kc = 0; kc < 2; ++kc)
#pragma unroll
            for (int nb = 0; nb < 4; ++nb) {
                short8 kf = *reinterpret_cast<const short8*>(
                    &Ks[p][(nb * 16 + l15) * 64 + ((kc * 32 + q8) ^ swz)]);
                Sacc[nb] = __builtin_amdgcn_mfma_f32_16x16x32_bf16(afc[kc], kf, Sacc[nb], 0, 0, 0);
            }
        __builtin_amdgcn_s_setprio(0);

        // ---- vector gather of rel diagonal, exp, pack P via cvt_pk ----
        float pv4[4][4];
#pragma unroll
        for (int nb = 0; nb < 4; ++nb) {
            const int jl = nb * 16 + l15;
            const int row = (basej + 63 + jl) & 127;
            union { uint2 u2; unsigned short us[4]; } rv;
            rv.u2 = *reinterpret_cast<const uint2*>(&Rb[(size_t)row * RST + m0]);
#pragma unroll
            for (int r = 0; r < 4; ++r) {
                float p2 = __expf(Sacc[nb][r] + bf2f(rv.us[r]));
                pv4[nb][r] = p2;
                lsum[r] += p2;
            }
        }
#pragma unroll
        for (int r = 0; r < 4; ++r) {
            unsigned short* prow = &Pp[(m0 + r) * SLD + l15];
#pragma unroll
            for (int np = 0; np < 2; ++np) {
                unsigned int pk = cvtpk(pv4[2 * np][r], pv4[2 * np + 1][r]);
                prow[(2 * np) * 16]     = (unsigned short)pk;
                prow[(2 * np + 1) * 16] = (unsigned short)(pk >> 16);
            }
        }

        // ---- PV GEMM: Oa += P · V from Vt[p] ----
        __builtin_amdgcn_s_setprio(1);
#pragma unroll
        for (int kc = 0; kc < 2; ++kc) {
            short8 pf = *reinterpret_cast<const short8*>(&Pp[(w * 16 + l15) * SLD + kc * 32 + q8]);
#pragma unroll
            for (int nb = 0; nb < 4; ++nb) {
                short8 vf = *reinterpret_cast<const short8*>(
                    &Vt[p][(nb * 16 + l15) * 64 + ((kc * 32 + q8) ^ swz)]);
                Oa[nb] = __builtin_amdgcn_mfma_f32_16x16x32_bf16(pf, vf, Oa[nb], 0, 0, 0);
            }
        }
        __builtin_amdgcn_s_setprio(0);
    }

    // ---- complete row sums, normalize, write ao directly ----
#pragma unroll
    for (int r = 0; r < 4; ++r) {
#pragma unroll
        for (int off = 1; off < 16; off <<= 1) lsum[r] += __shfl_xor(lsum[r], off);
        lsum[r] = 1.0f / lsum[r];
    }
#pragma unroll
    for (int nb = 0; nb < 4; ++nb) {
        unsigned int pk0 = cvtpk(Oa[nb][0] * lsum[0], Oa[nb][1] * lsum[1]);
        unsigned int pk1 = cvtpk(Oa[nb][2] * lsum[2], Oa[nb][3] * lsum[3]);
        unsigned short* prow = &Pp[m0 * SLD + nb * 16 + l15];
        prow[0 * SLD] = (unsigned short)pk0;
        prow[1 * SLD] = (unsigned short)(pk0 >> 16);
        prow[2 * SLD] = (unsigned short)pk1;
        prow[3 * SLD] = (unsigned short)(pk1 >> 16);
    }
    {
        const int rr2 = w * 16 + (lane >> 2), cc2 = (lane & 3) * 16;
        uint4 o0 = *reinterpret_cast<const uint4*>(&Pp[rr2 * SLD + cc2]);
        uint4 o1 = *reinterpret_cast<const uint4*>(&Pp[rr2 * SLD + cc2 + 8]);
        unsigned short* dst = &ao[((size_t)(b * N_ + i0 + rr2)) * 512 + h * 64 + cc2];
        *reinterpret_cast<uint4*>(dst)     = o0;
        *reinterpret_cast<uint4*>(dst + 8) = o1;
    }
}

// ---------------------------------------------------------------------------
// 4) out = ao @ Wo + bo, 64x128 tile, grid (12,64) = 768 blocks = 3/CU.
// ---------------------------------------------------------------------------
__global__ __launch_bounds__(256) void outproj_kernel(const unsigned int* __restrict__ flags,
                                                      const unsigned short* __restrict__ AO,
                                                      const unsigned short* __restrict__ Wot,
                                                      const void* __restrict__ bo,
                                                      void* __restrict__ out) {
    __shared__ __align__(16) unsigned short As[64 * 32];
    __shared__ __align__(16) unsigned short Bs[128 * 32];
    const int f32 = (int)flags[0];
    const int row0 = blockIdx.y * 64, col0 = blockIdx.x * 128;
    float4v acc[2][4];
#pragma unroll
    for (int mi = 0; mi < 2; ++mi)
#pragma unroll
        for (int ni = 0; ni < 4; ++ni) acc[mi][ni] = (float4v){0.f, 0.f, 0.f, 0.f};
    gemm64x128_core(AO, Wot, 512, row0, col0, As, Bs, acc);
    const int lane = threadIdx.x & 63, w = threadIdx.x >> 6;
    const int l15 = lane & 15, quad = lane >> 4;
    const int mr0 = (w & 1) * 32, nc0 = (w >> 1) * 64;
#pragma unroll
    for (int mi = 0; mi < 2; ++mi)
#pragma unroll
        for (int ni = 0; ni < 4; ++ni) {
            int n = col0 + nc0 + ni * 16 + l15;
            float bias = ldf(bo, f32, n);
#pragma unroll
            for (int r = 0; r < 4; ++r) {
                int m = row0 + mr0 + mi * 16 + quad * 4 + r;
                float v = acc[mi][ni][r] + bias;
                if (f32) ((float*)out)[(size_t)m * DIM_ + n] = v;
                else     ((unsigned short*)out)[(size_t)m * DIM_ + n] = f2bf(v);
            }
        }
}

// ---------------------------------------------------------------------------
extern "C" void kernel_launch(void* const* d_in, const int* in_sizes, int n_in,
                              void* d_out, int out_size, void* d_ws, size_t ws_size,
                              hipStream_t stream) {
    const void* x    = d_in[0];
    const void* Wq   = d_in[1];
    const void* Wk   = d_in[2];
    const void* Wv   = d_in[3];
    const void* Wo   = d_in[4];
    const void* bo   = d_in[5];
    const void* Wrel = d_in[6];
    const void* rcb  = d_in[7];
    const void* rpb  = d_in[8];

    char* ws = (char*)d_ws;
    unsigned int*   flags = (unsigned int*)(ws + OFF_FLAG);
    unsigned short* posb  = (unsigned short*)(ws + OFF_POS);
    unsigned short* qbuf  = (unsigned short*)(ws + OFF_Q);
    unsigned short* kbuf  = (unsigned short*)(ws + OFF_K);
    unsigned short* vbuf  = (unsigned short*)(ws + OFF_V);
    unsigned short* Wot   = (unsigned short*)(ws + OFF_WOT);
    unsigned short* Xb    = (unsigned short*)(ws + OFF_XB);
    unsigned short* ao    = (unsigned short*)(ws + OFF_AO);
    unsigned short* Wt    = (unsigned short*)(ws + OFF_WT);

    // Host-side constants (capture-time only; pure functions of problem consts)
    PosConsts pc;
    double maxp = 0.0;
    for (int g = 0; g < NB_; ++g) {
        double mean = 64.0 * (g + 1);
        double conc = (mean / 32.0) * (mean / 32.0);
        double rate = mean / 1024.0;
        double lgc  = std::lgamma(conc);
        double clr  = conc * std::log(rate);
        for (int ad = 1; ad < N_; ++ad) {
            double lp = (conc - 1.0) * std::log((double)ad) - rate * (double)ad - lgc + clr;
            double p  = std::exp(lp) + 1e-8;
            if (p > maxp) maxp = p;
        }
        pc.c1[g]    = (float)(conc - 1.0);   // exact small integer
        pc.rateF[g] = (float)rate;           // exact dyadic
        pc.gc[g]    = -lgc + clr;
    }
    pc.maxp = maxp;
    const double max_range = std::log((double)N_) / std::log(2.0);   // 11.0
    for (int f = 0; f < 32; ++f) {
        double t = 3.0 + (double)f * (max_range - 3.0) / 31.0;
        pc.inv_hl[f] = (float)std::exp2(-t);
        int e = f + 1;   // central-mask exponent for class index f
        pc.widthI[f] = (e >= 12) ? 0x7FFFFFFF : ((1 << e) - 1);   // adI<=2047: clamp exact
    }

    prep_kernel<<<dim3(2048), dim3(512), 0, stream>>>(pc, x, Wq, Wk, Wv, Wo, Wrel,
                                                      flags, Xb, Wt, Wot, posb);
    qkv_kernel<<<dim3(12, 64), dim3(256), 0, stream>>>(Xb, Wt, qbuf, kbuf, vbuf);
    attn_kernel<<<dim3(32, 16), dim3(256), 0, stream>>>(flags, qbuf, kbuf, vbuf, posb, rcb, rpb, ao);
    outproj_kernel<<<dim3(12, 64), dim3(256), 0, stream>>>(flags, ao, Wot, bo, d_out);
}

// Round 10
// 241.650 us; speedup vs baseline: 1.3932x; 1.0254x over previous
//
#include <hip/hip_runtime.h>
#include <stdint.h>
#include <cmath>

// Problem constants
#define B_    2
#define N_    2048
#define DIM_  1536
#define H_    8
#define NPOS  (2*N_ - 1)   // 4095 (posb padded to 4096 rows; pad row never gathered)
#define NB_   32           // basis per class (192/6)

typedef __attribute__((ext_vector_type(8))) short short8;
typedef __attribute__((ext_vector_type(4))) short short4v;
typedef __attribute__((ext_vector_type(4))) float float4v;

// Host-precomputed positional-basis constants (capture-time only)
struct PosConsts {
    float  inv_hl[32];   // 2^-t, t = 3 + f*(11-3)/31
    int    widthI[32];   // 2^(i+1)-1 clamped (central-mask widths)
    float  c1[32];       // conc-1 (exact small integers)
    float  rateF[32];    // rate = (g+1)/16 (exact dyadic)
    double gc[32];       // -lgamma(conc) + conc*log(rate)
    double maxp;
};

__device__ __forceinline__ float bf2f(unsigned short u) {
    return __uint_as_float(((unsigned int)u) << 16);
}
__device__ __forceinline__ unsigned short f2bf(float f) {
    unsigned int u = __float_as_uint(f);
    u += 0x7FFFu + ((u >> 16) & 1u);   // RNE
    return (unsigned short)(u >> 16);
}
// HW packed f32x2 -> bf16x2 (RNE, identical to f2bf pair; 1 VALU op vs ~8)
__device__ __forceinline__ unsigned int cvtpk(float lo, float hi) {
    unsigned int r;
    asm("v_cvt_pk_bf16_f32 %0, %1, %2" : "=v"(r) : "v"(lo), "v"(hi));
    return r;
}
__device__ __forceinline__ unsigned int pack2bf(float lo, float hi) {
    return cvtpk(lo, hi);
}
__device__ __forceinline__ float ldf(const void* p, int isF32, size_t idx) {
    return isF32 ? ((const float*)p)[idx] : bf2f(((const unsigned short*)p)[idx]);
}
// async global->LDS, 16B per lane; LDS dest = wave-uniform base (+lane*16 by HW);
// global src is per-lane.
__device__ __forceinline__ void gll16(const unsigned short* g, unsigned short* l) {
    __builtin_amdgcn_global_load_lds(
        (const __attribute__((address_space(1))) unsigned int*)g,
        (__attribute__((address_space(3))) unsigned int*)l, 16, 0, 0);
}

// ---------------------------------------------------------------------------
// Workspace layout (bytes) — unchanged (35.7 MB).
// ---------------------------------------------------------------------------
constexpr size_t OFF_FLAG = 0;                                   // uint
constexpr size_t OFF_POS  = 256;                                 // bf16 [8][4096][64] (SWIZZLED, key j&7, <<3)
constexpr size_t OFF_Q    = OFF_POS + (size_t)H_*4096*64*2;
constexpr size_t OFF_K    = OFF_Q   + (size_t)B_*H_*N_*64*2;     // SWIZZLED cols (key tok&7, <<3)
constexpr size_t OFF_V    = OFF_K   + (size_t)B_*H_*N_*64*2;     // bf16 [b*h][64 d][2048 j] transposed, SWIZZLED j (key d&7, <<2)
constexpr size_t OFF_WOT  = OFF_V   + (size_t)B_*H_*N_*64*2;     // bf16 [1536][512]
constexpr size_t OFF_XB   = OFF_WOT + (size_t)DIM_*512*2;        // bf16 [4096][1536]
constexpr size_t OFF_AO   = OFF_XB;                              // bf16 [4096][512] (alias head of XB)
constexpr size_t OFF_OP   = OFF_AO + (size_t)4096*512*2;         // (unused)
constexpr size_t OFF_LP   = OFF_OP + (size_t)3*16*32*4096*2;     // (unused)
constexpr size_t OFF_WT   = OFF_XB + (size_t)4096*DIM_*2;        // bf16 [3][512][1536]
static_assert(OFF_LP + (size_t)3*16*32*64*4 <= OFF_WT + (size_t)3*512*DIM_*2, "ws overflow");

// ---------------------------------------------------------------------------
// 1) prep_kernel: fused detect + posproj + cvtw + cvtx (one dispatch).
//    Roles: [0,256) posproj; [256,1024) cvtw 64x64; [1024,2048) cvtx.
// ---------------------------------------------------------------------------
__global__ __launch_bounds__(512) void prep_kernel(PosConsts pc,
                                                   const void* __restrict__ x,
                                                   const void* __restrict__ Wq, const void* __restrict__ Wk,
                                                   const void* __restrict__ Wv, const void* __restrict__ Wo,
                                                   const void* __restrict__ Wrel,
                                                   unsigned int* __restrict__ flags,
                                                   unsigned short* __restrict__ Xb,
                                                   unsigned short* __restrict__ Wt,
                                                   unsigned short* __restrict__ Wot,
                                                   unsigned short* __restrict__ posb) {
    __shared__ __align__(16) char smraw[16 * 192 * 4];   // 12288B: cnt / tile / eb overlay
    const int tid = threadIdx.x;
    const int bid = blockIdx.x;

    // ---- self-detect dtype (all blocks; ~1 cache line, L2 broadcast) ----
    int* cnt = (int*)smraw;
    int ok = 0;
    if (tid < 256) {
        unsigned short u = ((const unsigned short*)x)[2 * tid];
        int e = (u >> 7) & 0xFF;
        ok = (u == 0) || (e >= 95 && e <= 140);
    }
    cnt[tid] = ok;
    __syncthreads();
    for (int s = 256; s > 0; s >>= 1) {
        if (tid < s) cnt[tid] += cnt[tid + s];
        __syncthreads();
    }
    const int f32 = !(cnt[0] >= 192);
    __syncthreads();   // done with cnt before smem reuse
    if (bid == 0 && tid == 0) flags[0] = (unsigned int)f32;

    if (bid < 256) {
        // ---- role C: positional basis + projection (16 rows/block, FIRST) ----
        float* eb = (float*)smraw;    // [16][192]
        const int j0 = bid * 16;
        const int c  = tid;   // 0..511
        for (int u = c; u < 16 * 96; u += 512) {
            int rr = u / 96, f = u - rr * 96;
            int j = j0 + rr;
            float v = 0.f, sg = 0.f;
            if (j < NPOS) {
                int dd  = j - (N_ - 1);
                int adI = dd < 0 ? -dd : dd;
                float val;
                if (f < 32) {
                    val = exp2f(-(float)adI * pc.inv_hl[f]);
                } else if (f < 64) {
                    val = (adI < pc.widthI[f - 32]) ? 1.f : 0.f;
                } else {
                    int g = f - 64;
                    if (adI == 0) {
                        val = (float)(1e-8 / pc.maxp);
                    } else {
                        double lp = (double)pc.c1[g] * log((double)adI)
                                  - (double)pc.rateF[g] * (double)adI + pc.gc[g];
                        double p = (double)expf((float)lp) + 1e-8;
                        val = (float)(p / pc.maxp);
                    }
                }
                v  = val;
                sg = (dd > 0) ? 1.f : ((dd < 0) ? -1.f : 0.f);
            }
            eb[rr * 192 + f]      = v;
            eb[rr * 192 + 96 + f] = sg * v;
        }
        __syncthreads();
        float acc[16];
#pragma unroll
        for (int rr = 0; rr < 16; ++rr) acc[rr] = 0.f;
        for (int k = 0; k < 192; k += 4) {
            float w0 = ldf(Wrel, f32, (size_t)(k + 0) * 512 + c);
            float w1 = ldf(Wrel, f32, (size_t)(k + 1) * 512 + c);
            float w2 = ldf(Wrel, f32, (size_t)(k + 2) * 512 + c);
            float w3 = ldf(Wrel, f32, (size_t)(k + 3) * 512 + c);
#pragma unroll
            for (int rr = 0; rr < 16; ++rr) {
                float4v e = *reinterpret_cast<const float4v*>(&eb[rr * 192 + k]);
                acc[rr] += e[0] * w0;
                acc[rr] += e[1] * w1;
                acc[rr] += e[2] * w2;
                acc[rr] += e[3] * w3;
            }
        }
        int h = c >> 6, dcol = c & 63;
#pragma unroll
        for (int rr = 0; rr < 16; ++rr) {
            int j = j0 + rr;
            if (j < NPOS)
                posb[((size_t)h * 4096 + j) * 64 + (dcol ^ ((j & 7) << 3))] = f2bf(acc[rr]);
        }
    } else if (bid < 1024) {
        // ---- role B: weight transposes, 64x64 tiles -> bf16 [N][K] ----
        unsigned short (*tile)[66] = (unsigned short(*)[66])smraw;   // 8448 B
        const int idx = bid - 256;            // 0..767
        const int z = idx / 192, rem = idx % 192;
        const void* src = z == 0 ? Wq : (z == 1 ? Wk : (z == 2 ? Wv : Wo));
        unsigned short* dst = (z < 3) ? (Wt + (size_t)z * 512 * DIM_) : Wot;
        const int C     = (z < 3) ? 512 : DIM_;    // src cols (= dst rows)
        const int Rrows = (z < 3) ? DIM_ : 512;    // src rows (= dst cols)
        const int xt = C >> 6;
        const int bx = rem % xt, by = rem / xt;
        const int x0 = bx * 64, y0 = by * 64;
        const int tx2 = tid & 63, ty2 = tid >> 6;   // ty2 0..7
#pragma unroll
        for (int i = 0; i < 8; ++i)
            tile[ty2 + i * 8][tx2] = f2bf(ldf(src, f32, (size_t)(y0 + ty2 + i * 8) * C + x0 + tx2));
        __syncthreads();
#pragma unroll
        for (int i = 0; i < 8; ++i)
            dst[(size_t)(x0 + ty2 + i * 8) * Rrows + y0 + tx2] = tile[tx2][ty2 + i * 8];
    } else {
        // ---- role A: x -> bf16 contiguous ----
        const int ab = bid - 1024;   // 0..1023
        const size_t total = (size_t)4096 * DIM_;
        size_t i = ((size_t)ab * 512 + tid) * 8;
        const size_t stride = (size_t)1024 * 512 * 8;
        if (f32) {
            for (; i < total; i += stride) {
                float4v a = *reinterpret_cast<const float4v*>((const float*)x + i);
                float4v b = *reinterpret_cast<const float4v*>((const float*)x + i + 4);
                uint4 o;
                o.x = pack2bf(a[0], a[1]); o.y = pack2bf(a[2], a[3]);
                o.z = pack2bf(b[0], b[1]); o.w = pack2bf(b[2], b[3]);
                *reinterpret_cast<uint4*>(Xb + i) = o;
            }
        } else {
            for (; i < total; i += stride)
                *reinterpret_cast<uint4*>(Xb + i) =
                    *reinterpret_cast<const uint4*>((const unsigned short*)x + i);
        }
    }
}

// ---------------------------------------------------------------------------
// 64x128 GEMM core: A [M][K] bf16 rm, Bt [N][K] bf16 rm. BK=32.
// ---------------------------------------------------------------------------
__device__ __forceinline__ void gemm64x128_core(const unsigned short* __restrict__ A,
                                                const unsigned short* __restrict__ Bt,
                                                int K, int row0, int col0,
                                                unsigned short* As, unsigned short* Bs,
                                                float4v acc[2][4]) {
    const int tid = threadIdx.x, lane = tid & 63, w = tid >> 6;
    const int l15 = lane & 15, q8 = (lane >> 4) * 8;
    const int mr0 = (w & 1) * 32, nc0 = (w >> 1) * 64;
    const int sr = lane >> 2, sc8 = (lane & 3) * 8;
    for (int k0 = 0; k0 < K; k0 += 32) {
        __syncthreads();
        gll16(&A [(size_t)(row0 + w * 16 + sr) * K + k0 + sc8],      &As[w * 512]);
        gll16(&Bt[(size_t)(col0 + w * 32 + sr) * K + k0 + sc8],      &Bs[w * 1024]);
        gll16(&Bt[(size_t)(col0 + w * 32 + 16 + sr) * K + k0 + sc8], &Bs[w * 1024 + 512]);
        __syncthreads();
        short8 a[2], b[4];
#pragma unroll
        for (int mi = 0; mi < 2; ++mi)
            a[mi] = *reinterpret_cast<const short8*>(&As[(mr0 + mi * 16 + l15) * 32 + q8]);
#pragma unroll
        for (int ni = 0; ni < 4; ++ni)
            b[ni] = *reinterpret_cast<const short8*>(&Bs[(nc0 + ni * 16 + l15) * 32 + q8]);
#pragma unroll
        for (int mi = 0; mi < 2; ++mi)
#pragma unroll
            for (int ni = 0; ni < 4; ++ni)
                acc[mi][ni] = __builtin_amdgcn_mfma_f32_16x16x32_bf16(a[mi], b[ni], acc[mi][ni], 0, 0, 0);
    }
}

// ---------------------------------------------------------------------------
// 2) QKV single dispatch, 64x128 tile, grid (12,64) = 768 blocks = 3/CU.
//    kbuf: col dd -> dd ^ ((token&7)<<3)     (b128 frag reads in attn)
//    vbuf: [bh][d][j]; j-within-64 -> ^ ((d&7)<<2)   (b64 frag reads in attn)
//    Q unswizzled. Q/K epilogue bounced via per-wave LDS -> uint4 stores.
// ---------------------------------------------------------------------------
__global__ __launch_bounds__(256) void qkv_kernel(const unsigned short* __restrict__ Xb,
                                                  const unsigned short* __restrict__ Wt,
                                                  unsigned short* __restrict__ qbuf,
                                                  unsigned short* __restrict__ kbuf,
                                                  unsigned short* __restrict__ vbuf) {
    __shared__ __align__(16) unsigned short smem[64 * 32 + 128 * 32];   // As | Bs, reused as bounce
    unsigned short* As = smem;
    unsigned short* Bs = smem + 64 * 32;
    const int row0 = blockIdx.y * 64, col0 = blockIdx.x * 128;
    float4v acc[2][4];
#pragma unroll
    for (int mi = 0; mi < 2; ++mi)
#pragma unroll
        for (int ni = 0; ni < 4; ++ni) acc[mi][ni] = (float4v){0.f, 0.f, 0.f, 0.f};
    gemm64x128_core(Xb, Wt, DIM_, row0, col0, As, Bs, acc);
    __syncthreads();   // all waves done with As/Bs before bounce reuse

    const int lane = threadIdx.x & 63, w = threadIdx.x >> 6;
    const int l15 = lane & 15, quad = lane >> 4;
    const int mr0 = (w & 1) * 32, nc0 = (w >> 1) * 64;
    const int n0 = col0 + nc0;            // wave-uniform 64-col span start
    const int mode = n0 >> 9;             // 0=Q 1=K 2=V (uniform per wave)
    const int hh = (n0 & 511) >> 6;       // head (uniform per wave)

    if (mode == 2) {
        // ---- V: transposed + swizzled (key (d&7)<<2), uint2 per (mi,ni) ----
#pragma unroll
        for (int mi = 0; mi < 2; ++mi)
#pragma unroll
            for (int ni = 0; ni < 4; ++ni) {
                int dd = ni * 16 + l15;
                int mb = row0 + mr0 + mi * 16 + quad * 4;
                int bb = mb >> 11, ii = mb & 2047;
                union { unsigned short us[4]; uint2 u2; } pk;
                unsigned int p0 = cvtpk(acc[mi][ni][0], acc[mi][ni][1]);
                unsigned int p1 = cvtpk(acc[mi][ni][2], acc[mi][ni][3]);
                pk.u2 = (uint2){p0, p1};
                int jb = (ii & ~63) | ((ii & 63) ^ ((dd & 7) << 2));
                *reinterpret_cast<uint2*>(
                    &vbuf[((size_t)(bb * 8 + hh) * 64 + dd) * 2048 + jb]) = pk.u2;
            }
    } else {
        // ---- Q/K: bounce via per-wave [16][72] LDS -> vector global stores ----
        unsigned short* Obuf = (mode == 0) ? qbuf : kbuf;
        const float scale = (mode == 0) ? 0.125f : 1.0f;
        unsigned short* Lw = smem + w * 16 * 72;
        const int r16 = lane >> 2, c4 = (lane & 3) * 16;
#pragma unroll
        for (int mi = 0; mi < 2; ++mi) {
#pragma unroll
            for (int ni = 0; ni < 4; ++ni)
#pragma unroll
                for (int r = 0; r < 4; ++r)
                    Lw[(quad * 4 + r) * 72 + ni * 16 + l15] = f2bf(acc[mi][ni][r] * scale);
            int mb = row0 + mr0 + mi * 16 + r16;
            int bb = mb >> 11, tok = mb & 2047;
            unsigned short* gp = &Obuf[((size_t)(bb * 8 + hh) * N_ + tok) * 64];
            uint4 v0 = *reinterpret_cast<const uint4*>(&Lw[r16 * 72 + c4]);
            uint4 v1 = *reinterpret_cast<const uint4*>(&Lw[r16 * 72 + c4 + 8]);
            int swz2 = (mode == 1) ? ((tok & 7) << 3) : 0;
            *reinterpret_cast<uint4*>(gp + (c4 ^ swz2))       = v0;
            *reinterpret_cast<uint4*>(gp + ((c4 + 8) ^ swz2)) = v1;
        }
    }
}

// ---------------------------------------------------------------------------
// 3) MFMA flash attention — round-10 restructure: SWAPPED-OPERAND S^T +
//    j-partition. Each wave owns a 16-col (j) slice of the S/rel GEMMs:
//    K/pos frag reads 8->2 b128 per wave (kills the 4x wave duplication).
//    S^T's lane layout (m=l15, j=reg) IS the 16x16x16 MFMA B-frag layout ->
//    P stays in registers (no Pp LDS), PV = mfma(V^T-frag, P-frag) -> O^T,
//    V-frag = 4x b64 per wave (no duplication). End-of-block 4-wave O/lsum
//    reduction via LDS overlay. 2 barriers/tile (ring window is cross-wave).
//    LDS 66560 B -> 2 blocks/CU. Prefetch issued after mid barrier.
// ---------------------------------------------------------------------------
#define RST 68    // ring row stride (136B)

__device__ __forceinline__ void stage_lin(const unsigned short* __restrict__ g,
                                          unsigned short* s, int tid, int w) {
    gll16(g + tid * 8,        s + w * 512);
    gll16(g + 2048 + tid * 8, s + 2048 + w * 512);
}
__device__ __forceinline__ void stage_vt(const unsigned short* __restrict__ vbase,
                                         int jbase, unsigned short* s, int tid, int w) {
    {
        int L = tid * 8;        int d = L >> 6, cb = L & 63;
        gll16(vbase + (size_t)d * 2048 + jbase + cb, s + w * 512);
    }
    {
        int L = 2048 + tid * 8; int d = L >> 6, cb = L & 63;
        gll16(vbase + (size_t)d * 2048 + jbase + cb, s + 2048 + w * 512);
    }
}

__global__ __launch_bounds__(256, 2) void attn_kernel(const unsigned int* __restrict__ flags,
                                                      const unsigned short* __restrict__ qb,
                                                      const unsigned short* __restrict__ kb,   // swizzled <<3
                                                      const unsigned short* __restrict__ vb,   // [bh][d][j] swizzled <<2
                                                      const unsigned short* __restrict__ posb, // swizzled <<3
                                                      const void* __restrict__ rcb,
                                                      const void* __restrict__ rpb,
                                                      unsigned short* __restrict__ ao) {
    // [Ks0|Ks1|Ps0|Ps1|Vt0|Vt1|Rb] = 6*4096 + 128*68 = 33280 elem = 66560 B
    __shared__ __align__(16) unsigned short SM[33280];
    unsigned short* Rb = SM + 24576;

    const int f32 = (int)flags[0];
    const int tid = threadIdx.x;
    const int it = blockIdx.x, bh = blockIdx.y;
    const int h = bh & 7, b = bh >> 3;
    const int i0 = it * 64;
    const size_t qoff = (size_t)bh * N_ * 64;
    const size_t poff = (size_t)h * 4096 * 64;
    const unsigned short* vbase = vb + (size_t)bh * 64 * 2048;
    const int lane = tid & 63, w = tid >> 6;
    const int l15 = lane & 15, quad = lane >> 4, q8 = quad * 8, q4 = quad * 4;
    const int swz = (l15 & 7) << 3;   // K/pos b128 frag swizzle
    const int vsw = (l15 & 7) << 2;   // V b64 frag swizzle

    // ---- Q as B-fragments: ALL 64 rows per wave (afc/afr[mb][kc]), biases folded ----
    short8 afc[4][2], afr[4][2];
#pragma unroll
    for (int mb = 0; mb < 4; ++mb)
#pragma unroll
        for (int kc = 0; kc < 2; ++kc) {
            uint4 qv = *reinterpret_cast<const uint4*>(
                &qb[qoff + (size_t)(i0 + mb * 16 + l15) * 64 + kc * 32 + q8]);
            unsigned int uu[4] = {qv.x, qv.y, qv.z, qv.w};
            unsigned int cw[4], rw[4];
#pragma unroll
            for (int e = 0; e < 4; ++e) {
                int k = h * 64 + kc * 32 + q8 + 2 * e;
                float lo = __uint_as_float(uu[e] << 16);
                float hi = __uint_as_float(uu[e] & 0xffff0000u);
                cw[e] = pack2bf(lo + ldf(rcb, f32, k), hi + ldf(rcb, f32, k + 1));
                rw[e] = pack2bf(lo + ldf(rpb, f32, k), hi + ldf(rpb, f32, k + 1));
            }
            union { uint4 u; short8 s; } cv, rv2;
            cv.u  = (uint4){cw[0], cw[1], cw[2], cw[3]};
            rv2.u = (uint4){rw[0], rw[1], rw[2], rw[3]};
            afc[mb][kc] = cv.s;
            afr[mb][kc] = rv2.s;
        }

    float4v Oa[4][4];   // O^T partial: [db][mb], d = db*16+q4+r, m = mb*16+l15
#pragma unroll
    for (int db = 0; db < 4; ++db)
#pragma unroll
        for (int mb = 0; mb < 4; ++mb) Oa[db][mb] = (float4v){0.f, 0.f, 0.f, 0.f};
    float lsum[4] = {0.f, 0.f, 0.f, 0.f};   // [mb], m = mb*16+l15, partial over this wave's j

    const int base0 = 1984 - i0;
    const int NT = 32;
    const int cs0 = base0;

    unsigned short* Ks0 = SM;
    unsigned short* Ps0 = SM + 8192;
    unsigned short* Vt0 = SM + 16384;

    // ---- prologue 1: direct-stage pos window cs0 -> Ps0; seed ring (swapped) ----
    {
        int r = tid >> 2, c16 = (tid & 3) * 16;
        const uint4* psrc = reinterpret_cast<const uint4*>(&posb[poff + (size_t)(cs0 + r) * 64 + c16]);
        *reinterpret_cast<uint4*>(&Ps0[r * 64 + c16])     = psrc[0];
        *reinterpret_cast<uint4*>(&Ps0[r * 64 + c16 + 8]) = psrc[1];
    }
    __syncthreads();
    {
        float4v R[4];
#pragma unroll
        for (int mb = 0; mb < 4; ++mb) R[mb] = (float4v){0.f, 0.f, 0.f, 0.f};
        __builtin_amdgcn_s_setprio(1);
#pragma unroll
        for (int kc = 0; kc < 2; ++kc) {
            short8 pb = *reinterpret_cast<const short8*>(
                &Ps0[(w * 16 + l15) * 64 + ((kc * 32 + q8) ^ swz)]);
#pragma unroll
            for (int mb = 0; mb < 4; ++mb)
                R[mb] = __builtin_amdgcn_mfma_f32_16x16x32_bf16(pb, afr[mb][kc], R[mb], 0, 0, 0);
        }
        __builtin_amdgcn_s_setprio(0);
        // ring write, window tb = cs0: t = cs0 + w*16 + q4 + r, m = mb*16 + l15
#pragma unroll
        for (int mb = 0; mb < 4; ++mb) {
            const int col = mb * 16 + l15;
            const int R0 = cs0 + w * 16 + q4 + col;
            unsigned int pk0 = cvtpk(R[mb][0], R[mb][1]);
            unsigned int pk1 = cvtpk(R[mb][2], R[mb][3]);
            Rb[((R0 + 0) & 127) * RST + col] = (unsigned short)pk0;
            Rb[((R0 + 1) & 127) * RST + col] = (unsigned short)(pk0 >> 16);
            Rb[((R0 + 2) & 127) * RST + col] = (unsigned short)pk1;
            Rb[((R0 + 3) & 127) * RST + col] = (unsigned short)(pk1 >> 16);
        }
    }
    __syncthreads();   // seed visible; Ps0 free for restage

    // ---- prologue 2: async stage tile 0 (K0, pos window cs0+64, V0) ----
    stage_lin(&kb[qoff], Ks0, tid, w);
    stage_lin(&posb[poff + (size_t)(cs0 + 64) * 64], Ps0, tid, w);
    stage_vt(vbase, 0, Vt0, tid, w);

    for (int u = 0; u < NT; ++u) {
        const int p = u & 1;
        const int j0 = u * 64, basej = base0 + j0;
        unsigned short* Ksp = SM + p * 4096;
        unsigned short* Psp = SM + 8192 + p * 4096;
        unsigned short* Vtp = SM + 16384 + p * 4096;
        __syncthreads();   // buf[p] staged (drains prefetch)

        // ---- content S^T + rel R^T (swapped operands, wave owns 16 j-cols) ----
        float4v St[4], R[4];
#pragma unroll
        for (int mb = 0; mb < 4; ++mb) {
            St[mb] = (float4v){0.f, 0.f, 0.f, 0.f};
            R[mb]  = (float4v){0.f, 0.f, 0.f, 0.f};
        }
        __builtin_amdgcn_s_setprio(1);
#pragma unroll
        for (int kc = 0; kc < 2; ++kc) {
            short8 kf = *reinterpret_cast<const short8*>(
                &Ksp[(w * 16 + l15) * 64 + ((kc * 32 + q8) ^ swz)]);
            short8 pb = *reinterpret_cast<const short8*>(
                &Psp[(w * 16 + l15) * 64 + ((kc * 32 + q8) ^ swz)]);
#pragma unroll
            for (int mb = 0; mb < 4; ++mb) {
                St[mb] = __builtin_amdgcn_mfma_f32_16x16x32_bf16(kf, afc[mb][kc], St[mb], 0, 0, 0);
                R[mb]  = __builtin_amdgcn_mfma_f32_16x16x32_bf16(pb, afr[mb][kc], R[mb], 0, 0, 0);
            }
        }
        __builtin_amdgcn_s_setprio(0);

        // ---- ring write, window tb = basej+64 ----
        {
            const int tb = basej + 64;
#pragma unroll
            for (int mb = 0; mb < 4; ++mb) {
                const int col = mb * 16 + l15;
                const int R0 = tb + w * 16 + q4 + col;
                unsigned int pk0 = cvtpk(R[mb][0], R[mb][1]);
                unsigned int pk1 = cvtpk(R[mb][2], R[mb][3]);
                Rb[((R0 + 0) & 127) * RST + col] = (unsigned short)pk0;
                Rb[((R0 + 1) & 127) * RST + col] = (unsigned short)(pk0 >> 16);
                Rb[((R0 + 2) & 127) * RST + col] = (unsigned short)pk1;
                Rb[((R0 + 3) & 127) * RST + col] = (unsigned short)(pk1 >> 16);
            }
        }
        __syncthreads();   // fresh ring window visible cross-wave

        // ---- prefetch next tile (in flight across softmax+PV) ----
        if (u + 1 < NT) {
            stage_lin(&kb[qoff + (size_t)(j0 + 64) * 64], SM + (p ^ 1) * 4096, tid, w);
            stage_lin(&posb[poff + (size_t)(cs0 + (u + 2) * 64) * 64], SM + 8192 + (p ^ 1) * 4096, tid, w);
            stage_vt(vbase, j0 + 64, SM + 16384 + (p ^ 1) * 4096, tid, w);
        }

        // ---- gather rel diag, exp, pack P as PV B-frags (in regs) ----
        short4v pb16[4];
        const int G0 = basej + 63 + w * 16 + q4;
#pragma unroll
        for (int mb = 0; mb < 4; ++mb) {
            const int col = mb * 16 + l15;
            float pv[4];
#pragma unroll
            for (int r = 0; r < 4; ++r) {
                float rel = bf2f(Rb[((G0 + r) & 127) * RST + col]);
                float p2 = __expf(St[mb][r] + rel);
                lsum[mb] += p2;
                pv[r] = p2;
            }
            union { unsigned int u2[2]; short4v s; } pk;
            pk.u2[0] = cvtpk(pv[0], pv[1]);
            pk.u2[1] = cvtpk(pv[2], pv[3]);
            pb16[mb] = pk.s;
        }

        // ---- PV: O^T += V^T-frag x P-frag (16x16x16, K = wave's 16 j) ----
        __builtin_amdgcn_s_setprio(1);
#pragma unroll
        for (int db = 0; db < 4; ++db) {
            short4v vf = *reinterpret_cast<const short4v*>(
                &Vtp[(db * 16 + l15) * 64 + ((w * 16 + q4) ^ vsw)]);
#pragma unroll
            for (int mb = 0; mb < 4; ++mb)
                Oa[db][mb] = __builtin_amdgcn_mfma_f32_16x16x16bf16_1k(vf, pb16[mb], Oa[db][mb], 0, 0, 0);
        }
        __builtin_amdgcn_s_setprio(0);
    }

    // ---- wave-local lsum: reduce over quads (j within wave) ----
#pragma unroll
    for (int mb = 0; mb < 4; ++mb) {
        lsum[mb] += __shfl_xor(lsum[mb], 16);
        lsum[mb] += __shfl_xor(lsum[mb], 32);
    }

    // ---- cross-wave O^T + lsum reduction via LDS overlay ----
    __syncthreads();   // all tile LDS use done
    float* Of = (float*)SM;             // [64 d][65] f32 = 16640 B
    float* Ls = (float*)(SM + 8320);    // byte 16640: [4 w][64 m] f32
#pragma unroll
    for (int ww = 0; ww < 4; ++ww) {
        if (w == ww) {
            if (quad == 0) {
#pragma unroll
                for (int mb = 0; mb < 4; ++mb) Ls[ww * 64 + mb * 16 + l15] = lsum[mb];
            }
#pragma unroll
            for (int db = 0; db < 4; ++db)
#pragma unroll
                for (int mb = 0; mb < 4; ++mb)
#pragma unroll
                    for (int r = 0; r < 4; ++r) {
                        float* slot = &Of[(db * 16 + q4 + r) * 65 + mb * 16 + l15];
                        if (ww == 0) *slot = Oa[db][mb][r];
                        else         *slot += Oa[db][mb][r];
                    }
        }
        __syncthreads();
    }

    // ---- normalize + transpose-write ao[b][i][h*64+d] ----
    {
        const int m = tid >> 2, c0 = (tid & 3) * 16;
        float inv = 1.0f / (Ls[m] + Ls[64 + m] + Ls[128 + m] + Ls[192 + m]);
        unsigned int ou[8];
#pragma unroll
        for (int e = 0; e < 8; ++e) {
            float lo = Of[(c0 + 2 * e) * 65 + m] * inv;
            float hi = Of[(c0 + 2 * e + 1) * 65 + m] * inv;
            ou[e] = cvtpk(lo, hi);
        }
        unsigned short* dst = &ao[((size_t)(b * N_ + i0 + m)) * 512 + h * 64 + c0];
        *reinterpret_cast<uint4*>(dst)     = (uint4){ou[0], ou[1], ou[2], ou[3]};
        *reinterpret_cast<uint4*>(dst + 8) = (uint4){ou[4], ou[5], ou[6], ou[7]};
    }
}

// ---------------------------------------------------------------------------
// 4) out = ao @ Wo + bo, 64x128 tile, grid (12,64).
// ---------------------------------------------------------------------------
__global__ __launch_bounds__(256) void outproj_kernel(const unsigned int* __restrict__ flags,
                                                      const unsigned short* __restrict__ AO,
                                                      const unsigned short* __restrict__ Wot,
                                                      const void* __restrict__ bo,
                                                      void* __restrict__ out) {
    __shared__ __align__(16) unsigned short As[64 * 32];
    __shared__ __align__(16) unsigned short Bs[128 * 32];
    const int f32 = (int)flags[0];
    const int row0 = blockIdx.y * 64, col0 = blockIdx.x * 128;
    float4v acc[2][4];
#pragma unroll
    for (int mi = 0; mi < 2; ++mi)
#pragma unroll
        for (int ni = 0; ni < 4; ++ni) acc[mi][ni] = (float4v){0.f, 0.f, 0.f, 0.f};
    gemm64x128_core(AO, Wot, 512, row0, col0, As, Bs, acc);
    const int lane = threadIdx.x & 63, w = threadIdx.x >> 6;
    const int l15 = lane & 15, quad = lane >> 4;
    const int mr0 = (w & 1) * 32, nc0 = (w >> 1) * 64;
#pragma unroll
    for (int mi = 0; mi < 2; ++mi)
#pragma unroll
        for (int ni = 0; ni < 4; ++ni) {
            int n = col0 + nc0 + ni * 16 + l15;
            float bias = ldf(bo, f32, n);
#pragma unroll
            for (int r = 0; r < 4; ++r) {
                int m = row0 + mr0 + mi * 16 + quad * 4 + r;
                float v = acc[mi][ni][r] + bias;
                if (f32) ((float*)out)[(size_t)m * DIM_ + n] = v;
                else     ((unsigned short*)out)[(size_t)m * DIM_ + n] = f2bf(v);
            }
        }
}

// ---------------------------------------------------------------------------
extern "C" void kernel_launch(void* const* d_in, const int* in_sizes, int n_in,
                              void* d_out, int out_size, void* d_ws, size_t ws_size,
                              hipStream_t stream) {
    const void* x    = d_in[0];
    const void* Wq   = d_in[1];
    const void* Wk   = d_in[2];
    const void* Wv   = d_in[3];
    const void* Wo   = d_in[4];
    const void* bo   = d_in[5];
    const void* Wrel = d_in[6];
    const void* rcb  = d_in[7];
    const void* rpb  = d_in[8];

    char* ws = (char*)d_ws;
    unsigned int*   flags = (unsigned int*)(ws + OFF_FLAG);
    unsigned short* posb  = (unsigned short*)(ws + OFF_POS);
    unsigned short* qbuf  = (unsigned short*)(ws + OFF_Q);
    unsigned short* kbuf  = (unsigned short*)(ws + OFF_K);
    unsigned short* vbuf  = (unsigned short*)(ws + OFF_V);
    unsigned short* Wot   = (unsigned short*)(ws + OFF_WOT);
    unsigned short* Xb    = (unsigned short*)(ws + OFF_XB);
    unsigned short* ao    = (unsigned short*)(ws + OFF_AO);
    unsigned short* Wt    = (unsigned short*)(ws + OFF_WT);

    // Host-side constants (capture-time only; pure functions of problem consts)
    PosConsts pc;
    double maxp = 0.0;
    for (int g = 0; g < NB_; ++g) {
        double mean = 64.0 * (g + 1);
        double conc = (mean / 32.0) * (mean / 32.0);
        double rate = mean / 1024.0;
        double lgc  = std::lgamma(conc);
        double clr  = conc * std::log(rate);
        for (int ad = 1; ad < N_; ++ad) {
            double lp = (conc - 1.0) * std::log((double)ad) - rate * (double)ad - lgc + clr;
            double p  = std::exp(lp) + 1e-8;
            if (p > maxp) maxp = p;
        }
        pc.c1[g]    = (float)(conc - 1.0);   // exact small integer
        pc.rateF[g] = (float)rate;           // exact dyadic
        pc.gc[g]    = -lgc + clr;
    }
    pc.maxp = maxp;
    const double max_range = std::log((double)N_) / std::log(2.0);   // 11.0
    for (int f = 0; f < 32; ++f) {
        double t = 3.0 + (double)f * (max_range - 3.0) / 31.0;
        pc.inv_hl[f] = (float)std::exp2(-t);
        int e = f + 1;   // central-mask exponent for class index f
        pc.widthI[f] = (e >= 12) ? 0x7FFFFFFF : ((1 << e) - 1);   // adI<=2047: clamp exact
    }

    prep_kernel<<<dim3(2048), dim3(512), 0, stream>>>(pc, x, Wq, Wk, Wv, Wo, Wrel,
                                                      flags, Xb, Wt, Wot, posb);
    qkv_kernel<<<dim3(12, 64), dim3(256), 0, stream>>>(Xb, Wt, qbuf, kbuf, vbuf);
    attn_kernel<<<dim3(32, 16), dim3(256), 0, stream>>>(flags, qbuf, kbuf, vbuf, posb, rcb, rpb, ao);
    outproj_kernel<<<dim3(12, 64), dim3(256), 0, stream>>>(flags, ao, Wot, bo, d_out);
}

// Round 12
// 239.244 us; speedup vs baseline: 1.4072x; 1.0101x over previous
//
#include <hip/hip_runtime.h>
#include <stdint.h>
#include <cmath>

// Problem constants
#define B_    2
#define N_    2048
#define DIM_  1536
#define H_    8
#define NPOS  (2*N_ - 1)   // 4095 (posb padded to 4096 rows; pad row never gathered)
#define NB_   32           // basis per class (192/6)

typedef __attribute__((ext_vector_type(8))) short short8;
typedef __attribute__((ext_vector_type(4))) short short4v;
typedef __attribute__((ext_vector_type(4))) float float4v;

// Host-precomputed positional-basis constants (capture-time only)
struct PosConsts {
    float  inv_hl[32];   // 2^-t, t = 3 + f*(11-3)/31
    int    widthI[32];   // 2^(i+1)-1 clamped (central-mask widths)
    float  c1[32];       // conc-1 (exact small integers)
    float  rateF[32];    // rate = (g+1)/16 (exact dyadic)
    double gc[32];       // -lgamma(conc) + conc*log(rate)
    double maxp;
};

__device__ __forceinline__ float bf2f(unsigned short u) {
    return __uint_as_float(((unsigned int)u) << 16);
}
__device__ __forceinline__ unsigned short f2bf(float f) {
    unsigned int u = __float_as_uint(f);
    u += 0x7FFFu + ((u >> 16) & 1u);   // RNE
    return (unsigned short)(u >> 16);
}
// HW packed f32x2 -> bf16x2 (RNE, identical to f2bf pair; 1 VALU op vs ~8)
__device__ __forceinline__ unsigned int cvtpk(float lo, float hi) {
    unsigned int r;
    asm("v_cvt_pk_bf16_f32 %0, %1, %2" : "=v"(r) : "v"(lo), "v"(hi));
    return r;
}
__device__ __forceinline__ unsigned int pack2bf(float lo, float hi) {
    return cvtpk(lo, hi);
}
__device__ __forceinline__ float ldf(const void* p, int isF32, size_t idx) {
    return isF32 ? ((const float*)p)[idx] : bf2f(((const unsigned short*)p)[idx]);
}
// async global->LDS, 16B per lane; LDS dest = wave-uniform base (+lane*16 by HW);
// global src is per-lane.
__device__ __forceinline__ void gll16(const unsigned short* g, unsigned short* l) {
    __builtin_amdgcn_global_load_lds(
        (const __attribute__((address_space(1))) unsigned int*)g,
        (__attribute__((address_space(3))) unsigned int*)l, 16, 0, 0);
}

// ---------------------------------------------------------------------------
// Workspace layout (bytes) — unchanged (35.7 MB).
// ---------------------------------------------------------------------------
constexpr size_t OFF_FLAG = 0;                                   // uint
constexpr size_t OFF_POS  = 256;                                 // bf16 [8][4096][64] (SWIZZLED, key j&7, <<3)
constexpr size_t OFF_Q    = OFF_POS + (size_t)H_*4096*64*2;
constexpr size_t OFF_K    = OFF_Q   + (size_t)B_*H_*N_*64*2;     // SWIZZLED cols (key tok&7, <<3)
constexpr size_t OFF_V    = OFF_K   + (size_t)B_*H_*N_*64*2;     // bf16 [b*h][64 d][2048 j] transposed, SWIZZLED j (key d&7, <<2)
constexpr size_t OFF_WOT  = OFF_V   + (size_t)B_*H_*N_*64*2;     // bf16 [1536][512]
constexpr size_t OFF_XB   = OFF_WOT + (size_t)DIM_*512*2;        // bf16 [4096][1536]
constexpr size_t OFF_AO   = OFF_XB;                              // bf16 [4096][512] (alias head of XB)
constexpr size_t OFF_OP   = OFF_AO + (size_t)4096*512*2;         // (unused)
constexpr size_t OFF_LP   = OFF_OP + (size_t)3*16*32*4096*2;     // (unused)
constexpr size_t OFF_WT   = OFF_XB + (size_t)4096*DIM_*2;        // bf16 [3][512][1536]
static_assert(OFF_LP + (size_t)3*16*32*64*4 <= OFF_WT + (size_t)3*512*DIM_*2, "ws overflow");

// ---------------------------------------------------------------------------
// 1) prep_kernel: fused detect + posproj + cvtw + cvtx (one dispatch).
//    Roles: [0,256) posproj; [256,1024) cvtw 64x64; [1024,2048) cvtx.
// ---------------------------------------------------------------------------
__global__ __launch_bounds__(512) void prep_kernel(PosConsts pc,
                                                   const void* __restrict__ x,
                                                   const void* __restrict__ Wq, const void* __restrict__ Wk,
                                                   const void* __restrict__ Wv, const void* __restrict__ Wo,
                                                   const void* __restrict__ Wrel,
                                                   unsigned int* __restrict__ flags,
                                                   unsigned short* __restrict__ Xb,
                                                   unsigned short* __restrict__ Wt,
                                                   unsigned short* __restrict__ Wot,
                                                   unsigned short* __restrict__ posb) {
    __shared__ __align__(16) char smraw[16 * 192 * 4];   // 12288B: cnt / tile / eb overlay
    const int tid = threadIdx.x;
    const int bid = blockIdx.x;

    // ---- self-detect dtype (all blocks; ~1 cache line, L2 broadcast) ----
    int* cnt = (int*)smraw;
    int ok = 0;
    if (tid < 256) {
        unsigned short u = ((const unsigned short*)x)[2 * tid];
        int e = (u >> 7) & 0xFF;
        ok = (u == 0) || (e >= 95 && e <= 140);
    }
    cnt[tid] = ok;
    __syncthreads();
    for (int s = 256; s > 0; s >>= 1) {
        if (tid < s) cnt[tid] += cnt[tid + s];
        __syncthreads();
    }
    const int f32 = !(cnt[0] >= 192);
    __syncthreads();   // done with cnt before smem reuse
    if (bid == 0 && tid == 0) flags[0] = (unsigned int)f32;

    if (bid < 256) {
        // ---- role C: positional basis + projection (16 rows/block, FIRST) ----
        float* eb = (float*)smraw;    // [16][192]
        const int j0 = bid * 16;
        const int c  = tid;   // 0..511
        for (int u = c; u < 16 * 96; u += 512) {
            int rr = u / 96, f = u - rr * 96;
            int j = j0 + rr;
            float v = 0.f, sg = 0.f;
            if (j < NPOS) {
                int dd  = j - (N_ - 1);
                int adI = dd < 0 ? -dd : dd;
                float val;
                if (f < 32) {
                    val = exp2f(-(float)adI * pc.inv_hl[f]);
                } else if (f < 64) {
                    val = (adI < pc.widthI[f - 32]) ? 1.f : 0.f;
                } else {
                    int g = f - 64;
                    if (adI == 0) {
                        val = (float)(1e-8 / pc.maxp);
                    } else {
                        double lp = (double)pc.c1[g] * log((double)adI)
                                  - (double)pc.rateF[g] * (double)adI + pc.gc[g];
                        double p = (double)expf((float)lp) + 1e-8;
                        val = (float)(p / pc.maxp);
                    }
                }
                v  = val;
                sg = (dd > 0) ? 1.f : ((dd < 0) ? -1.f : 0.f);
            }
            eb[rr * 192 + f]      = v;
            eb[rr * 192 + 96 + f] = sg * v;
        }
        __syncthreads();
        float acc[16];
#pragma unroll
        for (int rr = 0; rr < 16; ++rr) acc[rr] = 0.f;
        for (int k = 0; k < 192; k += 4) {
            float w0 = ldf(Wrel, f32, (size_t)(k + 0) * 512 + c);
            float w1 = ldf(Wrel, f32, (size_t)(k + 1) * 512 + c);
            float w2 = ldf(Wrel, f32, (size_t)(k + 2) * 512 + c);
            float w3 = ldf(Wrel, f32, (size_t)(k + 3) * 512 + c);
#pragma unroll
            for (int rr = 0; rr < 16; ++rr) {
                float4v e = *reinterpret_cast<const float4v*>(&eb[rr * 192 + k]);
                acc[rr] += e[0] * w0;
                acc[rr] += e[1] * w1;
                acc[rr] += e[2] * w2;
                acc[rr] += e[3] * w3;
            }
        }
        int h = c >> 6, dcol = c & 63;
#pragma unroll
        for (int rr = 0; rr < 16; ++rr) {
            int j = j0 + rr;
            if (j < NPOS)
                posb[((size_t)h * 4096 + j) * 64 + (dcol ^ ((j & 7) << 3))] = f2bf(acc[rr]);
        }
    } else if (bid < 1024) {
        // ---- role B: weight transposes, 64x64 tiles -> bf16 [N][K] ----
        unsigned short (*tile)[66] = (unsigned short(*)[66])smraw;   // 8448 B
        const int idx = bid - 256;            // 0..767
        const int z = idx / 192, rem = idx % 192;
        const void* src = z == 0 ? Wq : (z == 1 ? Wk : (z == 2 ? Wv : Wo));
        unsigned short* dst = (z < 3) ? (Wt + (size_t)z * 512 * DIM_) : Wot;
        const int C     = (z < 3) ? 512 : DIM_;    // src cols (= dst rows)
        const int Rrows = (z < 3) ? DIM_ : 512;    // src rows (= dst cols)
        const int xt = C >> 6;
        const int bx = rem % xt, by = rem / xt;
        const int x0 = bx * 64, y0 = by * 64;
        const int tx2 = tid & 63, ty2 = tid >> 6;   // ty2 0..7
#pragma unroll
        for (int i = 0; i < 8; ++i)
            tile[ty2 + i * 8][tx2] = f2bf(ldf(src, f32, (size_t)(y0 + ty2 + i * 8) * C + x0 + tx2));
        __syncthreads();
#pragma unroll
        for (int i = 0; i < 8; ++i)
            dst[(size_t)(x0 + ty2 + i * 8) * Rrows + y0 + tx2] = tile[tx2][ty2 + i * 8];
    } else {
        // ---- role A: x -> bf16 contiguous ----
        const int ab = bid - 1024;   // 0..1023
        const size_t total = (size_t)4096 * DIM_;
        size_t i = ((size_t)ab * 512 + tid) * 8;
        const size_t stride = (size_t)1024 * 512 * 8;
        if (f32) {
            for (; i < total; i += stride) {
                float4v a = *reinterpret_cast<const float4v*>((const float*)x + i);
                float4v b = *reinterpret_cast<const float4v*>((const float*)x + i + 4);
                uint4 o;
                o.x = pack2bf(a[0], a[1]); o.y = pack2bf(a[2], a[3]);
                o.z = pack2bf(b[0], b[1]); o.w = pack2bf(b[2], b[3]);
                *reinterpret_cast<uint4*>(Xb + i) = o;
            }
        } else {
            for (; i < total; i += stride)
                *reinterpret_cast<uint4*>(Xb + i) =
                    *reinterpret_cast<const uint4*>((const unsigned short*)x + i);
        }
    }
}

// ---------------------------------------------------------------------------
// 64x128 GEMM core: A [M][K] bf16 rm, Bt [N][K] bf16 rm. BK=32.
// ---------------------------------------------------------------------------
__device__ __forceinline__ void gemm64x128_core(const unsigned short* __restrict__ A,
                                                const unsigned short* __restrict__ Bt,
                                                int K, int row0, int col0,
                                                unsigned short* As, unsigned short* Bs,
                                                float4v acc[2][4]) {
    const int tid = threadIdx.x, lane = tid & 63, w = tid >> 6;
    const int l15 = lane & 15, q8 = (lane >> 4) * 8;
    const int mr0 = (w & 1) * 32, nc0 = (w >> 1) * 64;
    const int sr = lane >> 2, sc8 = (lane & 3) * 8;
    for (int k0 = 0; k0 < K; k0 += 32) {
        __syncthreads();
        gll16(&A [(size_t)(row0 + w * 16 + sr) * K + k0 + sc8],      &As[w * 512]);
        gll16(&Bt[(size_t)(col0 + w * 32 + sr) * K + k0 + sc8],      &Bs[w * 1024]);
        gll16(&Bt[(size_t)(col0 + w * 32 + 16 + sr) * K + k0 + sc8], &Bs[w * 1024 + 512]);
        __syncthreads();
        short8 a[2], b[4];
#pragma unroll
        for (int mi = 0; mi < 2; ++mi)
            a[mi] = *reinterpret_cast<const short8*>(&As[(mr0 + mi * 16 + l15) * 32 + q8]);
#pragma unroll
        for (int ni = 0; ni < 4; ++ni)
            b[ni] = *reinterpret_cast<const short8*>(&Bs[(nc0 + ni * 16 + l15) * 32 + q8]);
#pragma unroll
        for (int mi = 0; mi < 2; ++mi)
#pragma unroll
            for (int ni = 0; ni < 4; ++ni)
                acc[mi][ni] = __builtin_amdgcn_mfma_f32_16x16x32_bf16(a[mi], b[ni], acc[mi][ni], 0, 0, 0);
    }
}

// ---------------------------------------------------------------------------
// 2) QKV single dispatch, 64x128 tile, grid (12,64) = 768 blocks = 3/CU.
//    kbuf: col dd -> dd ^ ((token&7)<<3)     (b128 frag reads in attn)
//    vbuf: [bh][d][j]; j-within-64 -> ^ ((d&7)<<2)   (b64 frag reads in attn)
//    Q unswizzled. Q/K epilogue bounced via per-wave LDS -> uint4 stores.
// ---------------------------------------------------------------------------
__global__ __launch_bounds__(256) void qkv_kernel(const unsigned short* __restrict__ Xb,
                                                  const unsigned short* __restrict__ Wt,
                                                  unsigned short* __restrict__ qbuf,
                                                  unsigned short* __restrict__ kbuf,
                                                  unsigned short* __restrict__ vbuf) {
    __shared__ __align__(16) unsigned short smem[64 * 32 + 128 * 32];   // As | Bs, reused as bounce
    unsigned short* As = smem;
    unsigned short* Bs = smem + 64 * 32;
    const int row0 = blockIdx.y * 64, col0 = blockIdx.x * 128;
    float4v acc[2][4];
#pragma unroll
    for (int mi = 0; mi < 2; ++mi)
#pragma unroll
        for (int ni = 0; ni < 4; ++ni) acc[mi][ni] = (float4v){0.f, 0.f, 0.f, 0.f};
    gemm64x128_core(Xb, Wt, DIM_, row0, col0, As, Bs, acc);
    __syncthreads();   // all waves done with As/Bs before bounce reuse

    const int lane = threadIdx.x & 63, w = threadIdx.x >> 6;
    const int l15 = lane & 15, quad = lane >> 4;
    const int mr0 = (w & 1) * 32, nc0 = (w >> 1) * 64;
    const int n0 = col0 + nc0;            // wave-uniform 64-col span start
    const int mode = n0 >> 9;             // 0=Q 1=K 2=V (uniform per wave)
    const int hh = (n0 & 511) >> 6;       // head (uniform per wave)

    if (mode == 2) {
        // ---- V: transposed + swizzled (key (d&7)<<2), uint2 per (mi,ni) ----
#pragma unroll
        for (int mi = 0; mi < 2; ++mi)
#pragma unroll
            for (int ni = 0; ni < 4; ++ni) {
                int dd = ni * 16 + l15;
                int mb = row0 + mr0 + mi * 16 + quad * 4;
                int bb = mb >> 11, ii = mb & 2047;
                union { unsigned short us[4]; uint2 u2; } pk;
                unsigned int p0 = cvtpk(acc[mi][ni][0], acc[mi][ni][1]);
                unsigned int p1 = cvtpk(acc[mi][ni][2], acc[mi][ni][3]);
                pk.u2 = (uint2){p0, p1};
                int jb = (ii & ~63) | ((ii & 63) ^ ((dd & 7) << 2));
                *reinterpret_cast<uint2*>(
                    &vbuf[((size_t)(bb * 8 + hh) * 64 + dd) * 2048 + jb]) = pk.u2;
            }
    } else {
        // ---- Q/K: bounce via per-wave [16][72] LDS -> vector global stores ----
        unsigned short* Obuf = (mode == 0) ? qbuf : kbuf;
        const float scale = (mode == 0) ? 0.125f : 1.0f;
        unsigned short* Lw = smem + w * 16 * 72;
        const int r16 = lane >> 2, c4 = (lane & 3) * 16;
#pragma unroll
        for (int mi = 0; mi < 2; ++mi) {
#pragma unroll
            for (int ni = 0; ni < 4; ++ni)
#pragma unroll
                for (int r = 0; r < 4; ++r)
                    Lw[(quad * 4 + r) * 72 + ni * 16 + l15] = f2bf(acc[mi][ni][r] * scale);
            int mb = row0 + mr0 + mi * 16 + r16;
            int bb = mb >> 11, tok = mb & 2047;
            unsigned short* gp = &Obuf[((size_t)(bb * 8 + hh) * N_ + tok) * 64];
            uint4 v0 = *reinterpret_cast<const uint4*>(&Lw[r16 * 72 + c4]);
            uint4 v1 = *reinterpret_cast<const uint4*>(&Lw[r16 * 72 + c4 + 8]);
            int swz2 = (mode == 1) ? ((tok & 7) << 3) : 0;
            *reinterpret_cast<uint4*>(gp + (c4 ^ swz2))       = v0;
            *reinterpret_cast<uint4*>(gp + ((c4 + 8) ^ swz2)) = v1;
        }
    }
}

// ---------------------------------------------------------------------------
// 3) MFMA flash attention — round-10 verified structure: swapped-operand S^T
//    + j-partition (wave owns 16 j-cols; K/pos frag reads 2 b128/wave),
//    P in registers (S^T lane layout = 16x16x16 B-frag), PV accumulates O^T,
//    skewed rel ring [(t+m)&127][m] (row-major, RST=68), dbuf gll16 staging,
//    end-of-block cross-wave O/lsum reduction, inline normalize, direct ao.
//    LDS 66560 B -> 2 blocks/CU.
// ---------------------------------------------------------------------------
#define RST 68    // ring row stride (136B)

__device__ __forceinline__ void stage_lin(const unsigned short* __restrict__ g,
                                          unsigned short* s, int tid, int w) {
    gll16(g + tid * 8,        s + w * 512);
    gll16(g + 2048 + tid * 8, s + 2048 + w * 512);
}
__device__ __forceinline__ void stage_vt(const unsigned short* __restrict__ vbase,
                                         int jbase, unsigned short* s, int tid, int w) {
    {
        int L = tid * 8;        int d = L >> 6, cb = L & 63;
        gll16(vbase + (size_t)d * 2048 + jbase + cb, s + w * 512);
    }
    {
        int L = 2048 + tid * 8; int d = L >> 6, cb = L & 63;
        gll16(vbase + (size_t)d * 2048 + jbase + cb, s + 2048 + w * 512);
    }
}

__global__ __launch_bounds__(256, 2) void attn_kernel(const unsigned int* __restrict__ flags,
                                                      const unsigned short* __restrict__ qb,
                                                      const unsigned short* __restrict__ kb,   // swizzled <<3
                                                      const unsigned short* __restrict__ vb,   // [bh][d][j] swizzled <<2
                                                      const unsigned short* __restrict__ posb, // swizzled <<3
                                                      const void* __restrict__ rcb,
                                                      const void* __restrict__ rpb,
                                                      unsigned short* __restrict__ ao) {
    // [Ks0|Ks1|Ps0|Ps1|Vt0|Vt1|Rb] = 6*4096 + 128*68 = 33280 elem = 66560 B
    __shared__ __align__(16) unsigned short SM[33280];
    unsigned short* Rb = SM + 24576;

    const int f32 = (int)flags[0];
    const int tid = threadIdx.x;
    const int it = blockIdx.x, bh = blockIdx.y;
    const int h = bh & 7, b = bh >> 3;
    const int i0 = it * 64;
    const size_t qoff = (size_t)bh * N_ * 64;
    const size_t poff = (size_t)h * 4096 * 64;
    const unsigned short* vbase = vb + (size_t)bh * 64 * 2048;
    const int lane = tid & 63, w = tid >> 6;
    const int l15 = lane & 15, quad = lane >> 4, q8 = quad * 8, q4 = quad * 4;
    const int swz = (l15 & 7) << 3;   // K/pos b128 frag swizzle
    const int vsw = (l15 & 7) << 2;   // V b64 frag swizzle

    // ---- Q as B-fragments: ALL 64 rows per wave (afc/afr[mb][kc]), biases folded ----
    short8 afc[4][2], afr[4][2];
#pragma unroll
    for (int mb = 0; mb < 4; ++mb)
#pragma unroll
        for (int kc = 0; kc < 2; ++kc) {
            uint4 qv = *reinterpret_cast<const uint4*>(
                &qb[qoff + (size_t)(i0 + mb * 16 + l15) * 64 + kc * 32 + q8]);
            unsigned int uu[4] = {qv.x, qv.y, qv.z, qv.w};
            unsigned int cw[4], rw[4];
#pragma unroll
            for (int e = 0; e < 4; ++e) {
                int k = h * 64 + kc * 32 + q8 + 2 * e;
                float lo = __uint_as_float(uu[e] << 16);
                float hi = __uint_as_float(uu[e] & 0xffff0000u);
                cw[e] = pack2bf(lo + ldf(rcb, f32, k), hi + ldf(rcb, f32, k + 1));
                rw[e] = pack2bf(lo + ldf(rpb, f32, k), hi + ldf(rpb, f32, k + 1));
            }
            union { uint4 u; short8 s; } cv, rv2;
            cv.u  = (uint4){cw[0], cw[1], cw[2], cw[3]};
            rv2.u = (uint4){rw[0], rw[1], rw[2], rw[3]};
            afc[mb][kc] = cv.s;
            afr[mb][kc] = rv2.s;
        }

    float4v Oa[4][4];   // O^T partial: [db][mb], d = db*16+q4+r, m = mb*16+l15
#pragma unroll
    for (int db = 0; db < 4; ++db)
#pragma unroll
        for (int mb = 0; mb < 4; ++mb) Oa[db][mb] = (float4v){0.f, 0.f, 0.f, 0.f};
    float lsum[4] = {0.f, 0.f, 0.f, 0.f};   // [mb], m = mb*16+l15, partial over this wave's j

    const int base0 = 1984 - i0;
    const int NT = 32;
    const int cs0 = base0;

    unsigned short* Ks0 = SM;
    unsigned short* Ps0 = SM + 8192;
    unsigned short* Vt0 = SM + 16384;

    // ---- prologue 1: direct-stage pos window cs0 -> Ps0; seed ring (swapped) ----
    {
        int r = tid >> 2, c16 = (tid & 3) * 16;
        const uint4* psrc = reinterpret_cast<const uint4*>(&posb[poff + (size_t)(cs0 + r) * 64 + c16]);
        *reinterpret_cast<uint4*>(&Ps0[r * 64 + c16])     = psrc[0];
        *reinterpret_cast<uint4*>(&Ps0[r * 64 + c16 + 8]) = psrc[1];
    }
    __syncthreads();
    {
        float4v R[4];
#pragma unroll
        for (int mb = 0; mb < 4; ++mb) R[mb] = (float4v){0.f, 0.f, 0.f, 0.f};
        __builtin_amdgcn_s_setprio(1);
#pragma unroll
        for (int kc = 0; kc < 2; ++kc) {
            short8 pb = *reinterpret_cast<const short8*>(
                &Ps0[(w * 16 + l15) * 64 + ((kc * 32 + q8) ^ swz)]);
#pragma unroll
            for (int mb = 0; mb < 4; ++mb)
                R[mb] = __builtin_amdgcn_mfma_f32_16x16x32_bf16(pb, afr[mb][kc], R[mb], 0, 0, 0);
        }
        __builtin_amdgcn_s_setprio(0);
        // ring write, window tb = cs0: t = cs0 + w*16 + q4 + r, m = mb*16 + l15
#pragma unroll
        for (int mb = 0; mb < 4; ++mb) {
            const int col = mb * 16 + l15;
            const int R0 = cs0 + w * 16 + q4 + col;
            unsigned int pk0 = cvtpk(R[mb][0], R[mb][1]);
            unsigned int pk1 = cvtpk(R[mb][2], R[mb][3]);
            Rb[((R0 + 0) & 127) * RST + col] = (unsigned short)pk0;
            Rb[((R0 + 1) & 127) * RST + col] = (unsigned short)(pk0 >> 16);
            Rb[((R0 + 2) & 127) * RST + col] = (unsigned short)pk1;
            Rb[((R0 + 3) & 127) * RST + col] = (unsigned short)(pk1 >> 16);
        }
    }
    __syncthreads();   // seed visible; Ps0 free for restage

    // ---- prologue 2: async stage tile 0 (K0, pos window cs0+64, V0) ----
    stage_lin(&kb[qoff], Ks0, tid, w);
    stage_lin(&posb[poff + (size_t)(cs0 + 64) * 64], Ps0, tid, w);
    stage_vt(vbase, 0, Vt0, tid, w);

    for (int u = 0; u < NT; ++u) {
        const int p = u & 1;
        const int j0 = u * 64, basej = base0 + j0;
        unsigned short* Ksp = SM + p * 4096;
        unsigned short* Psp = SM + 8192 + p * 4096;
        unsigned short* Vtp = SM + 16384 + p * 4096;
        __syncthreads();   // buf[p] staged (drains prefetch)

        // ---- content S^T + rel R^T (swapped operands, wave owns 16 j-cols) ----
        float4v St[4], R[4];
#pragma unroll
        for (int mb = 0; mb < 4; ++mb) {
            St[mb] = (float4v){0.f, 0.f, 0.f, 0.f};
            R[mb]  = (float4v){0.f, 0.f, 0.f, 0.f};
        }
        __builtin_amdgcn_s_setprio(1);
#pragma unroll
        for (int kc = 0; kc < 2; ++kc) {
            short8 kf = *reinterpret_cast<const short8*>(
                &Ksp[(w * 16 + l15) * 64 + ((kc * 32 + q8) ^ swz)]);
            short8 pb = *reinterpret_cast<const short8*>(
                &Psp[(w * 16 + l15) * 64 + ((kc * 32 + q8) ^ swz)]);
#pragma unroll
            for (int mb = 0; mb < 4; ++mb) {
                St[mb] = __builtin_amdgcn_mfma_f32_16x16x32_bf16(kf, afc[mb][kc], St[mb], 0, 0, 0);
                R[mb]  = __builtin_amdgcn_mfma_f32_16x16x32_bf16(pb, afr[mb][kc], R[mb], 0, 0, 0);
            }
        }
        __builtin_amdgcn_s_setprio(0);

        // ---- ring write, window tb = basej+64 ----
        {
            const int tb = basej + 64;
#pragma unroll
            for (int mb = 0; mb < 4; ++mb) {
                const int col = mb * 16 + l15;
                const int R0 = tb + w * 16 + q4 + col;
                unsigned int pk0 = cvtpk(R[mb][0], R[mb][1]);
                unsigned int pk1 = cvtpk(R[mb][2], R[mb][3]);
                Rb[((R0 + 0) & 127) * RST + col] = (unsigned short)pk0;
                Rb[((R0 + 1) & 127) * RST + col] = (unsigned short)(pk0 >> 16);
                Rb[((R0 + 2) & 127) * RST + col] = (unsigned short)pk1;
                Rb[((R0 + 3) & 127) * RST + col] = (unsigned short)(pk1 >> 16);
            }
        }
        __syncthreads();   // fresh ring window visible cross-wave

        // ---- prefetch next tile (in flight across softmax+PV) ----
        if (u + 1 < NT) {
            stage_lin(&kb[qoff + (size_t)(j0 + 64) * 64], SM + (p ^ 1) * 4096, tid, w);
            stage_lin(&posb[poff + (size_t)(cs0 + (u + 2) * 64) * 64], SM + 8192 + (p ^ 1) * 4096, tid, w);
            stage_vt(vbase, j0 + 64, SM + 16384 + (p ^ 1) * 4096, tid, w);
        }

        // ---- gather rel diag, exp, pack P as PV B-frags (in regs) ----
        short4v pb16[4];
        const int G0 = basej + 63 + w * 16 + q4;
#pragma unroll
        for (int mb = 0; mb < 4; ++mb) {
            const int col = mb * 16 + l15;
            float pv[4];
#pragma unroll
            for (int r = 0; r < 4; ++r) {
                float rel = bf2f(Rb[((G0 + r) & 127) * RST + col]);
                float p2 = __expf(St[mb][r] + rel);
                lsum[mb] += p2;
                pv[r] = p2;
            }
            union { unsigned int u2[2]; short4v s; } pk;
            pk.u2[0] = cvtpk(pv[0], pv[1]);
            pk.u2[1] = cvtpk(pv[2], pv[3]);
            pb16[mb] = pk.s;
        }

        // ---- PV: O^T += V^T-frag x P-frag (16x16x16, K = wave's 16 j) ----
        __builtin_amdgcn_s_setprio(1);
#pragma unroll
        for (int db = 0; db < 4; ++db) {
            short4v vf = *reinterpret_cast<const short4v*>(
                &Vtp[(db * 16 + l15) * 64 + ((w * 16 + q4) ^ vsw)]);
#pragma unroll
            for (int mb = 0; mb < 4; ++mb)
                Oa[db][mb] = __builtin_amdgcn_mfma_f32_16x16x16bf16_1k(vf, pb16[mb], Oa[db][mb], 0, 0, 0);
        }
        __builtin_amdgcn_s_setprio(0);
    }

    // ---- wave-local lsum: reduce over quads (j within wave) ----
#pragma unroll
    for (int mb = 0; mb < 4; ++mb) {
        lsum[mb] += __shfl_xor(lsum[mb], 16);
        lsum[mb] += __shfl_xor(lsum[mb], 32);
    }

    // ---- cross-wave O^T + lsum reduction via LDS overlay ----
    __syncthreads();   // all tile LDS use done
    float* Of = (float*)SM;             // [64 d][65] f32 = 16640 B
    float* Ls = (float*)(SM + 8320);    // byte 16640: [4 w][64 m] f32
#pragma unroll
    for (int ww = 0; ww < 4; ++ww) {
        if (w == ww) {
            if (quad == 0) {
#pragma unroll
                for (int mb = 0; mb < 4; ++mb) Ls[ww * 64 + mb * 16 + l15] = lsum[mb];
            }
#pragma unroll
            for (int db = 0; db < 4; ++db)
#pragma unroll
                for (int mb = 0; mb < 4; ++mb)
#pragma unroll
                    for (int r = 0; r < 4; ++r) {
                        float* slot = &Of[(db * 16 + q4 + r) * 65 + mb * 16 + l15];
                        if (ww == 0) *slot = Oa[db][mb][r];
                        else         *slot += Oa[db][mb][r];
                    }
        }
        __syncthreads();
    }

    // ---- normalize + transpose-write ao[b][i][h*64+d] ----
    {
        const int m = tid >> 2, c0 = (tid & 3) * 16;
        float inv = 1.0f / (Ls[m] + Ls[64 + m] + Ls[128 + m] + Ls[192 + m]);
        unsigned int ou[8];
#pragma unroll
        for (int e = 0; e < 8; ++e) {
            float lo = Of[(c0 + 2 * e) * 65 + m] * inv;
            float hi = Of[(c0 + 2 * e + 1) * 65 + m] * inv;
            ou[e] = cvtpk(lo, hi);
        }
        unsigned short* dst = &ao[((size_t)(b * N_ + i0 + m)) * 512 + h * 64 + c0];
        *reinterpret_cast<uint4*>(dst)     = (uint4){ou[0], ou[1], ou[2], ou[3]};
        *reinterpret_cast<uint4*>(dst + 8) = (uint4){ou[4], ou[5], ou[6], ou[7]};
    }
}

// ---------------------------------------------------------------------------
// 4) out = ao @ Wo + bo, 64x128 tile, grid (12,64).
// ---------------------------------------------------------------------------
__global__ __launch_bounds__(256) void outproj_kernel(const unsigned int* __restrict__ flags,
                                                      const unsigned short* __restrict__ AO,
                                                      const unsigned short* __restrict__ Wot,
                                                      const void* __restrict__ bo,
                                                      void* __restrict__ out) {
    __shared__ __align__(16) unsigned short As[64 * 32];
    __shared__ __align__(16) unsigned short Bs[128 * 32];
    const int f32 = (int)flags[0];
    const int row0 = blockIdx.y * 64, col0 = blockIdx.x * 128;
    float4v acc[2][4];
#pragma unroll
    for (int mi = 0; mi < 2; ++mi)
#pragma unroll
        for (int ni = 0; ni < 4; ++ni) acc[mi][ni] = (float4v){0.f, 0.f, 0.f, 0.f};
    gemm64x128_core(AO, Wot, 512, row0, col0, As, Bs, acc);
    const int lane = threadIdx.x & 63, w = threadIdx.x >> 6;
    const int l15 = lane & 15, quad = lane >> 4;
    const int mr0 = (w & 1) * 32, nc0 = (w >> 1) * 64;
#pragma unroll
    for (int mi = 0; mi < 2; ++mi)
#pragma unroll
        for (int ni = 0; ni < 4; ++ni) {
            int n = col0 + nc0 + ni * 16 + l15;
            float bias = ldf(bo, f32, n);
#pragma unroll
            for (int r = 0; r < 4; ++r) {
                int m = row0 + mr0 + mi * 16 + quad * 4 + r;
                float v = acc[mi][ni][r] + bias;
                if (f32) ((float*)out)[(size_t)m * DIM_ + n] = v;
                else     ((unsigned short*)out)[(size_t)m * DIM_ + n] = f2bf(v);
            }
        }
}

// ---------------------------------------------------------------------------
extern "C" void kernel_launch(void* const* d_in, const int* in_sizes, int n_in,
                              void* d_out, int out_size, void* d_ws, size_t ws_size,
                              hipStream_t stream) {
    const void* x    = d_in[0];
    const void* Wq   = d_in[1];
    const void* Wk   = d_in[2];
    const void* Wv   = d_in[3];
    const void* Wo   = d_in[4];
    const void* bo   = d_in[5];
    const void* Wrel = d_in[6];
    const void* rcb  = d_in[7];
    const void* rpb  = d_in[8];

    char* ws = (char*)d_ws;
    unsigned int*   flags = (unsigned int*)(ws + OFF_FLAG);
    unsigned short* posb  = (unsigned short*)(ws + OFF_POS);
    unsigned short* qbuf  = (unsigned short*)(ws + OFF_Q);
    unsigned short* kbuf  = (unsigned short*)(ws + OFF_K);
    unsigned short* vbuf  = (unsigned short*)(ws + OFF_V);
    unsigned short* Wot   = (unsigned short*)(ws + OFF_WOT);
    unsigned short* Xb    = (unsigned short*)(ws + OFF_XB);
    unsigned short* ao    = (unsigned short*)(ws + OFF_AO);
    unsigned short* Wt    = (unsigned short*)(ws + OFF_WT);

    // Host-side constants (capture-time only; pure functions of problem consts)
    PosConsts pc;
    double maxp = 0.0;
    for (int g = 0; g < NB_; ++g) {
        double mean = 64.0 * (g + 1);
        double conc = (mean / 32.0) * (mean / 32.0);
        double rate = mean / 1024.0;
        double lgc  = std::lgamma(conc);
        double clr  = conc * std::log(rate);
        for (int ad = 1; ad < N_; ++ad) {
            double lp = (conc - 1.0) * std::log((double)ad) - rate * (double)ad - lgc + clr;
            double p  = std::exp(lp) + 1e-8;
            if (p > maxp) maxp = p;
        }
        pc.c1[g]    = (float)(conc - 1.0);   // exact small integer
        pc.rateF[g] = (float)rate;           // exact dyadic
        pc.gc[g]    = -lgc + clr;
    }
    pc.maxp = maxp;
    const double max_range = std::log((double)N_) / std::log(2.0);   // 11.0
    for (int f = 0; f < 32; ++f) {
        double t = 3.0 + (double)f * (max_range - 3.0) / 31.0;
        pc.inv_hl[f] = (float)std::exp2(-t);
        int e = f + 1;   // central-mask exponent for class index f
        pc.widthI[f] = (e >= 12) ? 0x7FFFFFFF : ((1 << e) - 1);   // adI<=2047: clamp exact
    }

    prep_kernel<<<dim3(2048), dim3(512), 0, stream>>>(pc, x, Wq, Wk, Wv, Wo, Wrel,
                                                      flags, Xb, Wt, Wot, posb);
    qkv_kernel<<<dim3(12, 64), dim3(256), 0, stream>>>(Xb, Wt, qbuf, kbuf, vbuf);
    attn_kernel<<<dim3(32, 16), dim3(256), 0, stream>>>(flags, qbuf, kbuf, vbuf, posb, rcb, rpb, ao);
    outproj_kernel<<<dim3(12, 64), dim3(256), 0, stream>>>(flags, ao, Wot, bo, d_out);
}